// Round 5
// baseline (568.083 us; speedup 1.0000x reference)
//
#include <hip/hip_runtime.h>
#include <cstdint>
#include <math.h>

#define BB 16
#define NN 2048
#define EE 32768
#define FIN 32
#define HH 128
#define KK1 1639
#define KK2 1312
#define KK3 1050

// ---------------- layer-1 CSR count: incoming edges per dst ----------------
__global__ void csr_count_kernel(const int* __restrict__ dsts, int stride,
                                 int* __restrict__ deg) {
    int t = blockIdx.x * blockDim.x + threadIdx.x;   // B*E
    int e = t & (EE - 1);
    int b = t >> 15;
    if (b >= BB) return;
    int d = dsts[(size_t)b * stride + e];
    if (d >= 0) atomicAdd(&deg[b * NN + d], 1);
}

// ---------------- CSR scan (shfl) + self-zero deg for next layer ----------------
__global__ __launch_bounds__(1024) void csr_scan_kernel(
    int* __restrict__ deg, int* __restrict__ rowptr, int* __restrict__ cursor) {
    __shared__ int wsum[16];
    int b = blockIdx.x, t = threadIdx.x;
    int d0 = deg[b * NN + 2 * t];
    int d1 = deg[b * NN + 2 * t + 1];
    deg[b * NN + 2 * t] = 0;                 // zero for next layer's counting
    deg[b * NN + 2 * t + 1] = 0;
    int s = d0 + d1;
    int lane = t & 63;
    int v = s;
#pragma unroll
    for (int off = 1; off < 64; off <<= 1) {
        int u = __shfl_up(v, off);
        if (lane >= off) v += u;
    }
    if (lane == 63) wsum[t >> 6] = v;
    __syncthreads();
    int w = t >> 6;
    int woff = 0;
#pragma unroll
    for (int i = 0; i < 16; i++) woff += (i < w) ? wsum[i] : 0;
    int excl = woff + v - s;
    int base = b * (NN + 1);
    if (t == 0) { rowptr[base] = 0; cursor[base] = 0; }
    int p0 = excl + d0, p1 = excl + d0 + d1;
    rowptr[base + 2 * t + 1] = p0; cursor[base + 2 * t + 1] = p0;
    rowptr[base + 2 * t + 2] = p1; cursor[base + 2 * t + 2] = p1;
}

// ---------------- CSR fill: scatter source ids ----------------
__global__ void csr_fill_kernel(const int* __restrict__ srcs,
                                const int* __restrict__ dsts, int stride,
                                int* __restrict__ cursor, int* __restrict__ csr) {
    int t = blockIdx.x * blockDim.x + threadIdx.x;   // B*E
    int e = t & (EE - 1);
    int b = t >> 15;
    if (b >= BB) return;
    int s = srcs[(size_t)b * stride + e];
    int d = dsts[(size_t)b * stride + e];
    if (s >= 0 && d >= 0) {
        int pos = atomicAdd(&cursor[b * (NN + 1) + d], 1);
        csr[(size_t)b * EE + pos] = s;
    }
}

// ---------------- pull aggregation, F=32 (layer 1) ----------------
__global__ __launch_bounds__(256) void agg1_csr_kernel(
    const float* __restrict__ x, const int* __restrict__ rowptr,
    const int* __restrict__ csr, float* __restrict__ agg) {
    int b = blockIdx.y;
    int g = threadIdx.x >> 5, lane = threadIdx.x & 31;
    int node = blockIdx.x * 8 + g;
    int beg = rowptr[b * (NN + 1) + node];
    int end = rowptr[b * (NN + 1) + node + 1];
    float acc = 0.f;
    for (int j = beg; j < end; j++) {
        int s = csr[(size_t)b * EE + j];
        acc += x[((size_t)b * NN + s) * FIN + lane];
    }
    agg[((size_t)b * NN + node) * FIN + lane] = acc;
}

// ---------------- pull aggregation, F=128 (layers 2/3) ----------------
__global__ __launch_bounds__(128) void agg23_csr_kernel(
    const float* __restrict__ x, const int* __restrict__ rowptr,
    const int* __restrict__ csr, float* __restrict__ agg, int n) {
    int b = blockIdx.y;
    int tid = threadIdx.x;
#pragma unroll
    for (int r = 0; r < 4; r++) {
        int node = blockIdx.x * 4 + r;
        if (node >= n) break;
        int beg = rowptr[b * (NN + 1) + node];
        int end = rowptr[b * (NN + 1) + node + 1];
        float acc = 0.f;
        for (int j = beg; j < end; j++) {
            int s = csr[(size_t)b * EE + j];
            acc += x[((size_t)b * NN + s) * HH + tid];
        }
        agg[((size_t)b * NN + node) * HH + tid] = acc;
    }
}

// ---------------- fused conv + score/key ----------------
// 32 rows x 128 cols per block, K-chunk 32; 256 threads, each a 4x4 tile.
// LDS ~22KB -> ~7 blocks/CU so staging bubbles overlap across blocks.
template<int FI>
__global__ __launch_bounds__(256) void conv_fused_kernel(
    const float* __restrict__ x, const float* __restrict__ agg,
    const float* __restrict__ Wroot, const float* __restrict__ Wrel,
    const float* __restrict__ bias, const float* __restrict__ p,
    float* __restrict__ h, unsigned long long* __restrict__ keys,
    float* __restrict__ ssc, int n) {
    constexpr int NCH = (2 * FI) / 32;      // K-chunks of 32
    __shared__ float sxt[32][36];           // [j][row], 36*4B keeps 16B align, bank-safe
    __shared__ float swt[32][132];          // [j][col]
    __shared__ float sp[HH];
    __shared__ float snorm;

    int b = blockIdx.y;
    int r0 = blockIdx.x * 32;
    int t = threadIdx.x;

    if (t < HH) sp[t] = p[t];
    __syncthreads();
    if (t < 64) {
        float v = sp[t] * sp[t] + sp[t + 64] * sp[t + 64];
#pragma unroll
        for (int off = 32; off; off >>= 1) v += __shfl_xor(v, off);
        if (t == 0) snorm = sqrtf(v);
    }

    int cg = t & 31;          // col group (4 cols)
    int rg = t >> 5;          // row group (4 rows)
    int c4 = cg * 4;
    int rl = rg * 4;
    int xrow = t >> 3;        // staging: row 0..31
    int xj4 = t & 7;          // staging: j-quad 0..7

    float acc[4][4];
#pragma unroll
    for (int i = 0; i < 4; i++)
#pragma unroll
        for (int j = 0; j < 4; j++) acc[i][j] = 0.f;

    for (int ch = 0; ch < NCH; ch++) {
        int j0 = ch * 32;
        __syncthreads();
        {   // stage x/agg tile (32 rows x 32 j), transposed
            int jj = j0 + xj4 * 4;
            const float* src = (jj < FI)
                ? (x + ((size_t)b * NN + r0 + xrow) * FI + jj)
                : (agg + ((size_t)b * NN + r0 + xrow) * FI + (jj - FI));
            float4 v = *reinterpret_cast<const float4*>(src);
            sxt[xj4 * 4 + 0][xrow] = v.x;
            sxt[xj4 * 4 + 1][xrow] = v.y;
            sxt[xj4 * 4 + 2][xrow] = v.z;
            sxt[xj4 * 4 + 3][xrow] = v.w;
        }
#pragma unroll
        for (int it = 0; it < 4; it++) {    // stage W tile (128 cols x 32 j), transposed
            int idx = t + it * 256;
            int c = idx >> 3;
            int j4 = idx & 7;
            int jj = j0 + j4 * 4;
            const float* src = (jj < FI)
                ? (Wroot + (size_t)c * FI + jj)
                : (Wrel + (size_t)c * FI + (jj - FI));
            float4 v = *reinterpret_cast<const float4*>(src);
            swt[j4 * 4 + 0][c] = v.x;
            swt[j4 * 4 + 1][c] = v.y;
            swt[j4 * 4 + 2][c] = v.z;
            swt[j4 * 4 + 3][c] = v.w;
        }
        __syncthreads();
#pragma unroll 8
        for (int j = 0; j < 32; j++) {
            float4 wv = *reinterpret_cast<const float4*>(&swt[j][c4]);
            float4 xv = *reinterpret_cast<const float4*>(&sxt[j][rl]);
            float xs[4] = {xv.x, xv.y, xv.z, xv.w};
            float wsv[4] = {wv.x, wv.y, wv.z, wv.w};
#pragma unroll
            for (int ri = 0; ri < 4; ri++)
#pragma unroll
                for (int ci = 0; ci < 4; ci++)
                    acc[ri][ci] += xs[ri] * wsv[ci];
        }
    }

    // epilogue: bias + relu + store + fused score
    float4 bv = *reinterpret_cast<const float4*>(bias + c4);
    float pc[4] = {sp[c4], sp[c4 + 1], sp[c4 + 2], sp[c4 + 3]};
    float pr[4];
#pragma unroll
    for (int ri = 0; ri < 4; ri++) {
        int row = r0 + rl + ri;
        float4 hv;
        hv.x = fmaxf(acc[ri][0] + bv.x, 0.f);
        hv.y = fmaxf(acc[ri][1] + bv.y, 0.f);
        hv.z = fmaxf(acc[ri][2] + bv.z, 0.f);
        hv.w = fmaxf(acc[ri][3] + bv.w, 0.f);
        pr[ri] = hv.x * pc[0] + hv.y * pc[1] + hv.z * pc[2] + hv.w * pc[3];
        if (row < n)
            *reinterpret_cast<float4*>(h + ((size_t)b * NN + row) * HH + c4) = hv;
    }
#pragma unroll
    for (int ri = 0; ri < 4; ri++) {
#pragma unroll
        for (int off = 16; off; off >>= 1) pr[ri] += __shfl_xor(pr[ri], off);
    }
    if (cg == 0) {
        float inorm = 1.f / snorm;
#pragma unroll
        for (int ri = 0; ri < 4; ri++) {
            int row = r0 + rl + ri;
            if (row < n) {
                float sc = tanhf(pr[ri] * inorm);
                unsigned u = __float_as_uint(sc);
                u = (u & 0x80000000u) ? ~u : (u ^ 0x80000000u);   // monotone asc
                u = ~u;                                            // -> descending
                keys[(size_t)b * NN + row] = ((unsigned long long)u << 32) | (unsigned)row;
                ssc[(size_t)b * NN + row] = sc;
            }
        }
    }
}

// ---------------- exact rank via all-pairs compare (keys unique; tail in-kernel) ----------------
__global__ __launch_bounds__(256) void rank_kernel(
    const unsigned long long* __restrict__ keys, const float* __restrict__ ssc,
    int n, int k, int* __restrict__ perm, float* __restrict__ vals,
    int* __restrict__ inv) {
    __shared__ unsigned long long sk[NN];
    int b = blockIdx.y;
    for (int i = threadIdx.x; i < NN; i += 256)
        sk[i] = (i < n) ? keys[(size_t)b * NN + i] : ~0ULL;
    __syncthreads();
    int i = blockIdx.x * 256 + threadIdx.x;
    unsigned long long my = sk[i];
    int rank = 0;
#pragma unroll 8
    for (int j = 0; j < NN; j++) rank += (sk[j] < my) ? 1 : 0;
    if (i < n) {
        if (rank < k) {
            perm[b * NN + rank] = i;
            vals[b * NN + rank] = ssc[(size_t)b * NN + i];
            inv[b * NN + i] = rank;
        } else {
            inv[b * NN + i] = -1;
        }
    }
}

// ---------------- fused gather*score + readout partials ----------------
__global__ __launch_bounds__(128) void gather_part_kernel(
    const float* __restrict__ hin, float* __restrict__ xout,
    const int* __restrict__ perm, const float* __restrict__ vals, int k,
    float* __restrict__ part) {
    int b = blockIdx.x >> 4;
    int j = blockIdx.x & 15;
    int f = threadIdx.x;
    float mx = -INFINITY, sm = 0.f;
    for (int i = j; i < k; i += 16) {
        int pi = perm[b * NN + i];
        float v = vals[b * NN + i];
        float hv = hin[((size_t)b * NN + pi) * HH + f] * v;
        xout[((size_t)b * NN + i) * HH + f] = hv;
        mx = fmaxf(mx, hv);
        sm += hv;
    }
    part[(size_t)blockIdx.x * 256 + f] = mx;
    part[(size_t)blockIdx.x * 256 + 128 + f] = sm;
}

// ---------------- edge remap through inv + degree count for next CSR ----------------
__global__ void remap_count_kernel(const int* __restrict__ inv,
                                   const int* __restrict__ sin_,
                                   const int* __restrict__ din_,
                                   int in_stride,
                                   int* __restrict__ sout, int* __restrict__ dout,
                                   int* __restrict__ deg) {
    int t = blockIdx.x * blockDim.x + threadIdx.x;   // B*E
    int e = t & (EE - 1);
    int b = t >> 15;
    if (b >= BB) return;
    int s = sin_[(size_t)b * in_stride + e];
    int d = din_[(size_t)b * in_stride + e];
    int ns = -1, nd = -1;
    if (s >= 0 && d >= 0) {
        ns = inv[b * NN + s];
        nd = inv[b * NN + d];
    }
    if (ns < 0 || nd < 0) { ns = -1; nd = -1; }
    sout[b * EE + e] = ns;
    dout[b * EE + e] = nd;
    if (nd >= 0) atomicAdd(&deg[b * NN + nd], 1);
}

// ---------------- final: combine partials (3 layers) + MLP ----------------
__global__ __launch_bounds__(256) void mlp_kernel(
    const float* __restrict__ part1, const float* __restrict__ part2,
    const float* __restrict__ part3,
    const float* __restrict__ W1, const float* __restrict__ b1,
    const float* __restrict__ W2, const float* __restrict__ b2,
    const float* __restrict__ W3, const float* __restrict__ b3,
    float* __restrict__ out) {
    __shared__ float sg[256];
    __shared__ float s1[128];
    __shared__ float s2[64];
    int b = blockIdx.x, tid = threadIdx.x;
    const float* parts[3] = {part1, part2, part3};
    const float kk[3] = {(float)KK1, (float)KK2, (float)KK3};
    float acc = 0.f;
    if (tid < 128) {
#pragma unroll
        for (int l = 0; l < 3; l++) {
            float mx = -INFINITY;
            for (int j = 0; j < 16; j++)
                mx = fmaxf(mx, parts[l][((size_t)b * 16 + j) * 256 + tid]);
            acc += mx;
        }
    } else {
        int f = tid - 128;
#pragma unroll
        for (int l = 0; l < 3; l++) {
            float sm = 0.f;
            for (int j = 0; j < 16; j++)
                sm += parts[l][((size_t)b * 16 + j) * 256 + 128 + f];
            acc += sm / kk[l];
        }
    }
    sg[tid] = acc;
    __syncthreads();
    if (tid < 128) {
        float a = b1[tid];
        for (int j = 0; j < 256; j++) a += sg[j] * W1[tid * 256 + j];
        s1[tid] = fmaxf(a, 0.f);
    }
    __syncthreads();
    if (tid < 64) {
        float a = b2[tid];
        for (int j = 0; j < 128; j++) a += s1[j] * W2[tid * 128 + j];
        s2[tid] = fmaxf(a, 0.f);
    }
    __syncthreads();
    if (tid == 0) {
        float a = b3[0];
        for (int j = 0; j < 64; j++) a += s2[j] * W3[j];
        out[b] = 1.f / (1.f + expf(-a));
    }
}

extern "C" void kernel_launch(void* const* d_in, const int* in_sizes, int n_in,
                              void* d_out, int out_size, void* d_ws, size_t ws_size,
                              hipStream_t stream) {
    const float* x   = (const float*)d_in[0];
    const int*   ei  = (const int*)d_in[1];
    const float* Wr1 = (const float*)d_in[2];
    const float* Wl1 = (const float*)d_in[3];
    const float* b1  = (const float*)d_in[4];
    const float* p1  = (const float*)d_in[5];
    const float* Wr2 = (const float*)d_in[6];
    const float* Wl2 = (const float*)d_in[7];
    const float* b2  = (const float*)d_in[8];
    const float* p2  = (const float*)d_in[9];
    const float* Wr3 = (const float*)d_in[10];
    const float* Wl3 = (const float*)d_in[11];
    const float* b3  = (const float*)d_in[12];
    const float* p3  = (const float*)d_in[13];
    const float* l1W = (const float*)d_in[14];
    const float* l1b = (const float*)d_in[15];
    const float* l2W = (const float*)d_in[16];
    const float* l2b = (const float*)d_in[17];
    const float* l3W = (const float*)d_in[18];
    const float* l3b = (const float*)d_in[19];
    float* out = (float*)d_out;

    char* ws = (char*)d_ws;
    float* bufA = (float*)ws; ws += (size_t)BB * NN * HH * 4;
    float* bufB = (float*)ws; ws += (size_t)BB * NN * HH * 4;
    float* agg  = (float*)ws; ws += (size_t)BB * NN * HH * 4;
    int*   perm = (int*)ws;   ws += (size_t)BB * NN * 4;
    float* vals = (float*)ws; ws += (size_t)BB * NN * 4;
    int*   inv  = (int*)ws;   ws += (size_t)BB * NN * 4;
    int*   curS = (int*)ws;   ws += (size_t)BB * EE * 4;
    int*   curD = (int*)ws;   ws += (size_t)BB * EE * 4;
    float* part1 = (float*)ws; ws += (size_t)BB * 16 * 256 * 4;
    float* part2 = (float*)ws; ws += (size_t)BB * 16 * 256 * 4;
    float* part3 = (float*)ws; ws += (size_t)BB * 16 * 256 * 4;
    int*   deg  = (int*)ws;   ws += (size_t)BB * NN * 4;
    int*   rowptr = (int*)ws; ws += (size_t)BB * (NN + 1) * 4;
    int*   cursor = (int*)ws; ws += (size_t)BB * (NN + 1) * 4;
    unsigned long long* keys = (unsigned long long*)ws; ws += (size_t)BB * NN * 8;
    float* ssc  = (float*)ws; ws += (size_t)BB * NN * 4;
    // CSR source array lives in bufA: per layer, CSR build + aggregation finish
    // BEFORE conv writes bufA, and CSR is dead afterwards.
    int*   csr = (int*)bufA;

    // ---------- layer 1 ----------
    hipMemsetAsync(deg, 0, (size_t)BB * NN * 4, stream);
    hipLaunchKernelGGL(csr_count_kernel, dim3(BB * EE / 256), dim3(256), 0, stream, ei + EE, 2 * EE, deg);
    hipLaunchKernelGGL(csr_scan_kernel, dim3(BB), dim3(1024), 0, stream, deg, rowptr, cursor);
    hipLaunchKernelGGL(csr_fill_kernel, dim3(BB * EE / 256), dim3(256), 0, stream, ei, ei + EE, 2 * EE, cursor, csr);
    hipLaunchKernelGGL(agg1_csr_kernel, dim3(NN / 8, BB), dim3(256), 0, stream, x, rowptr, csr, agg);
    hipLaunchKernelGGL((conv_fused_kernel<FIN>), dim3(NN / 32, BB), dim3(256), 0, stream,
                       x, agg, Wr1, Wl1, b1, p1, bufA, keys, ssc, NN);
    hipLaunchKernelGGL(rank_kernel, dim3(NN / 256, BB), dim3(256), 0, stream, keys, ssc, NN, KK1, perm, vals, inv);
    hipLaunchKernelGGL(gather_part_kernel, dim3(BB * 16), dim3(128), 0, stream, bufA, bufB, perm, vals, KK1, part1);
    hipLaunchKernelGGL(remap_count_kernel, dim3(BB * EE / 256), dim3(256), 0, stream, inv, ei, ei + EE, 2 * EE, curS, curD, deg);

    // ---------- layer 2 ----------
    hipLaunchKernelGGL(csr_scan_kernel, dim3(BB), dim3(1024), 0, stream, deg, rowptr, cursor);
    hipLaunchKernelGGL(csr_fill_kernel, dim3(BB * EE / 256), dim3(256), 0, stream, curS, curD, EE, cursor, csr);
    hipLaunchKernelGGL(agg23_csr_kernel, dim3((KK1 + 3) / 4, BB), dim3(128), 0, stream, bufB, rowptr, csr, agg, KK1);
    hipLaunchKernelGGL((conv_fused_kernel<HH>), dim3((KK1 + 31) / 32, BB), dim3(256), 0, stream,
                       bufB, agg, Wr2, Wl2, b2, p2, bufA, keys, ssc, KK1);
    hipLaunchKernelGGL(rank_kernel, dim3(NN / 256, BB), dim3(256), 0, stream, keys, ssc, KK1, KK2, perm, vals, inv);
    hipLaunchKernelGGL(gather_part_kernel, dim3(BB * 16), dim3(128), 0, stream, bufA, bufB, perm, vals, KK2, part2);
    hipLaunchKernelGGL(remap_count_kernel, dim3(BB * EE / 256), dim3(256), 0, stream, inv, curS, curD, EE, curS, curD, deg);

    // ---------- layer 3 ----------
    hipLaunchKernelGGL(csr_scan_kernel, dim3(BB), dim3(1024), 0, stream, deg, rowptr, cursor);
    hipLaunchKernelGGL(csr_fill_kernel, dim3(BB * EE / 256), dim3(256), 0, stream, curS, curD, EE, cursor, csr);
    hipLaunchKernelGGL(agg23_csr_kernel, dim3((KK2 + 3) / 4, BB), dim3(128), 0, stream, bufB, rowptr, csr, agg, KK2);
    hipLaunchKernelGGL((conv_fused_kernel<HH>), dim3((KK2 + 31) / 32, BB), dim3(256), 0, stream,
                       bufB, agg, Wr3, Wl3, b3, p3, bufA, keys, ssc, KK2);
    hipLaunchKernelGGL(rank_kernel, dim3(NN / 256, BB), dim3(256), 0, stream, keys, ssc, KK2, KK3, perm, vals, inv);
    hipLaunchKernelGGL(gather_part_kernel, dim3(BB * 16), dim3(128), 0, stream, bufA, bufB, perm, vals, KK3, part3);

    // ---------- final: combine readouts + MLP ----------
    hipLaunchKernelGGL(mlp_kernel, dim3(BB), dim3(256), 0, stream,
                       part1, part2, part3, l1W, l1b, l2W, l2b, l3W, l3b, out);
}

// Round 6
// 501.991 us; speedup vs baseline: 1.1317x; 1.1317x over previous
//
#include <hip/hip_runtime.h>
#include <cstdint>
#include <math.h>

#define BB 16
#define NN 2048
#define EE 32768
#define FIN 32
#define HH 128
#define KK1 1639
#define KK2 1312
#define KK3 1050
#define PARTS 128

// ---------------- layer-1 CSR count: incoming edges per dst ----------------
__global__ void csr_count_kernel(const int* __restrict__ dsts, int stride,
                                 int* __restrict__ deg) {
    int t = blockIdx.x * blockDim.x + threadIdx.x;   // B*E
    int e = t & (EE - 1);
    int b = t >> 15;
    if (b >= BB) return;
    int d = dsts[(size_t)b * stride + e];
    if (d >= 0) atomicAdd(&deg[b * NN + d], 1);
}

// ---------------- CSR scan (shfl) + self-zero deg for next layer ----------------
__global__ __launch_bounds__(1024) void csr_scan_kernel(
    int* __restrict__ deg, int* __restrict__ rowptr, int* __restrict__ cursor) {
    __shared__ int wsum[16];
    int b = blockIdx.x, t = threadIdx.x;
    int d0 = deg[b * NN + 2 * t];
    int d1 = deg[b * NN + 2 * t + 1];
    deg[b * NN + 2 * t] = 0;                 // zero for next layer's counting
    deg[b * NN + 2 * t + 1] = 0;
    int s = d0 + d1;
    int lane = t & 63;
    int v = s;
#pragma unroll
    for (int off = 1; off < 64; off <<= 1) {
        int u = __shfl_up(v, off);
        if (lane >= off) v += u;
    }
    if (lane == 63) wsum[t >> 6] = v;
    __syncthreads();
    int w = t >> 6;
    int woff = 0;
#pragma unroll
    for (int i = 0; i < 16; i++) woff += (i < w) ? wsum[i] : 0;
    int excl = woff + v - s;
    int base = b * (NN + 1);
    if (t == 0) { rowptr[base] = 0; cursor[base] = 0; }
    int p0 = excl + d0, p1 = excl + d0 + d1;
    rowptr[base + 2 * t + 1] = p0; cursor[base + 2 * t + 1] = p0;
    rowptr[base + 2 * t + 2] = p1; cursor[base + 2 * t + 2] = p1;
}

// ---------------- CSR fill: scatter source ids ----------------
__global__ void csr_fill_kernel(const int* __restrict__ srcs,
                                const int* __restrict__ dsts, int stride,
                                int* __restrict__ cursor, int* __restrict__ csr) {
    int t = blockIdx.x * blockDim.x + threadIdx.x;   // B*E
    int e = t & (EE - 1);
    int b = t >> 15;
    if (b >= BB) return;
    int s = srcs[(size_t)b * stride + e];
    int d = dsts[(size_t)b * stride + e];
    if (s >= 0 && d >= 0) {
        int pos = atomicAdd(&cursor[b * (NN + 1) + d], 1);
        csr[(size_t)b * EE + pos] = s;
    }
}

// ---------------- pull aggregation, F=32 (layer 1) ----------------
__global__ __launch_bounds__(256) void agg1_csr_kernel(
    const float* __restrict__ x, const int* __restrict__ rowptr,
    const int* __restrict__ csr, float* __restrict__ agg) {
    int b = blockIdx.y;
    int g = threadIdx.x >> 5, lane = threadIdx.x & 31;
    int node = blockIdx.x * 8 + g;
    int beg = rowptr[b * (NN + 1) + node];
    int end = rowptr[b * (NN + 1) + node + 1];
    float acc = 0.f;
    for (int j = beg; j < end; j++) {
        int s = csr[(size_t)b * EE + j];
        acc += x[((size_t)b * NN + s) * FIN + lane];
    }
    agg[((size_t)b * NN + node) * FIN + lane] = acc;
}

// ---------------- pull aggregation, F=128 (layers 2/3) ----------------
__global__ __launch_bounds__(128) void agg23_csr_kernel(
    const float* __restrict__ x, const int* __restrict__ rowptr,
    const int* __restrict__ csr, float* __restrict__ agg, int n) {
    int b = blockIdx.y;
    int tid = threadIdx.x;
#pragma unroll
    for (int r = 0; r < 4; r++) {
        int node = blockIdx.x * 4 + r;
        if (node >= n) break;
        int beg = rowptr[b * (NN + 1) + node];
        int end = rowptr[b * (NN + 1) + node + 1];
        float acc = 0.f;
        for (int j = beg; j < end; j++) {
            int s = csr[(size_t)b * EE + j];
            acc += x[((size_t)b * NN + s) * HH + tid];
        }
        agg[((size_t)b * NN + node) * HH + tid] = acc;
    }
}

// ---------------- fused conv + score/key ----------------
// 32 rows x 128 cols per block, K-chunk 32; 256 threads, each a 4x4 tile.
template<int FI>
__global__ __launch_bounds__(256) void conv_fused_kernel(
    const float* __restrict__ x, const float* __restrict__ agg,
    const float* __restrict__ Wroot, const float* __restrict__ Wrel,
    const float* __restrict__ bias, const float* __restrict__ p,
    float* __restrict__ h, unsigned long long* __restrict__ keys,
    float* __restrict__ ssc, int n) {
    constexpr int NCH = (2 * FI) / 32;      // K-chunks of 32
    __shared__ float sxt[32][36];           // [j][row]
    __shared__ float swt[32][132];          // [j][col]
    __shared__ float sp[HH];
    __shared__ float snorm;

    int b = blockIdx.y;
    int r0 = blockIdx.x * 32;
    int t = threadIdx.x;

    if (t < HH) sp[t] = p[t];
    __syncthreads();
    if (t < 64) {
        float v = sp[t] * sp[t] + sp[t + 64] * sp[t + 64];
#pragma unroll
        for (int off = 32; off; off >>= 1) v += __shfl_xor(v, off);
        if (t == 0) snorm = sqrtf(v);
    }

    int cg = t & 31;          // col group (4 cols)
    int rg = t >> 5;          // row group (4 rows)
    int c4 = cg * 4;
    int rl = rg * 4;
    int xrow = t >> 3;        // staging: row 0..31
    int xj4 = t & 7;          // staging: j-quad 0..7

    float acc[4][4];
#pragma unroll
    for (int i = 0; i < 4; i++)
#pragma unroll
        for (int j = 0; j < 4; j++) acc[i][j] = 0.f;

    for (int ch = 0; ch < NCH; ch++) {
        int j0 = ch * 32;
        __syncthreads();
        {   // stage x/agg tile (32 rows x 32 j), transposed
            int jj = j0 + xj4 * 4;
            const float* src = (jj < FI)
                ? (x + ((size_t)b * NN + r0 + xrow) * FI + jj)
                : (agg + ((size_t)b * NN + r0 + xrow) * FI + (jj - FI));
            float4 v = *reinterpret_cast<const float4*>(src);
            sxt[xj4 * 4 + 0][xrow] = v.x;
            sxt[xj4 * 4 + 1][xrow] = v.y;
            sxt[xj4 * 4 + 2][xrow] = v.z;
            sxt[xj4 * 4 + 3][xrow] = v.w;
        }
#pragma unroll
        for (int it = 0; it < 4; it++) {    // stage W tile (128 cols x 32 j), transposed
            int idx = t + it * 256;
            int c = idx >> 3;
            int j4 = idx & 7;
            int jj = j0 + j4 * 4;
            const float* src = (jj < FI)
                ? (Wroot + (size_t)c * FI + jj)
                : (Wrel + (size_t)c * FI + (jj - FI));
            float4 v = *reinterpret_cast<const float4*>(src);
            swt[j4 * 4 + 0][c] = v.x;
            swt[j4 * 4 + 1][c] = v.y;
            swt[j4 * 4 + 2][c] = v.z;
            swt[j4 * 4 + 3][c] = v.w;
        }
        __syncthreads();
#pragma unroll 8
        for (int j = 0; j < 32; j++) {
            float4 wv = *reinterpret_cast<const float4*>(&swt[j][c4]);
            float4 xv = *reinterpret_cast<const float4*>(&sxt[j][rl]);
            float xs[4] = {xv.x, xv.y, xv.z, xv.w};
            float wsv[4] = {wv.x, wv.y, wv.z, wv.w};
#pragma unroll
            for (int ri = 0; ri < 4; ri++)
#pragma unroll
                for (int ci = 0; ci < 4; ci++)
                    acc[ri][ci] += xs[ri] * wsv[ci];
        }
    }

    // epilogue: bias + relu + store + fused score
    float4 bv = *reinterpret_cast<const float4*>(bias + c4);
    float pc[4] = {sp[c4], sp[c4 + 1], sp[c4 + 2], sp[c4 + 3]};
    float pr[4];
#pragma unroll
    for (int ri = 0; ri < 4; ri++) {
        int row = r0 + rl + ri;
        float4 hv;
        hv.x = fmaxf(acc[ri][0] + bv.x, 0.f);
        hv.y = fmaxf(acc[ri][1] + bv.y, 0.f);
        hv.z = fmaxf(acc[ri][2] + bv.z, 0.f);
        hv.w = fmaxf(acc[ri][3] + bv.w, 0.f);
        pr[ri] = hv.x * pc[0] + hv.y * pc[1] + hv.z * pc[2] + hv.w * pc[3];
        if (row < n)
            *reinterpret_cast<float4*>(h + ((size_t)b * NN + row) * HH + c4) = hv;
    }
#pragma unroll
    for (int ri = 0; ri < 4; ri++) {
#pragma unroll
        for (int off = 16; off; off >>= 1) pr[ri] += __shfl_xor(pr[ri], off);
    }
    if (cg == 0) {
        float inorm = 1.f / snorm;
#pragma unroll
        for (int ri = 0; ri < 4; ri++) {
            int row = r0 + rl + ri;
            if (row < n) {
                float sc = tanhf(pr[ri] * inorm);
                unsigned u = __float_as_uint(sc);
                u = (u & 0x80000000u) ? ~u : (u ^ 0x80000000u);   // monotone asc
                u = ~u;                                            // -> descending
                keys[(size_t)b * NN + row] = ((unsigned long long)u << 32) | (unsigned)row;
                ssc[(size_t)b * NN + row] = sc;
            }
        }
    }
}

// ---------------- exact rank via all-pairs compare (keys unique; tail in-kernel) ----------------
__global__ __launch_bounds__(256) void rank_kernel(
    const unsigned long long* __restrict__ keys, const float* __restrict__ ssc,
    int n, int k, int* __restrict__ perm, float* __restrict__ vals,
    int* __restrict__ inv) {
    __shared__ unsigned long long sk[NN];
    int b = blockIdx.y;
    for (int i = threadIdx.x; i < NN; i += 256)
        sk[i] = (i < n) ? keys[(size_t)b * NN + i] : ~0ULL;
    __syncthreads();
    int i = blockIdx.x * 256 + threadIdx.x;
    unsigned long long my = sk[i];
    int rank = 0;
#pragma unroll 8
    for (int j = 0; j < NN; j++) rank += (sk[j] < my) ? 1 : 0;
    if (i < n) {
        if (rank < k) {
            perm[b * NN + rank] = i;
            vals[b * NN + rank] = ssc[(size_t)b * NN + i];
            inv[b * NN + i] = rank;
        } else {
            inv[b * NN + i] = -1;
        }
    }
}

// ---------------- fused gather*score + readout partials (high-TLP) ----------------
__global__ __launch_bounds__(128) void gather_part_kernel(
    const float* __restrict__ hin, float* __restrict__ xout,
    const int* __restrict__ perm, const float* __restrict__ vals, int k,
    float* __restrict__ part) {
    int b = blockIdx.x >> 7;                 // PARTS=128 splits per graph
    int j = blockIdx.x & (PARTS - 1);
    int f = threadIdx.x;
    float mx = -INFINITY, sm = 0.f;
    for (int i = j; i < k; i += PARTS) {
        int pi = perm[b * NN + i];
        float v = vals[b * NN + i];
        float hv = hin[((size_t)b * NN + pi) * HH + f] * v;
        xout[((size_t)b * NN + i) * HH + f] = hv;
        mx = fmaxf(mx, hv);
        sm += hv;
    }
    part[(size_t)blockIdx.x * 256 + f] = mx;
    part[(size_t)blockIdx.x * 256 + 128 + f] = sm;
}

// ---------------- edge remap through inv + degree count for next CSR ----------------
__global__ void remap_count_kernel(const int* __restrict__ inv,
                                   const int* __restrict__ sin_,
                                   const int* __restrict__ din_,
                                   int in_stride,
                                   int* __restrict__ sout, int* __restrict__ dout,
                                   int* __restrict__ deg) {
    int t = blockIdx.x * blockDim.x + threadIdx.x;   // B*E
    int e = t & (EE - 1);
    int b = t >> 15;
    if (b >= BB) return;
    int s = sin_[(size_t)b * in_stride + e];
    int d = din_[(size_t)b * in_stride + e];
    int ns = -1, nd = -1;
    if (s >= 0 && d >= 0) {
        ns = inv[b * NN + s];
        nd = inv[b * NN + d];
    }
    if (ns < 0 || nd < 0) { ns = -1; nd = -1; }
    sout[b * EE + e] = ns;
    dout[b * EE + e] = nd;
    if (nd >= 0) atomicAdd(&deg[b * NN + nd], 1);
}

// ---------------- final: combine partials (3 layers) + MLP ----------------
__global__ __launch_bounds__(256) void mlp_kernel(
    const float* __restrict__ part1, const float* __restrict__ part2,
    const float* __restrict__ part3,
    const float* __restrict__ W1, const float* __restrict__ b1,
    const float* __restrict__ W2, const float* __restrict__ b2,
    const float* __restrict__ W3, const float* __restrict__ b3,
    float* __restrict__ out) {
    __shared__ float sg[256];
    __shared__ float s1[128];
    __shared__ float s2[64];
    int b = blockIdx.x, tid = threadIdx.x;
    const float* parts[3] = {part1, part2, part3};
    const float kk[3] = {(float)KK1, (float)KK2, (float)KK3};
    float acc = 0.f;
    if (tid < 128) {
#pragma unroll
        for (int l = 0; l < 3; l++) {
            float mx = -INFINITY;
            for (int j = 0; j < PARTS; j++)
                mx = fmaxf(mx, parts[l][((size_t)b * PARTS + j) * 256 + tid]);
            acc += mx;
        }
    } else {
        int f = tid - 128;
#pragma unroll
        for (int l = 0; l < 3; l++) {
            float sm = 0.f;
            for (int j = 0; j < PARTS; j++)
                sm += parts[l][((size_t)b * PARTS + j) * 256 + 128 + f];
            acc += sm / kk[l];
        }
    }
    sg[tid] = acc;
    __syncthreads();
    if (tid < 128) {
        float a = b1[tid];
        for (int j = 0; j < 256; j++) a += sg[j] * W1[tid * 256 + j];
        s1[tid] = fmaxf(a, 0.f);
    }
    __syncthreads();
    if (tid < 64) {
        float a = b2[tid];
        for (int j = 0; j < 128; j++) a += s1[j] * W2[tid * 128 + j];
        s2[tid] = fmaxf(a, 0.f);
    }
    __syncthreads();
    if (tid == 0) {
        float a = b3[0];
        for (int j = 0; j < 64; j++) a += s2[j] * W3[j];
        out[b] = 1.f / (1.f + expf(-a));
    }
}

extern "C" void kernel_launch(void* const* d_in, const int* in_sizes, int n_in,
                              void* d_out, int out_size, void* d_ws, size_t ws_size,
                              hipStream_t stream) {
    const float* x   = (const float*)d_in[0];
    const int*   ei  = (const int*)d_in[1];
    const float* Wr1 = (const float*)d_in[2];
    const float* Wl1 = (const float*)d_in[3];
    const float* b1  = (const float*)d_in[4];
    const float* p1  = (const float*)d_in[5];
    const float* Wr2 = (const float*)d_in[6];
    const float* Wl2 = (const float*)d_in[7];
    const float* b2  = (const float*)d_in[8];
    const float* p2  = (const float*)d_in[9];
    const float* Wr3 = (const float*)d_in[10];
    const float* Wl3 = (const float*)d_in[11];
    const float* b3  = (const float*)d_in[12];
    const float* p3  = (const float*)d_in[13];
    const float* l1W = (const float*)d_in[14];
    const float* l1b = (const float*)d_in[15];
    const float* l2W = (const float*)d_in[16];
    const float* l2b = (const float*)d_in[17];
    const float* l3W = (const float*)d_in[18];
    const float* l3b = (const float*)d_in[19];
    float* out = (float*)d_out;

    char* ws = (char*)d_ws;
    float* bufA = (float*)ws; ws += (size_t)BB * NN * HH * 4;
    float* bufB = (float*)ws; ws += (size_t)BB * NN * HH * 4;
    float* agg  = (float*)ws; ws += (size_t)BB * NN * HH * 4;
    int*   perm = (int*)ws;   ws += (size_t)BB * NN * 4;
    float* vals = (float*)ws; ws += (size_t)BB * NN * 4;
    int*   inv  = (int*)ws;   ws += (size_t)BB * NN * 4;
    int*   curS = (int*)ws;   ws += (size_t)BB * EE * 4;
    int*   curD = (int*)ws;   ws += (size_t)BB * EE * 4;
    float* part1 = (float*)ws; ws += (size_t)BB * PARTS * 256 * 4;
    float* part2 = (float*)ws; ws += (size_t)BB * PARTS * 256 * 4;
    float* part3 = (float*)ws; ws += (size_t)BB * PARTS * 256 * 4;
    int*   deg  = (int*)ws;   ws += (size_t)BB * NN * 4;
    int*   rowptr = (int*)ws; ws += (size_t)BB * (NN + 1) * 4;
    int*   cursor = (int*)ws; ws += (size_t)BB * (NN + 1) * 4;
    unsigned long long* keys = (unsigned long long*)ws; ws += (size_t)BB * NN * 8;
    float* ssc  = (float*)ws; ws += (size_t)BB * NN * 4;
    // CSR source array lives in bufA: per layer, CSR build + aggregation finish
    // BEFORE conv writes bufA, and CSR is dead afterwards.
    int*   csr = (int*)bufA;

    // ---------- layer 1 ----------
    hipMemsetAsync(deg, 0, (size_t)BB * NN * 4, stream);
    hipLaunchKernelGGL(csr_count_kernel, dim3(BB * EE / 256), dim3(256), 0, stream, ei + EE, 2 * EE, deg);
    hipLaunchKernelGGL(csr_scan_kernel, dim3(BB), dim3(1024), 0, stream, deg, rowptr, cursor);
    hipLaunchKernelGGL(csr_fill_kernel, dim3(BB * EE / 256), dim3(256), 0, stream, ei, ei + EE, 2 * EE, cursor, csr);
    hipLaunchKernelGGL(agg1_csr_kernel, dim3(NN / 8, BB), dim3(256), 0, stream, x, rowptr, csr, agg);
    hipLaunchKernelGGL((conv_fused_kernel<FIN>), dim3(NN / 32, BB), dim3(256), 0, stream,
                       x, agg, Wr1, Wl1, b1, p1, bufA, keys, ssc, NN);
    hipLaunchKernelGGL(rank_kernel, dim3(NN / 256, BB), dim3(256), 0, stream, keys, ssc, NN, KK1, perm, vals, inv);
    hipLaunchKernelGGL(gather_part_kernel, dim3(BB * PARTS), dim3(128), 0, stream, bufA, bufB, perm, vals, KK1, part1);
    hipLaunchKernelGGL(remap_count_kernel, dim3(BB * EE / 256), dim3(256), 0, stream, inv, ei, ei + EE, 2 * EE, curS, curD, deg);

    // ---------- layer 2 ----------
    hipLaunchKernelGGL(csr_scan_kernel, dim3(BB), dim3(1024), 0, stream, deg, rowptr, cursor);
    hipLaunchKernelGGL(csr_fill_kernel, dim3(BB * EE / 256), dim3(256), 0, stream, curS, curD, EE, cursor, csr);
    hipLaunchKernelGGL(agg23_csr_kernel, dim3((KK1 + 3) / 4, BB), dim3(128), 0, stream, bufB, rowptr, csr, agg, KK1);
    hipLaunchKernelGGL((conv_fused_kernel<HH>), dim3((KK1 + 31) / 32, BB), dim3(256), 0, stream,
                       bufB, agg, Wr2, Wl2, b2, p2, bufA, keys, ssc, KK1);
    hipLaunchKernelGGL(rank_kernel, dim3(NN / 256, BB), dim3(256), 0, stream, keys, ssc, KK1, KK2, perm, vals, inv);
    hipLaunchKernelGGL(gather_part_kernel, dim3(BB * PARTS), dim3(128), 0, stream, bufA, bufB, perm, vals, KK2, part2);
    hipLaunchKernelGGL(remap_count_kernel, dim3(BB * EE / 256), dim3(256), 0, stream, inv, curS, curD, EE, curS, curD, deg);

    // ---------- layer 3 ----------
    hipLaunchKernelGGL(csr_scan_kernel, dim3(BB), dim3(1024), 0, stream, deg, rowptr, cursor);
    hipLaunchKernelGGL(csr_fill_kernel, dim3(BB * EE / 256), dim3(256), 0, stream, curS, curD, EE, cursor, csr);
    hipLaunchKernelGGL(agg23_csr_kernel, dim3((KK2 + 3) / 4, BB), dim3(128), 0, stream, bufB, rowptr, csr, agg, KK2);
    hipLaunchKernelGGL((conv_fused_kernel<HH>), dim3((KK2 + 31) / 32, BB), dim3(256), 0, stream,
                       bufB, agg, Wr3, Wl3, b3, p3, bufA, keys, ssc, KK2);
    hipLaunchKernelGGL(rank_kernel, dim3(NN / 256, BB), dim3(256), 0, stream, keys, ssc, KK2, KK3, perm, vals, inv);
    hipLaunchKernelGGL(gather_part_kernel, dim3(BB * PARTS), dim3(128), 0, stream, bufA, bufB, perm, vals, KK3, part3);

    // ---------- final: combine readouts + MLP ----------
    hipLaunchKernelGGL(mlp_kernel, dim3(BB), dim3(256), 0, stream,
                       part1, part2, part3, l1W, l1b, l2W, l2b, l3W, l3b, out);
}

// Round 7
// 445.548 us; speedup vs baseline: 1.2750x; 1.1267x over previous
//
#include <hip/hip_runtime.h>
#include <cstdint>
#include <math.h>

#define BB 16
#define NN 2048
#define EE 32768
#define FIN 32
#define HH 128
#define KK1 1639
#define KK2 1312
#define KK3 1050
#define PARTS 128
#define PGRP 8            // combined groups per graph/layer
#define JPG (PARTS / PGRP)

// ---------------- layer-1 CSR count: incoming edges per dst ----------------
__global__ void csr_count_kernel(const int* __restrict__ dsts, int stride,
                                 int* __restrict__ deg) {
    int t = blockIdx.x * blockDim.x + threadIdx.x;   // B*E
    int e = t & (EE - 1);
    int b = t >> 15;
    if (b >= BB) return;
    int d = dsts[(size_t)b * stride + e];
    if (d >= 0) atomicAdd(&deg[b * NN + d], 1);
}

// ---------------- CSR scan (shfl) + self-zero deg for next layer ----------------
__global__ __launch_bounds__(1024) void csr_scan_kernel(
    int* __restrict__ deg, int* __restrict__ rowptr, int* __restrict__ cursor) {
    __shared__ int wsum[16];
    int b = blockIdx.x, t = threadIdx.x;
    int d0 = deg[b * NN + 2 * t];
    int d1 = deg[b * NN + 2 * t + 1];
    deg[b * NN + 2 * t] = 0;                 // zero for next layer's counting
    deg[b * NN + 2 * t + 1] = 0;
    int s = d0 + d1;
    int lane = t & 63;
    int v = s;
#pragma unroll
    for (int off = 1; off < 64; off <<= 1) {
        int u = __shfl_up(v, off);
        if (lane >= off) v += u;
    }
    if (lane == 63) wsum[t >> 6] = v;
    __syncthreads();
    int w = t >> 6;
    int woff = 0;
#pragma unroll
    for (int i = 0; i < 16; i++) woff += (i < w) ? wsum[i] : 0;
    int excl = woff + v - s;
    int base = b * (NN + 1);
    if (t == 0) { rowptr[base] = 0; cursor[base] = 0; }
    int p0 = excl + d0, p1 = excl + d0 + d1;
    rowptr[base + 2 * t + 1] = p0; cursor[base + 2 * t + 1] = p0;
    rowptr[base + 2 * t + 2] = p1; cursor[base + 2 * t + 2] = p1;
}

// ---------------- CSR fill: scatter source ids ----------------
__global__ void csr_fill_kernel(const int* __restrict__ srcs,
                                const int* __restrict__ dsts, int stride,
                                int* __restrict__ cursor, int* __restrict__ csr) {
    int t = blockIdx.x * blockDim.x + threadIdx.x;   // B*E
    int e = t & (EE - 1);
    int b = t >> 15;
    if (b >= BB) return;
    int s = srcs[(size_t)b * stride + e];
    int d = dsts[(size_t)b * stride + e];
    if (s >= 0 && d >= 0) {
        int pos = atomicAdd(&cursor[b * (NN + 1) + d], 1);
        csr[(size_t)b * EE + pos] = s;
    }
}

// ---------------- pull aggregation, F=32 (layer 1) ----------------
__global__ __launch_bounds__(256) void agg1_csr_kernel(
    const float* __restrict__ x, const int* __restrict__ rowptr,
    const int* __restrict__ csr, float* __restrict__ agg) {
    int b = blockIdx.y;
    int g = threadIdx.x >> 5, lane = threadIdx.x & 31;
    int node = blockIdx.x * 8 + g;
    int beg = rowptr[b * (NN + 1) + node];
    int end = rowptr[b * (NN + 1) + node + 1];
    float acc = 0.f;
    for (int j = beg; j < end; j++) {
        int s = csr[(size_t)b * EE + j];
        acc += x[((size_t)b * NN + s) * FIN + lane];
    }
    agg[((size_t)b * NN + node) * FIN + lane] = acc;
}

// ---------------- pull aggregation, F=128 (layers 2/3) ----------------
__global__ __launch_bounds__(128) void agg23_csr_kernel(
    const float* __restrict__ x, const int* __restrict__ rowptr,
    const int* __restrict__ csr, float* __restrict__ agg, int n) {
    int b = blockIdx.y;
    int tid = threadIdx.x;
#pragma unroll
    for (int r = 0; r < 4; r++) {
        int node = blockIdx.x * 4 + r;
        if (node >= n) break;
        int beg = rowptr[b * (NN + 1) + node];
        int end = rowptr[b * (NN + 1) + node + 1];
        float acc = 0.f;
        for (int j = beg; j < end; j++) {
            int s = csr[(size_t)b * EE + j];
            acc += x[((size_t)b * NN + s) * HH + tid];
        }
        agg[((size_t)b * NN + node) * HH + tid] = acc;
    }
}

// ---------------- fused conv + score/key ----------------
// 32 rows x 128 cols per block, K-chunk 32; 256 threads, each a 4x4 tile.
template<int FI>
__global__ __launch_bounds__(256) void conv_fused_kernel(
    const float* __restrict__ x, const float* __restrict__ agg,
    const float* __restrict__ Wroot, const float* __restrict__ Wrel,
    const float* __restrict__ bias, const float* __restrict__ p,
    float* __restrict__ h, unsigned long long* __restrict__ keys,
    float* __restrict__ ssc, int n) {
    constexpr int NCH = (2 * FI) / 32;      // K-chunks of 32
    __shared__ float sxt[32][36];           // [j][row]
    __shared__ float swt[32][132];          // [j][col]
    __shared__ float sp[HH];
    __shared__ float snorm;

    int b = blockIdx.y;
    int r0 = blockIdx.x * 32;
    int t = threadIdx.x;

    if (t < HH) sp[t] = p[t];
    __syncthreads();
    if (t < 64) {
        float v = sp[t] * sp[t] + sp[t + 64] * sp[t + 64];
#pragma unroll
        for (int off = 32; off; off >>= 1) v += __shfl_xor(v, off);
        if (t == 0) snorm = sqrtf(v);
    }

    int cg = t & 31;          // col group (4 cols)
    int rg = t >> 5;          // row group (4 rows)
    int c4 = cg * 4;
    int rl = rg * 4;
    int xrow = t >> 3;        // staging: row 0..31
    int xj4 = t & 7;          // staging: j-quad 0..7

    float acc[4][4];
#pragma unroll
    for (int i = 0; i < 4; i++)
#pragma unroll
        for (int j = 0; j < 4; j++) acc[i][j] = 0.f;

    for (int ch = 0; ch < NCH; ch++) {
        int j0 = ch * 32;
        __syncthreads();
        {   // stage x/agg tile (32 rows x 32 j), transposed
            int jj = j0 + xj4 * 4;
            const float* src = (jj < FI)
                ? (x + ((size_t)b * NN + r0 + xrow) * FI + jj)
                : (agg + ((size_t)b * NN + r0 + xrow) * FI + (jj - FI));
            float4 v = *reinterpret_cast<const float4*>(src);
            sxt[xj4 * 4 + 0][xrow] = v.x;
            sxt[xj4 * 4 + 1][xrow] = v.y;
            sxt[xj4 * 4 + 2][xrow] = v.z;
            sxt[xj4 * 4 + 3][xrow] = v.w;
        }
#pragma unroll
        for (int it = 0; it < 4; it++) {    // stage W tile (128 cols x 32 j), transposed
            int idx = t + it * 256;
            int c = idx >> 3;
            int j4 = idx & 7;
            int jj = j0 + j4 * 4;
            const float* src = (jj < FI)
                ? (Wroot + (size_t)c * FI + jj)
                : (Wrel + (size_t)c * FI + (jj - FI));
            float4 v = *reinterpret_cast<const float4*>(src);
            swt[j4 * 4 + 0][c] = v.x;
            swt[j4 * 4 + 1][c] = v.y;
            swt[j4 * 4 + 2][c] = v.z;
            swt[j4 * 4 + 3][c] = v.w;
        }
        __syncthreads();
#pragma unroll 8
        for (int j = 0; j < 32; j++) {
            float4 wv = *reinterpret_cast<const float4*>(&swt[j][c4]);
            float4 xv = *reinterpret_cast<const float4*>(&sxt[j][rl]);
            float xs[4] = {xv.x, xv.y, xv.z, xv.w};
            float wsv[4] = {wv.x, wv.y, wv.z, wv.w};
#pragma unroll
            for (int ri = 0; ri < 4; ri++)
#pragma unroll
                for (int ci = 0; ci < 4; ci++)
                    acc[ri][ci] += xs[ri] * wsv[ci];
        }
    }

    // epilogue: bias + relu + store + fused score
    float4 bv = *reinterpret_cast<const float4*>(bias + c4);
    float pc[4] = {sp[c4], sp[c4 + 1], sp[c4 + 2], sp[c4 + 3]};
    float pr[4];
#pragma unroll
    for (int ri = 0; ri < 4; ri++) {
        int row = r0 + rl + ri;
        float4 hv;
        hv.x = fmaxf(acc[ri][0] + bv.x, 0.f);
        hv.y = fmaxf(acc[ri][1] + bv.y, 0.f);
        hv.z = fmaxf(acc[ri][2] + bv.z, 0.f);
        hv.w = fmaxf(acc[ri][3] + bv.w, 0.f);
        pr[ri] = hv.x * pc[0] + hv.y * pc[1] + hv.z * pc[2] + hv.w * pc[3];
        if (row < n)
            *reinterpret_cast<float4*>(h + ((size_t)b * NN + row) * HH + c4) = hv;
    }
#pragma unroll
    for (int ri = 0; ri < 4; ri++) {
#pragma unroll
        for (int off = 16; off; off >>= 1) pr[ri] += __shfl_xor(pr[ri], off);
    }
    if (cg == 0) {
        float inorm = 1.f / snorm;
#pragma unroll
        for (int ri = 0; ri < 4; ri++) {
            int row = r0 + rl + ri;
            if (row < n) {
                float sc = tanhf(pr[ri] * inorm);
                unsigned u = __float_as_uint(sc);
                u = (u & 0x80000000u) ? ~u : (u ^ 0x80000000u);   // monotone asc
                u = ~u;                                            // -> descending
                keys[(size_t)b * NN + row] = ((unsigned long long)u << 32) | (unsigned)row;
                ssc[(size_t)b * NN + row] = sc;
            }
        }
    }
}

// ---------------- exact rank via all-pairs compare (keys unique; tail in-kernel) ----------------
__global__ __launch_bounds__(256) void rank_kernel(
    const unsigned long long* __restrict__ keys, const float* __restrict__ ssc,
    int n, int k, int* __restrict__ perm, float* __restrict__ vals,
    int* __restrict__ inv) {
    __shared__ unsigned long long sk[NN];
    int b = blockIdx.y;
    for (int i = threadIdx.x; i < NN; i += 256)
        sk[i] = (i < n) ? keys[(size_t)b * NN + i] : ~0ULL;
    __syncthreads();
    int i = blockIdx.x * 256 + threadIdx.x;
    unsigned long long my = sk[i];
    int rank = 0;
#pragma unroll 8
    for (int j = 0; j < NN; j++) rank += (sk[j] < my) ? 1 : 0;
    if (i < n) {
        if (rank < k) {
            perm[b * NN + rank] = i;
            vals[b * NN + rank] = ssc[(size_t)b * NN + i];
            inv[b * NN + i] = rank;
        } else {
            inv[b * NN + i] = -1;
        }
    }
}

// ---------------- fused gather*score + readout partials (high-TLP) ----------------
__global__ __launch_bounds__(128) void gather_part_kernel(
    const float* __restrict__ hin, float* __restrict__ xout,
    const int* __restrict__ perm, const float* __restrict__ vals, int k,
    float* __restrict__ part) {
    int b = blockIdx.x >> 7;                 // PARTS=128 splits per graph
    int j = blockIdx.x & (PARTS - 1);
    int f = threadIdx.x;
    float mx = -INFINITY, sm = 0.f;
    for (int i = j; i < k; i += PARTS) {
        int pi = perm[b * NN + i];
        float v = vals[b * NN + i];
        float hv = hin[((size_t)b * NN + pi) * HH + f] * v;
        xout[((size_t)b * NN + i) * HH + f] = hv;
        mx = fmaxf(mx, hv);
        sm += hv;
    }
    part[(size_t)blockIdx.x * 256 + f] = mx;
    part[(size_t)blockIdx.x * 256 + 128 + f] = sm;
}

// ---------------- hierarchical combine: [3][BB][PARTS][256] -> [3][BB][PGRP][256] ----------------
__global__ __launch_bounds__(256) void combine_kernel(
    const float* __restrict__ partAll, float* __restrict__ partG) {
    int blk = blockIdx.x;            // l*BB*PGRP + b*PGRP + g
    int g = blk % PGRP;
    int rem = blk / PGRP;
    int b = rem & 15;
    int l = rem >> 4;
    int f = threadIdx.x;
    const float* src = partAll + ((((size_t)l * BB + b) * PARTS) + (size_t)g * JPG) * 256;
    float r;
    if (f < 128) {
        r = -INFINITY;
#pragma unroll
        for (int j = 0; j < JPG; j++) r = fmaxf(r, src[j * 256 + f]);
    } else {
        r = 0.f;
#pragma unroll
        for (int j = 0; j < JPG; j++) r += src[j * 256 + f];
    }
    partG[(((size_t)l * BB + b) * PGRP + g) * 256 + f] = r;
}

// ---------------- final: combine group partials (3 layers) + MLP ----------------
__global__ __launch_bounds__(256) void mlp_kernel(
    const float* __restrict__ partG,
    const float* __restrict__ W1, const float* __restrict__ b1,
    const float* __restrict__ W2, const float* __restrict__ b2,
    const float* __restrict__ W3, const float* __restrict__ b3,
    float* __restrict__ out) {
    __shared__ float sg[256];
    __shared__ float s1[128];
    __shared__ float s2[64];
    int b = blockIdx.x, tid = threadIdx.x;
    const float kk[3] = {(float)KK1, (float)KK2, (float)KK3};
    float acc = 0.f;
    if (tid < 128) {
#pragma unroll
        for (int l = 0; l < 3; l++) {
            float mx = -INFINITY;
#pragma unroll
            for (int j = 0; j < PGRP; j++)
                mx = fmaxf(mx, partG[(((size_t)l * BB + b) * PGRP + j) * 256 + tid]);
            acc += mx;
        }
    } else {
#pragma unroll
        for (int l = 0; l < 3; l++) {
            float sm = 0.f;
#pragma unroll
            for (int j = 0; j < PGRP; j++)
                sm += partG[(((size_t)l * BB + b) * PGRP + j) * 256 + tid];
            acc += sm / kk[l];
        }
    }
    sg[tid] = acc;
    __syncthreads();
    if (tid < 128) {
        float a = b1[tid];
        for (int j = 0; j < 256; j++) a += sg[j] * W1[tid * 256 + j];
        s1[tid] = fmaxf(a, 0.f);
    }
    __syncthreads();
    if (tid < 64) {
        float a = b2[tid];
        for (int j = 0; j < 128; j++) a += s1[j] * W2[tid * 128 + j];
        s2[tid] = fmaxf(a, 0.f);
    }
    __syncthreads();
    if (tid == 0) {
        float a = b3[0];
        for (int j = 0; j < 64; j++) a += s2[j] * W3[j];
        out[b] = 1.f / (1.f + expf(-a));
    }
}

// ---------------- edge remap through inv + degree count for next CSR ----------------
__global__ void remap_count_kernel(const int* __restrict__ inv,
                                   const int* __restrict__ sin_,
                                   const int* __restrict__ din_,
                                   int in_stride,
                                   int* __restrict__ sout, int* __restrict__ dout,
                                   int* __restrict__ deg) {
    int t = blockIdx.x * blockDim.x + threadIdx.x;   // B*E
    int e = t & (EE - 1);
    int b = t >> 15;
    if (b >= BB) return;
    int s = sin_[(size_t)b * in_stride + e];
    int d = din_[(size_t)b * in_stride + e];
    int ns = -1, nd = -1;
    if (s >= 0 && d >= 0) {
        ns = inv[b * NN + s];
        nd = inv[b * NN + d];
    }
    if (ns < 0 || nd < 0) { ns = -1; nd = -1; }
    sout[b * EE + e] = ns;
    dout[b * EE + e] = nd;
    if (nd >= 0) atomicAdd(&deg[b * NN + nd], 1);
}

extern "C" void kernel_launch(void* const* d_in, const int* in_sizes, int n_in,
                              void* d_out, int out_size, void* d_ws, size_t ws_size,
                              hipStream_t stream) {
    const float* x   = (const float*)d_in[0];
    const int*   ei  = (const int*)d_in[1];
    const float* Wr1 = (const float*)d_in[2];
    const float* Wl1 = (const float*)d_in[3];
    const float* b1  = (const float*)d_in[4];
    const float* p1  = (const float*)d_in[5];
    const float* Wr2 = (const float*)d_in[6];
    const float* Wl2 = (const float*)d_in[7];
    const float* b2  = (const float*)d_in[8];
    const float* p2  = (const float*)d_in[9];
    const float* Wr3 = (const float*)d_in[10];
    const float* Wl3 = (const float*)d_in[11];
    const float* b3  = (const float*)d_in[12];
    const float* p3  = (const float*)d_in[13];
    const float* l1W = (const float*)d_in[14];
    const float* l1b = (const float*)d_in[15];
    const float* l2W = (const float*)d_in[16];
    const float* l2b = (const float*)d_in[17];
    const float* l3W = (const float*)d_in[18];
    const float* l3b = (const float*)d_in[19];
    float* out = (float*)d_out;

    char* ws = (char*)d_ws;
    float* bufA = (float*)ws; ws += (size_t)BB * NN * HH * 4;
    float* bufB = (float*)ws; ws += (size_t)BB * NN * HH * 4;
    float* agg  = (float*)ws; ws += (size_t)BB * NN * HH * 4;
    int*   perm = (int*)ws;   ws += (size_t)BB * NN * 4;
    float* vals = (float*)ws; ws += (size_t)BB * NN * 4;
    int*   inv  = (int*)ws;   ws += (size_t)BB * NN * 4;
    int*   curS = (int*)ws;   ws += (size_t)BB * EE * 4;
    int*   curD = (int*)ws;   ws += (size_t)BB * EE * 4;
    float* partAll = (float*)ws; ws += (size_t)3 * BB * PARTS * 256 * 4;
    float* partG   = (float*)ws; ws += (size_t)3 * BB * PGRP * 256 * 4;
    int*   deg  = (int*)ws;   ws += (size_t)BB * NN * 4;
    int*   rowptr = (int*)ws; ws += (size_t)BB * (NN + 1) * 4;
    int*   cursor = (int*)ws; ws += (size_t)BB * (NN + 1) * 4;
    unsigned long long* keys = (unsigned long long*)ws; ws += (size_t)BB * NN * 8;
    float* ssc  = (float*)ws; ws += (size_t)BB * NN * 4;
    // CSR source array lives in bufA: per layer, CSR build + aggregation finish
    // BEFORE conv writes bufA, and CSR is dead afterwards.
    int*   csr = (int*)bufA;
    float* part1 = partAll;
    float* part2 = partAll + (size_t)BB * PARTS * 256;
    float* part3 = partAll + (size_t)2 * BB * PARTS * 256;

    // ---------- layer 1 ----------
    hipMemsetAsync(deg, 0, (size_t)BB * NN * 4, stream);
    hipLaunchKernelGGL(csr_count_kernel, dim3(BB * EE / 256), dim3(256), 0, stream, ei + EE, 2 * EE, deg);
    hipLaunchKernelGGL(csr_scan_kernel, dim3(BB), dim3(1024), 0, stream, deg, rowptr, cursor);
    hipLaunchKernelGGL(csr_fill_kernel, dim3(BB * EE / 256), dim3(256), 0, stream, ei, ei + EE, 2 * EE, cursor, csr);
    hipLaunchKernelGGL(agg1_csr_kernel, dim3(NN / 8, BB), dim3(256), 0, stream, x, rowptr, csr, agg);
    hipLaunchKernelGGL((conv_fused_kernel<FIN>), dim3(NN / 32, BB), dim3(256), 0, stream,
                       x, agg, Wr1, Wl1, b1, p1, bufA, keys, ssc, NN);
    hipLaunchKernelGGL(rank_kernel, dim3(NN / 256, BB), dim3(256), 0, stream, keys, ssc, NN, KK1, perm, vals, inv);
    hipLaunchKernelGGL(gather_part_kernel, dim3(BB * PARTS), dim3(128), 0, stream, bufA, bufB, perm, vals, KK1, part1);
    hipLaunchKernelGGL(remap_count_kernel, dim3(BB * EE / 256), dim3(256), 0, stream, inv, ei, ei + EE, 2 * EE, curS, curD, deg);

    // ---------- layer 2 ----------
    hipLaunchKernelGGL(csr_scan_kernel, dim3(BB), dim3(1024), 0, stream, deg, rowptr, cursor);
    hipLaunchKernelGGL(csr_fill_kernel, dim3(BB * EE / 256), dim3(256), 0, stream, curS, curD, EE, cursor, csr);
    hipLaunchKernelGGL(agg23_csr_kernel, dim3((KK1 + 3) / 4, BB), dim3(128), 0, stream, bufB, rowptr, csr, agg, KK1);
    hipLaunchKernelGGL((conv_fused_kernel<HH>), dim3((KK1 + 31) / 32, BB), dim3(256), 0, stream,
                       bufB, agg, Wr2, Wl2, b2, p2, bufA, keys, ssc, KK1);
    hipLaunchKernelGGL(rank_kernel, dim3(NN / 256, BB), dim3(256), 0, stream, keys, ssc, KK1, KK2, perm, vals, inv);
    hipLaunchKernelGGL(gather_part_kernel, dim3(BB * PARTS), dim3(128), 0, stream, bufA, bufB, perm, vals, KK2, part2);
    hipLaunchKernelGGL(remap_count_kernel, dim3(BB * EE / 256), dim3(256), 0, stream, inv, curS, curD, EE, curS, curD, deg);

    // ---------- layer 3 ----------
    hipLaunchKernelGGL(csr_scan_kernel, dim3(BB), dim3(1024), 0, stream, deg, rowptr, cursor);
    hipLaunchKernelGGL(csr_fill_kernel, dim3(BB * EE / 256), dim3(256), 0, stream, curS, curD, EE, cursor, csr);
    hipLaunchKernelGGL(agg23_csr_kernel, dim3((KK2 + 3) / 4, BB), dim3(128), 0, stream, bufB, rowptr, csr, agg, KK2);
    hipLaunchKernelGGL((conv_fused_kernel<HH>), dim3((KK2 + 31) / 32, BB), dim3(256), 0, stream,
                       bufB, agg, Wr3, Wl3, b3, p3, bufA, keys, ssc, KK2);
    hipLaunchKernelGGL(rank_kernel, dim3(NN / 256, BB), dim3(256), 0, stream, keys, ssc, KK2, KK3, perm, vals, inv);
    hipLaunchKernelGGL(gather_part_kernel, dim3(BB * PARTS), dim3(128), 0, stream, bufA, bufB, perm, vals, KK3, part3);

    // ---------- final: hierarchical combine + MLP ----------
    hipLaunchKernelGGL(combine_kernel, dim3(3 * BB * PGRP), dim3(256), 0, stream, partAll, partG);
    hipLaunchKernelGGL(mlp_kernel, dim3(BB), dim3(256), 0, stream,
                       partG, l1W, l1b, l2W, l2b, l3W, l3b, out);
}

// Round 8
// 429.303 us; speedup vs baseline: 1.3233x; 1.0378x over previous
//
#include <hip/hip_runtime.h>
#include <cstdint>
#include <math.h>

#define BB 16
#define NN 2048
#define EE 32768
#define FIN 32
#define HH 128
#define KK1 1639
#define KK2 1312
#define KK3 1050
#define PARTS 128
#define PGRP 8            // combined groups per graph/layer
#define JPG (PARTS / PGRP)

using f16x8 = __attribute__((ext_vector_type(8))) _Float16;
using f32x4 = __attribute__((ext_vector_type(4))) float;

// ---------------- layer-1 CSR count: incoming edges per dst ----------------
__global__ void csr_count_kernel(const int* __restrict__ dsts, int stride,
                                 int* __restrict__ deg) {
    int t = blockIdx.x * blockDim.x + threadIdx.x;   // B*E
    int e = t & (EE - 1);
    int b = t >> 15;
    if (b >= BB) return;
    int d = dsts[(size_t)b * stride + e];
    if (d >= 0) atomicAdd(&deg[b * NN + d], 1);
}

// ---------------- CSR scan (shfl) + self-zero deg for next layer ----------------
__global__ __launch_bounds__(1024) void csr_scan_kernel(
    int* __restrict__ deg, int* __restrict__ rowptr, int* __restrict__ cursor) {
    __shared__ int wsum[16];
    int b = blockIdx.x, t = threadIdx.x;
    int d0 = deg[b * NN + 2 * t];
    int d1 = deg[b * NN + 2 * t + 1];
    deg[b * NN + 2 * t] = 0;                 // zero for next layer's counting
    deg[b * NN + 2 * t + 1] = 0;
    int s = d0 + d1;
    int lane = t & 63;
    int v = s;
#pragma unroll
    for (int off = 1; off < 64; off <<= 1) {
        int u = __shfl_up(v, off);
        if (lane >= off) v += u;
    }
    if (lane == 63) wsum[t >> 6] = v;
    __syncthreads();
    int w = t >> 6;
    int woff = 0;
#pragma unroll
    for (int i = 0; i < 16; i++) woff += (i < w) ? wsum[i] : 0;
    int excl = woff + v - s;
    int base = b * (NN + 1);
    if (t == 0) { rowptr[base] = 0; cursor[base] = 0; }
    int p0 = excl + d0, p1 = excl + d0 + d1;
    rowptr[base + 2 * t + 1] = p0; cursor[base + 2 * t + 1] = p0;
    rowptr[base + 2 * t + 2] = p1; cursor[base + 2 * t + 2] = p1;
}

// ---------------- CSR fill: scatter source ids ----------------
__global__ void csr_fill_kernel(const int* __restrict__ srcs,
                                const int* __restrict__ dsts, int stride,
                                int* __restrict__ cursor, int* __restrict__ csr) {
    int t = blockIdx.x * blockDim.x + threadIdx.x;   // B*E
    int e = t & (EE - 1);
    int b = t >> 15;
    if (b >= BB) return;
    int s = srcs[(size_t)b * stride + e];
    int d = dsts[(size_t)b * stride + e];
    if (s >= 0 && d >= 0) {
        int pos = atomicAdd(&cursor[b * (NN + 1) + d], 1);
        csr[(size_t)b * EE + pos] = s;
    }
}

// ---------------- pull aggregation, F=32 (layer 1) ----------------
__global__ __launch_bounds__(256) void agg1_csr_kernel(
    const float* __restrict__ x, const int* __restrict__ rowptr,
    const int* __restrict__ csr, float* __restrict__ agg) {
    int b = blockIdx.y;
    int g = threadIdx.x >> 5, lane = threadIdx.x & 31;
    int node = blockIdx.x * 8 + g;
    int beg = rowptr[b * (NN + 1) + node];
    int end = rowptr[b * (NN + 1) + node + 1];
    float acc = 0.f;
    for (int j = beg; j < end; j++) {
        int s = csr[(size_t)b * EE + j];
        acc += x[((size_t)b * NN + s) * FIN + lane];
    }
    agg[((size_t)b * NN + node) * FIN + lane] = acc;
}

// ---------------- pull aggregation, F=128 (layers 2/3) ----------------
__global__ __launch_bounds__(128) void agg23_csr_kernel(
    const float* __restrict__ x, const int* __restrict__ rowptr,
    const int* __restrict__ csr, float* __restrict__ agg, int n) {
    int b = blockIdx.y;
    int tid = threadIdx.x;
#pragma unroll
    for (int r = 0; r < 4; r++) {
        int node = blockIdx.x * 4 + r;
        if (node >= n) break;
        int beg = rowptr[b * (NN + 1) + node];
        int end = rowptr[b * (NN + 1) + node + 1];
        float acc = 0.f;
        for (int j = beg; j < end; j++) {
            int s = csr[(size_t)b * EE + j];
            acc += x[((size_t)b * NN + s) * HH + tid];
        }
        agg[((size_t)b * NN + node) * HH + tid] = acc;
    }
}

// ---------------- f32 -> f16x8 fragment load (RNE via v_cvt_f16_f32) ----------------
__device__ __forceinline__ f16x8 load_cvt16(const float* src) {
    float4 lo = *reinterpret_cast<const float4*>(src);
    float4 hi = *reinterpret_cast<const float4*>(src + 4);
    f16x8 r;
    r[0] = (_Float16)lo.x; r[1] = (_Float16)lo.y;
    r[2] = (_Float16)lo.z; r[3] = (_Float16)lo.w;
    r[4] = (_Float16)hi.x; r[5] = (_Float16)hi.y;
    r[6] = (_Float16)hi.z; r[7] = (_Float16)hi.w;
    return r;
}

// ---------------- MFMA conv + fused score/key ----------------
// [x|agg] (n x 2FI) @ [Wroot|Wrel]^T (2FI x 128). Block = 32 rows x 128 cols,
// 4 waves, each wave 2x2 tiles of 16x16x32_f16 MFMA. No GEMM LDS staging:
// A/B fragments load 8 contiguous K f32 from global (L1/L2-hot) + cvt to f16.
// A layout: lane holds A[lane%16][ (lane/16)*8 + i ]; B (N x K = W layout) same.
// D layout: col = lane&15, row = (lane>>4)*4 + reg.
template<int FI>
__global__ __launch_bounds__(256) void conv_mfma_kernel(
    const float* __restrict__ x, const float* __restrict__ agg,
    const float* __restrict__ Wroot, const float* __restrict__ Wrel,
    const float* __restrict__ bias, const float* __restrict__ p,
    float* __restrict__ h, unsigned long long* __restrict__ keys,
    float* __restrict__ ssc, int n) {
    __shared__ float spart[4][32];
    __shared__ float snorm_s;
    int b = blockIdx.y;
    int r0 = blockIdx.x * 32;
    int t = threadIdx.x;
    int wv = t >> 6, lane = t & 63;
    int m16 = lane & 15, q = lane >> 4;

    if (t < 64) {
        float v = p[t] * p[t] + p[t + 64] * p[t + 64];
#pragma unroll
        for (int off = 32; off; off >>= 1) v += __shfl_xor(v, off);
        if (t == 0) snorm_s = sqrtf(v);
    }

    f32x4 acc[2][2];
#pragma unroll
    for (int rt = 0; rt < 2; rt++)
#pragma unroll
        for (int ct = 0; ct < 2; ct++) {
            acc[rt][ct][0] = 0.f; acc[rt][ct][1] = 0.f;
            acc[rt][ct][2] = 0.f; acc[rt][ct][3] = 0.f;
        }

    int rowA[2] = { r0 + m16, r0 + 16 + m16 };
    int colB[2] = { wv * 32 + m16, wv * 32 + 16 + m16 };

#pragma unroll
    for (int step = 0; step < (2 * FI) / 32; step++) {
        int k0 = step * 32 + q * 8;
        f16x8 afr[2], bfr[2];
#pragma unroll
        for (int rt = 0; rt < 2; rt++) {
            const float* src = (k0 < FI)
                ? x   + ((size_t)b * NN + rowA[rt]) * FI + k0
                : agg + ((size_t)b * NN + rowA[rt]) * FI + (k0 - FI);
            afr[rt] = load_cvt16(src);
        }
#pragma unroll
        for (int ct = 0; ct < 2; ct++) {
            const float* src = (k0 < FI)
                ? Wroot + (size_t)colB[ct] * FI + k0
                : Wrel  + (size_t)colB[ct] * FI + (k0 - FI);
            bfr[ct] = load_cvt16(src);
        }
#pragma unroll
        for (int rt = 0; rt < 2; rt++)
#pragma unroll
            for (int ct = 0; ct < 2; ct++)
                acc[rt][ct] = __builtin_amdgcn_mfma_f32_16x16x32_f16(
                    afr[rt], bfr[ct], acc[rt][ct], 0, 0, 0);
    }

    // epilogue: bias + relu + store h + score partial over this wave's 32 cols
    float prt[2][4];
#pragma unroll
    for (int rt = 0; rt < 2; rt++)
#pragma unroll
        for (int reg = 0; reg < 4; reg++) prt[rt][reg] = 0.f;

#pragma unroll
    for (int ct = 0; ct < 2; ct++) {
        int col = wv * 32 + ct * 16 + m16;
        float pc = p[col];
        float bv = bias[col];
#pragma unroll
        for (int rt = 0; rt < 2; rt++)
#pragma unroll
            for (int reg = 0; reg < 4; reg++) {
                int row = r0 + rt * 16 + q * 4 + reg;
                float hv = fmaxf(acc[rt][ct][reg] + bv, 0.f);
                if (row < n)
                    h[((size_t)b * NN + row) * HH + col] = hv;
                prt[rt][reg] += hv * pc;
            }
    }
    // reduce over the 16 col-lanes (same q group)
#pragma unroll
    for (int rt = 0; rt < 2; rt++)
#pragma unroll
        for (int reg = 0; reg < 4; reg++) {
            float v = prt[rt][reg];
            v += __shfl_xor(v, 1); v += __shfl_xor(v, 2);
            v += __shfl_xor(v, 4); v += __shfl_xor(v, 8);
            prt[rt][reg] = v;
        }
    if (m16 == 0) {
#pragma unroll
        for (int rt = 0; rt < 2; rt++)
#pragma unroll
            for (int reg = 0; reg < 4; reg++)
                spart[wv][rt * 16 + q * 4 + reg] = prt[rt][reg];
    }
    __syncthreads();
    if (t < 32) {
        int row = r0 + t;
        if (row < n) {
            float s = spart[0][t] + spart[1][t] + spart[2][t] + spart[3][t];
            float sc = tanhf(s / snorm_s);
            unsigned u = __float_as_uint(sc);
            u = (u & 0x80000000u) ? ~u : (u ^ 0x80000000u);   // monotone asc
            u = ~u;                                            // -> descending
            keys[(size_t)b * NN + row] = ((unsigned long long)u << 32) | (unsigned)row;
            ssc[(size_t)b * NN + row] = sc;
        }
    }
}

// ---------------- exact rank via all-pairs compare (keys unique; tail in-kernel) ----------------
__global__ __launch_bounds__(256) void rank_kernel(
    const unsigned long long* __restrict__ keys, const float* __restrict__ ssc,
    int n, int k, int* __restrict__ perm, float* __restrict__ vals,
    int* __restrict__ inv) {
    __shared__ unsigned long long sk[NN];
    int b = blockIdx.y;
    for (int i = threadIdx.x; i < NN; i += 256)
        sk[i] = (i < n) ? keys[(size_t)b * NN + i] : ~0ULL;
    __syncthreads();
    int i = blockIdx.x * 256 + threadIdx.x;
    unsigned long long my = sk[i];
    int rank = 0;
#pragma unroll 8
    for (int j = 0; j < NN; j++) rank += (sk[j] < my) ? 1 : 0;
    if (i < n) {
        if (rank < k) {
            perm[b * NN + rank] = i;
            vals[b * NN + rank] = ssc[(size_t)b * NN + i];
            inv[b * NN + i] = rank;
        } else {
            inv[b * NN + i] = -1;
        }
    }
}

// ---------------- fused gather*score + readout partials (high-TLP) ----------------
__global__ __launch_bounds__(128) void gather_part_kernel(
    const float* __restrict__ hin, float* __restrict__ xout,
    const int* __restrict__ perm, const float* __restrict__ vals, int k,
    float* __restrict__ part) {
    int b = blockIdx.x >> 7;                 // PARTS=128 splits per graph
    int j = blockIdx.x & (PARTS - 1);
    int f = threadIdx.x;
    float mx = -INFINITY, sm = 0.f;
    for (int i = j; i < k; i += PARTS) {
        int pi = perm[b * NN + i];
        float v = vals[b * NN + i];
        float hv = hin[((size_t)b * NN + pi) * HH + f] * v;
        xout[((size_t)b * NN + i) * HH + f] = hv;
        mx = fmaxf(mx, hv);
        sm += hv;
    }
    part[(size_t)blockIdx.x * 256 + f] = mx;
    part[(size_t)blockIdx.x * 256 + 128 + f] = sm;
}

// ---------------- hierarchical combine: [3][BB][PARTS][256] -> [3][BB][PGRP][256] ----------------
__global__ __launch_bounds__(256) void combine_kernel(
    const float* __restrict__ partAll, float* __restrict__ partG) {
    int blk = blockIdx.x;            // l*BB*PGRP + b*PGRP + g
    int g = blk % PGRP;
    int rem = blk / PGRP;
    int b = rem & 15;
    int l = rem >> 4;
    int f = threadIdx.x;
    const float* src = partAll + ((((size_t)l * BB + b) * PARTS) + (size_t)g * JPG) * 256;
    float r;
    if (f < 128) {
        r = -INFINITY;
#pragma unroll
        for (int j = 0; j < JPG; j++) r = fmaxf(r, src[j * 256 + f]);
    } else {
        r = 0.f;
#pragma unroll
        for (int j = 0; j < JPG; j++) r += src[j * 256 + f];
    }
    partG[(((size_t)l * BB + b) * PGRP + g) * 256 + f] = r;
}

// ---------------- final: combine group partials (3 layers) + MLP ----------------
__global__ __launch_bounds__(256) void mlp_kernel(
    const float* __restrict__ partG,
    const float* __restrict__ W1, const float* __restrict__ b1,
    const float* __restrict__ W2, const float* __restrict__ b2,
    const float* __restrict__ W3, const float* __restrict__ b3,
    float* __restrict__ out) {
    __shared__ float sg[256];
    __shared__ float s1[128];
    __shared__ float s2[64];
    int b = blockIdx.x, tid = threadIdx.x;
    const float kk[3] = {(float)KK1, (float)KK2, (float)KK3};
    float acc = 0.f;
    if (tid < 128) {
#pragma unroll
        for (int l = 0; l < 3; l++) {
            float mx = -INFINITY;
#pragma unroll
            for (int j = 0; j < PGRP; j++)
                mx = fmaxf(mx, partG[(((size_t)l * BB + b) * PGRP + j) * 256 + tid]);
            acc += mx;
        }
    } else {
#pragma unroll
        for (int l = 0; l < 3; l++) {
            float sm = 0.f;
#pragma unroll
            for (int j = 0; j < PGRP; j++)
                sm += partG[(((size_t)l * BB + b) * PGRP + j) * 256 + tid];
            acc += sm / kk[l];
        }
    }
    sg[tid] = acc;
    __syncthreads();
    if (tid < 128) {
        float a = b1[tid];
        for (int j = 0; j < 256; j++) a += sg[j] * W1[tid * 256 + j];
        s1[tid] = fmaxf(a, 0.f);
    }
    __syncthreads();
    if (tid < 64) {
        float a = b2[tid];
        for (int j = 0; j < 128; j++) a += s1[j] * W2[tid * 128 + j];
        s2[tid] = fmaxf(a, 0.f);
    }
    __syncthreads();
    if (tid == 0) {
        float a = b3[0];
        for (int j = 0; j < 64; j++) a += s2[j] * W3[j];
        out[b] = 1.f / (1.f + expf(-a));
    }
}

// ---------------- edge remap through inv + degree count for next CSR ----------------
__global__ void remap_count_kernel(const int* __restrict__ inv,
                                   const int* __restrict__ sin_,
                                   const int* __restrict__ din_,
                                   int in_stride,
                                   int* __restrict__ sout, int* __restrict__ dout,
                                   int* __restrict__ deg) {
    int t = blockIdx.x * blockDim.x + threadIdx.x;   // B*E
    int e = t & (EE - 1);
    int b = t >> 15;
    if (b >= BB) return;
    int s = sin_[(size_t)b * in_stride + e];
    int d = din_[(size_t)b * in_stride + e];
    int ns = -1, nd = -1;
    if (s >= 0 && d >= 0) {
        ns = inv[b * NN + s];
        nd = inv[b * NN + d];
    }
    if (ns < 0 || nd < 0) { ns = -1; nd = -1; }
    sout[b * EE + e] = ns;
    dout[b * EE + e] = nd;
    if (nd >= 0) atomicAdd(&deg[b * NN + nd], 1);
}

extern "C" void kernel_launch(void* const* d_in, const int* in_sizes, int n_in,
                              void* d_out, int out_size, void* d_ws, size_t ws_size,
                              hipStream_t stream) {
    const float* x   = (const float*)d_in[0];
    const int*   ei  = (const int*)d_in[1];
    const float* Wr1 = (const float*)d_in[2];
    const float* Wl1 = (const float*)d_in[3];
    const float* b1  = (const float*)d_in[4];
    const float* p1  = (const float*)d_in[5];
    const float* Wr2 = (const float*)d_in[6];
    const float* Wl2 = (const float*)d_in[7];
    const float* b2  = (const float*)d_in[8];
    const float* p2  = (const float*)d_in[9];
    const float* Wr3 = (const float*)d_in[10];
    const float* Wl3 = (const float*)d_in[11];
    const float* b3  = (const float*)d_in[12];
    const float* p3  = (const float*)d_in[13];
    const float* l1W = (const float*)d_in[14];
    const float* l1b = (const float*)d_in[15];
    const float* l2W = (const float*)d_in[16];
    const float* l2b = (const float*)d_in[17];
    const float* l3W = (const float*)d_in[18];
    const float* l3b = (const float*)d_in[19];
    float* out = (float*)d_out;

    char* ws = (char*)d_ws;
    float* bufA = (float*)ws; ws += (size_t)BB * NN * HH * 4;
    float* bufB = (float*)ws; ws += (size_t)BB * NN * HH * 4;
    float* agg  = (float*)ws; ws += (size_t)BB * NN * HH * 4;
    int*   perm = (int*)ws;   ws += (size_t)BB * NN * 4;
    float* vals = (float*)ws; ws += (size_t)BB * NN * 4;
    int*   inv  = (int*)ws;   ws += (size_t)BB * NN * 4;
    int*   curS = (int*)ws;   ws += (size_t)BB * EE * 4;
    int*   curD = (int*)ws;   ws += (size_t)BB * EE * 4;
    float* partAll = (float*)ws; ws += (size_t)3 * BB * PARTS * 256 * 4;
    float* partG   = (float*)ws; ws += (size_t)3 * BB * PGRP * 256 * 4;
    int*   deg  = (int*)ws;   ws += (size_t)BB * NN * 4;
    int*   rowptr = (int*)ws; ws += (size_t)BB * (NN + 1) * 4;
    int*   cursor = (int*)ws; ws += (size_t)BB * (NN + 1) * 4;
    unsigned long long* keys = (unsigned long long*)ws; ws += (size_t)BB * NN * 8;
    float* ssc  = (float*)ws; ws += (size_t)BB * NN * 4;
    // CSR source array lives in bufA: per layer, CSR build + aggregation finish
    // BEFORE conv writes bufA, and CSR is dead afterwards.
    int*   csr = (int*)bufA;
    float* part1 = partAll;
    float* part2 = partAll + (size_t)BB * PARTS * 256;
    float* part3 = partAll + (size_t)2 * BB * PARTS * 256;

    // ---------- layer 1 ----------
    hipMemsetAsync(deg, 0, (size_t)BB * NN * 4, stream);
    hipLaunchKernelGGL(csr_count_kernel, dim3(BB * EE / 256), dim3(256), 0, stream, ei + EE, 2 * EE, deg);
    hipLaunchKernelGGL(csr_scan_kernel, dim3(BB), dim3(1024), 0, stream, deg, rowptr, cursor);
    hipLaunchKernelGGL(csr_fill_kernel, dim3(BB * EE / 256), dim3(256), 0, stream, ei, ei + EE, 2 * EE, cursor, csr);
    hipLaunchKernelGGL(agg1_csr_kernel, dim3(NN / 8, BB), dim3(256), 0, stream, x, rowptr, csr, agg);
    hipLaunchKernelGGL((conv_mfma_kernel<FIN>), dim3(NN / 32, BB), dim3(256), 0, stream,
                       x, agg, Wr1, Wl1, b1, p1, bufA, keys, ssc, NN);
    hipLaunchKernelGGL(rank_kernel, dim3(NN / 256, BB), dim3(256), 0, stream, keys, ssc, NN, KK1, perm, vals, inv);
    hipLaunchKernelGGL(gather_part_kernel, dim3(BB * PARTS), dim3(128), 0, stream, bufA, bufB, perm, vals, KK1, part1);
    hipLaunchKernelGGL(remap_count_kernel, dim3(BB * EE / 256), dim3(256), 0, stream, inv, ei, ei + EE, 2 * EE, curS, curD, deg);

    // ---------- layer 2 ----------
    hipLaunchKernelGGL(csr_scan_kernel, dim3(BB), dim3(1024), 0, stream, deg, rowptr, cursor);
    hipLaunchKernelGGL(csr_fill_kernel, dim3(BB * EE / 256), dim3(256), 0, stream, curS, curD, EE, cursor, csr);
    hipLaunchKernelGGL(agg23_csr_kernel, dim3((KK1 + 3) / 4, BB), dim3(128), 0, stream, bufB, rowptr, csr, agg, KK1);
    hipLaunchKernelGGL((conv_mfma_kernel<HH>), dim3((KK1 + 31) / 32, BB), dim3(256), 0, stream,
                       bufB, agg, Wr2, Wl2, b2, p2, bufA, keys, ssc, KK1);
    hipLaunchKernelGGL(rank_kernel, dim3(NN / 256, BB), dim3(256), 0, stream, keys, ssc, KK1, KK2, perm, vals, inv);
    hipLaunchKernelGGL(gather_part_kernel, dim3(BB * PARTS), dim3(128), 0, stream, bufA, bufB, perm, vals, KK2, part2);
    hipLaunchKernelGGL(remap_count_kernel, dim3(BB * EE / 256), dim3(256), 0, stream, inv, curS, curD, EE, curS, curD, deg);

    // ---------- layer 3 ----------
    hipLaunchKernelGGL(csr_scan_kernel, dim3(BB), dim3(1024), 0, stream, deg, rowptr, cursor);
    hipLaunchKernelGGL(csr_fill_kernel, dim3(BB * EE / 256), dim3(256), 0, stream, curS, curD, EE, cursor, csr);
    hipLaunchKernelGGL(agg23_csr_kernel, dim3((KK2 + 3) / 4, BB), dim3(128), 0, stream, bufB, rowptr, csr, agg, KK2);
    hipLaunchKernelGGL((conv_mfma_kernel<HH>), dim3((KK2 + 31) / 32, BB), dim3(256), 0, stream,
                       bufB, agg, Wr3, Wl3, b3, p3, bufA, keys, ssc, KK2);
    hipLaunchKernelGGL(rank_kernel, dim3(NN / 256, BB), dim3(256), 0, stream, keys, ssc, KK2, KK3, perm, vals, inv);
    hipLaunchKernelGGL(gather_part_kernel, dim3(BB * PARTS), dim3(128), 0, stream, bufA, bufB, perm, vals, KK3, part3);

    // ---------- final: hierarchical combine + MLP ----------
    hipLaunchKernelGGL(combine_kernel, dim3(3 * BB * PGRP), dim3(256), 0, stream, partAll, partG);
    hipLaunchKernelGGL(mlp_kernel, dim3(BB), dim3(256), 0, stream,
                       partG, l1W, l1b, l2W, l2b, l3W, l3b, out);
}

// Round 9
// 371.614 us; speedup vs baseline: 1.5287x; 1.1552x over previous
//
#include <hip/hip_runtime.h>
#include <cstdint>
#include <math.h>

#define BB 16
#define NN 2048
#define EE 32768
#define FIN 32
#define HH 128
#define KK1 1639
#define KK2 1312
#define KK3 1050
#define PARTS 128
#define PGRP 8            // combined groups per graph/layer
#define JPG (PARTS / PGRP)

using f16x8 = __attribute__((ext_vector_type(8))) _Float16;
using f32x4 = __attribute__((ext_vector_type(4))) float;

// ---------------- layer-1 CSR count: incoming edges per dst ----------------
__global__ void csr_count_kernel(const int* __restrict__ dsts, int stride,
                                 int* __restrict__ deg) {
    int t = blockIdx.x * blockDim.x + threadIdx.x;   // B*E
    int e = t & (EE - 1);
    int b = t >> 15;
    if (b >= BB) return;
    int d = dsts[(size_t)b * stride + e];
    if (d >= 0) atomicAdd(&deg[b * NN + d], 1);
}

// ---------------- CSR scan (shfl) + self-zero deg for next layer ----------------
__global__ __launch_bounds__(1024) void csr_scan_kernel(
    int* __restrict__ deg, int* __restrict__ rowptr, int* __restrict__ cursor) {
    __shared__ int wsum[16];
    int b = blockIdx.x, t = threadIdx.x;
    int d0 = deg[b * NN + 2 * t];
    int d1 = deg[b * NN + 2 * t + 1];
    deg[b * NN + 2 * t] = 0;                 // zero for next layer's counting
    deg[b * NN + 2 * t + 1] = 0;
    int s = d0 + d1;
    int lane = t & 63;
    int v = s;
#pragma unroll
    for (int off = 1; off < 64; off <<= 1) {
        int u = __shfl_up(v, off);
        if (lane >= off) v += u;
    }
    if (lane == 63) wsum[t >> 6] = v;
    __syncthreads();
    int w = t >> 6;
    int woff = 0;
#pragma unroll
    for (int i = 0; i < 16; i++) woff += (i < w) ? wsum[i] : 0;
    int excl = woff + v - s;
    int base = b * (NN + 1);
    if (t == 0) { rowptr[base] = 0; cursor[base] = 0; }
    int p0 = excl + d0, p1 = excl + d0 + d1;
    rowptr[base + 2 * t + 1] = p0; cursor[base + 2 * t + 1] = p0;
    rowptr[base + 2 * t + 2] = p1; cursor[base + 2 * t + 2] = p1;
}

// ---------------- CSR fill: scatter source ids ----------------
__global__ void csr_fill_kernel(const int* __restrict__ srcs,
                                const int* __restrict__ dsts, int stride,
                                int* __restrict__ cursor, int* __restrict__ csr) {
    int t = blockIdx.x * blockDim.x + threadIdx.x;   // B*E
    int e = t & (EE - 1);
    int b = t >> 15;
    if (b >= BB) return;
    int s = srcs[(size_t)b * stride + e];
    int d = dsts[(size_t)b * stride + e];
    if (s >= 0 && d >= 0) {
        int pos = atomicAdd(&cursor[b * (NN + 1) + d], 1);
        csr[(size_t)b * EE + pos] = s;
    }
}

// ---------------- pull aggregation, F=32 (layer 1), batched index prefetch ----------------
__global__ __launch_bounds__(256) void agg1_csr_kernel(
    const float* __restrict__ x, const int* __restrict__ rowptr,
    const int* __restrict__ csr, float* __restrict__ agg) {
    int b = blockIdx.y;
    int g = threadIdx.x >> 5, lane = threadIdx.x & 31;
    int node = blockIdx.x * 8 + g;
    int beg = rowptr[b * (NN + 1) + node];
    int end = rowptr[b * (NN + 1) + node + 1];
    float acc = 0.f;
    for (int base = beg; base < end; base += 8) {
        int m = end - base; if (m > 8) m = 8;
        int idx[8];
#pragma unroll
        for (int u = 0; u < 8; u++)
            idx[u] = csr[(size_t)b * EE + base + ((u < m) ? u : 0)];
#pragma unroll
        for (int u = 0; u < 8; u++)
            if (u < m) acc += x[((size_t)b * NN + idx[u]) * FIN + lane];
    }
    agg[((size_t)b * NN + node) * FIN + lane] = acc;
}

// ---------------- pull aggregation, F=128 (layers 2/3), batched index prefetch ----------------
__global__ __launch_bounds__(128) void agg23_csr_kernel(
    const float* __restrict__ x, const int* __restrict__ rowptr,
    const int* __restrict__ csr, float* __restrict__ agg, int n) {
    int b = blockIdx.y;
    int tid = threadIdx.x;
#pragma unroll
    for (int r = 0; r < 4; r++) {
        int node = blockIdx.x * 4 + r;
        if (node >= n) break;
        int beg = rowptr[b * (NN + 1) + node];
        int end = rowptr[b * (NN + 1) + node + 1];
        float acc = 0.f;
        for (int base = beg; base < end; base += 8) {
            int m = end - base; if (m > 8) m = 8;
            int idx[8];
#pragma unroll
            for (int u = 0; u < 8; u++)
                idx[u] = csr[(size_t)b * EE + base + ((u < m) ? u : 0)];
#pragma unroll
            for (int u = 0; u < 8; u++)
                if (u < m) acc += x[((size_t)b * NN + idx[u]) * HH + tid];
        }
        agg[((size_t)b * NN + node) * HH + tid] = acc;
    }
}

// ---------------- f32 -> f16x8 fragment load (RNE via v_cvt_f16_f32) ----------------
__device__ __forceinline__ f16x8 load_cvt16(const float* src) {
    float4 lo = *reinterpret_cast<const float4*>(src);
    float4 hi = *reinterpret_cast<const float4*>(src + 4);
    f16x8 r;
    r[0] = (_Float16)lo.x; r[1] = (_Float16)lo.y;
    r[2] = (_Float16)lo.z; r[3] = (_Float16)lo.w;
    r[4] = (_Float16)hi.x; r[5] = (_Float16)hi.y;
    r[6] = (_Float16)hi.z; r[7] = (_Float16)hi.w;
    return r;
}

// ---------------- MFMA conv + fused score/key ----------------
// Block = 32 rows x 128 cols, 4 waves, each wave 2x2 tiles of 16x16x32_f16.
// A layout: lane holds A[lane%16][(lane/16)*8 + i]; B (W layout) same.
// D layout: col = lane&15, row = (lane>>4)*4 + reg.
template<int FI>
__global__ __launch_bounds__(256) void conv_mfma_kernel(
    const float* __restrict__ x, const float* __restrict__ agg,
    const float* __restrict__ Wroot, const float* __restrict__ Wrel,
    const float* __restrict__ bias, const float* __restrict__ p,
    float* __restrict__ h, unsigned long long* __restrict__ keys,
    float* __restrict__ ssc, int n) {
    __shared__ float spart[4][32];
    __shared__ float snorm_s;
    int b = blockIdx.y;
    int r0 = blockIdx.x * 32;
    int t = threadIdx.x;
    int wv = t >> 6, lane = t & 63;
    int m16 = lane & 15, q = lane >> 4;

    if (t < 64) {
        float v = p[t] * p[t] + p[t + 64] * p[t + 64];
#pragma unroll
        for (int off = 32; off; off >>= 1) v += __shfl_xor(v, off);
        if (t == 0) snorm_s = sqrtf(v);
    }

    f32x4 acc[2][2];
#pragma unroll
    for (int rt = 0; rt < 2; rt++)
#pragma unroll
        for (int ct = 0; ct < 2; ct++) {
            acc[rt][ct][0] = 0.f; acc[rt][ct][1] = 0.f;
            acc[rt][ct][2] = 0.f; acc[rt][ct][3] = 0.f;
        }

    int rowA[2] = { r0 + m16, r0 + 16 + m16 };
    int colB[2] = { wv * 32 + m16, wv * 32 + 16 + m16 };

#pragma unroll
    for (int step = 0; step < (2 * FI) / 32; step++) {
        int k0 = step * 32 + q * 8;
        f16x8 afr[2], bfr[2];
#pragma unroll
        for (int rt = 0; rt < 2; rt++) {
            const float* src = (k0 < FI)
                ? x   + ((size_t)b * NN + rowA[rt]) * FI + k0
                : agg + ((size_t)b * NN + rowA[rt]) * FI + (k0 - FI);
            afr[rt] = load_cvt16(src);
        }
#pragma unroll
        for (int ct = 0; ct < 2; ct++) {
            const float* src = (k0 < FI)
                ? Wroot + (size_t)colB[ct] * FI + k0
                : Wrel  + (size_t)colB[ct] * FI + (k0 - FI);
            bfr[ct] = load_cvt16(src);
        }
#pragma unroll
        for (int rt = 0; rt < 2; rt++)
#pragma unroll
            for (int ct = 0; ct < 2; ct++)
                acc[rt][ct] = __builtin_amdgcn_mfma_f32_16x16x32_f16(
                    afr[rt], bfr[ct], acc[rt][ct], 0, 0, 0);
    }

    // epilogue: bias + relu + store h + score partial over this wave's 32 cols
    float prt[2][4];
#pragma unroll
    for (int rt = 0; rt < 2; rt++)
#pragma unroll
        for (int reg = 0; reg < 4; reg++) prt[rt][reg] = 0.f;

#pragma unroll
    for (int ct = 0; ct < 2; ct++) {
        int col = wv * 32 + ct * 16 + m16;
        float pc = p[col];
        float bv = bias[col];
#pragma unroll
        for (int rt = 0; rt < 2; rt++)
#pragma unroll
            for (int reg = 0; reg < 4; reg++) {
                int row = r0 + rt * 16 + q * 4 + reg;
                float hv = fmaxf(acc[rt][ct][reg] + bv, 0.f);
                if (row < n)
                    h[((size_t)b * NN + row) * HH + col] = hv;
                prt[rt][reg] += hv * pc;
            }
    }
#pragma unroll
    for (int rt = 0; rt < 2; rt++)
#pragma unroll
        for (int reg = 0; reg < 4; reg++) {
            float v = prt[rt][reg];
            v += __shfl_xor(v, 1); v += __shfl_xor(v, 2);
            v += __shfl_xor(v, 4); v += __shfl_xor(v, 8);
            prt[rt][reg] = v;
        }
    if (m16 == 0) {
#pragma unroll
        for (int rt = 0; rt < 2; rt++)
#pragma unroll
            for (int reg = 0; reg < 4; reg++)
                spart[wv][rt * 16 + q * 4 + reg] = prt[rt][reg];
    }
    __syncthreads();
    if (t < 32) {
        int row = r0 + t;
        if (row < n) {
            float s = spart[0][t] + spart[1][t] + spart[2][t] + spart[3][t];
            float sc = tanhf(s / snorm_s);
            unsigned u = __float_as_uint(sc);
            u = (u & 0x80000000u) ? ~u : (u ^ 0x80000000u);   // monotone asc
            u = ~u;                                            // -> descending
            keys[(size_t)b * NN + row] = ((unsigned long long)u << 32) | (unsigned)row;
            ssc[(size_t)b * NN + row] = sc;
        }
    }
}

// ---------------- exact rank, j-scan partitioned 4-way ----------------
// Block: 64 i's x 4 j-groups (512 j each); 512 blocks total.
__global__ __launch_bounds__(256) void rank_kernel(
    const unsigned long long* __restrict__ keys, const float* __restrict__ ssc,
    int n, int k, int* __restrict__ perm, float* __restrict__ vals,
    int* __restrict__ inv) {
    __shared__ unsigned long long sk[NN];
    __shared__ int pr2[256];
    int b = blockIdx.y;
    for (int i = threadIdx.x; i < NN; i += 256)
        sk[i] = (i < n) ? keys[(size_t)b * NN + i] : ~0ULL;
    __syncthreads();
    int il = threadIdx.x & 63;           // local i
    int jg = threadIdx.x >> 6;           // j-group (one wave each)
    int i = blockIdx.x * 64 + il;
    unsigned long long my = sk[i];
    int rank = 0;
#pragma unroll 8
    for (int j = jg * 512; j < jg * 512 + 512; j++)
        rank += (sk[j] < my) ? 1 : 0;
    pr2[threadIdx.x] = rank;
    __syncthreads();
    if (jg == 0 && i < n) {
        rank = pr2[il] + pr2[64 + il] + pr2[128 + il] + pr2[192 + il];
        if (rank < k) {
            perm[b * NN + rank] = i;
            vals[b * NN + rank] = ssc[(size_t)b * NN + i];
            inv[b * NN + i] = rank;
        } else {
            inv[b * NN + i] = -1;
        }
    }
}

// ---------------- fused gather*score + readout partials (high-TLP) ----------------
__global__ __launch_bounds__(128) void gather_part_kernel(
    const float* __restrict__ hin, float* __restrict__ xout,
    const int* __restrict__ perm, const float* __restrict__ vals, int k,
    float* __restrict__ part) {
    int b = blockIdx.x >> 7;                 // PARTS=128 splits per graph
    int j = blockIdx.x & (PARTS - 1);
    int f = threadIdx.x;
    float mx = -INFINITY, sm = 0.f;
    for (int i = j; i < k; i += PARTS) {
        int pi = perm[b * NN + i];
        float v = vals[b * NN + i];
        float hv = hin[((size_t)b * NN + pi) * HH + f] * v;
        xout[((size_t)b * NN + i) * HH + f] = hv;
        mx = fmaxf(mx, hv);
        sm += hv;
    }
    part[(size_t)blockIdx.x * 256 + f] = mx;
    part[(size_t)blockIdx.x * 256 + 128 + f] = sm;
}

// ---------------- hierarchical combine: [3][BB][PARTS][256] -> [3][BB][PGRP][256] ----------------
__global__ __launch_bounds__(256) void combine_kernel(
    const float* __restrict__ partAll, float* __restrict__ partG) {
    int blk = blockIdx.x;            // l*BB*PGRP + b*PGRP + g
    int g = blk % PGRP;
    int rem = blk / PGRP;
    int b = rem & 15;
    int l = rem >> 4;
    int f = threadIdx.x;
    const float* src = partAll + ((((size_t)l * BB + b) * PARTS) + (size_t)g * JPG) * 256;
    float r;
    if (f < 128) {
        r = -INFINITY;
#pragma unroll
        for (int j = 0; j < JPG; j++) r = fmaxf(r, src[j * 256 + f]);
    } else {
        r = 0.f;
#pragma unroll
        for (int j = 0; j < JPG; j++) r += src[j * 256 + f];
    }
    partG[(((size_t)l * BB + b) * PGRP + g) * 256 + f] = r;
}

// ---------------- final: combine group partials (3 layers) + MLP ----------------
__global__ __launch_bounds__(256) void mlp_kernel(
    const float* __restrict__ partG,
    const float* __restrict__ W1, const float* __restrict__ b1,
    const float* __restrict__ W2, const float* __restrict__ b2,
    const float* __restrict__ W3, const float* __restrict__ b3,
    float* __restrict__ out) {
    __shared__ float sg[256];
    __shared__ float s1[128];
    __shared__ float s2[64];
    int b = blockIdx.x, tid = threadIdx.x;
    const float kk[3] = {(float)KK1, (float)KK2, (float)KK3};
    float acc = 0.f;
    if (tid < 128) {
#pragma unroll
        for (int l = 0; l < 3; l++) {
            float mx = -INFINITY;
#pragma unroll
            for (int j = 0; j < PGRP; j++)
                mx = fmaxf(mx, partG[(((size_t)l * BB + b) * PGRP + j) * 256 + tid]);
            acc += mx;
        }
    } else {
#pragma unroll
        for (int l = 0; l < 3; l++) {
            float sm = 0.f;
#pragma unroll
            for (int j = 0; j < PGRP; j++)
                sm += partG[(((size_t)l * BB + b) * PGRP + j) * 256 + tid];
            acc += sm / kk[l];
        }
    }
    sg[tid] = acc;
    __syncthreads();
    if (tid < 128) {
        float a = b1[tid];
        for (int j = 0; j < 256; j++) a += sg[j] * W1[tid * 256 + j];
        s1[tid] = fmaxf(a, 0.f);
    }
    __syncthreads();
    if (tid < 64) {
        float a = b2[tid];
        for (int j = 0; j < 128; j++) a += s1[j] * W2[tid * 128 + j];
        s2[tid] = fmaxf(a, 0.f);
    }
    __syncthreads();
    if (tid == 0) {
        float a = b3[0];
        for (int j = 0; j < 64; j++) a += s2[j] * W3[j];
        out[b] = 1.f / (1.f + expf(-a));
    }
}

// ---------------- edge remap through inv + degree count for next CSR ----------------
__global__ void remap_count_kernel(const int* __restrict__ inv,
                                   const int* __restrict__ sin_,
                                   const int* __restrict__ din_,
                                   int in_stride,
                                   int* __restrict__ sout, int* __restrict__ dout,
                                   int* __restrict__ deg) {
    int t = blockIdx.x * blockDim.x + threadIdx.x;   // B*E
    int e = t & (EE - 1);
    int b = t >> 15;
    if (b >= BB) return;
    int s = sin_[(size_t)b * in_stride + e];
    int d = din_[(size_t)b * in_stride + e];
    int ns = -1, nd = -1;
    if (s >= 0 && d >= 0) {
        ns = inv[b * NN + s];
        nd = inv[b * NN + d];
    }
    if (ns < 0 || nd < 0) { ns = -1; nd = -1; }
    sout[b * EE + e] = ns;
    dout[b * EE + e] = nd;
    if (nd >= 0) atomicAdd(&deg[b * NN + nd], 1);
}

extern "C" void kernel_launch(void* const* d_in, const int* in_sizes, int n_in,
                              void* d_out, int out_size, void* d_ws, size_t ws_size,
                              hipStream_t stream) {
    const float* x   = (const float*)d_in[0];
    const int*   ei  = (const int*)d_in[1];
    const float* Wr1 = (const float*)d_in[2];
    const float* Wl1 = (const float*)d_in[3];
    const float* b1  = (const float*)d_in[4];
    const float* p1  = (const float*)d_in[5];
    const float* Wr2 = (const float*)d_in[6];
    const float* Wl2 = (const float*)d_in[7];
    const float* b2  = (const float*)d_in[8];
    const float* p2  = (const float*)d_in[9];
    const float* Wr3 = (const float*)d_in[10];
    const float* Wl3 = (const float*)d_in[11];
    const float* b3  = (const float*)d_in[12];
    const float* p3  = (const float*)d_in[13];
    const float* l1W = (const float*)d_in[14];
    const float* l1b = (const float*)d_in[15];
    const float* l2W = (const float*)d_in[16];
    const float* l2b = (const float*)d_in[17];
    const float* l3W = (const float*)d_in[18];
    const float* l3b = (const float*)d_in[19];
    float* out = (float*)d_out;

    char* ws = (char*)d_ws;
    float* bufA = (float*)ws; ws += (size_t)BB * NN * HH * 4;
    float* bufB = (float*)ws; ws += (size_t)BB * NN * HH * 4;
    float* agg  = (float*)ws; ws += (size_t)BB * NN * HH * 4;
    int*   perm = (int*)ws;   ws += (size_t)BB * NN * 4;
    float* vals = (float*)ws; ws += (size_t)BB * NN * 4;
    int*   inv  = (int*)ws;   ws += (size_t)BB * NN * 4;
    int*   curS = (int*)ws;   ws += (size_t)BB * EE * 4;
    int*   curD = (int*)ws;   ws += (size_t)BB * EE * 4;
    float* partAll = (float*)ws; ws += (size_t)3 * BB * PARTS * 256 * 4;
    float* partG   = (float*)ws; ws += (size_t)3 * BB * PGRP * 256 * 4;
    int*   deg  = (int*)ws;   ws += (size_t)BB * NN * 4;
    int*   rowptr = (int*)ws; ws += (size_t)BB * (NN + 1) * 4;
    int*   cursor = (int*)ws; ws += (size_t)BB * (NN + 1) * 4;
    unsigned long long* keys = (unsigned long long*)ws; ws += (size_t)BB * NN * 8;
    float* ssc  = (float*)ws; ws += (size_t)BB * NN * 4;
    // CSR source array lives in bufA: per layer, CSR build + aggregation finish
    // BEFORE conv writes bufA, and CSR is dead afterwards.
    int*   csr = (int*)bufA;
    float* part1 = partAll;
    float* part2 = partAll + (size_t)BB * PARTS * 256;
    float* part3 = partAll + (size_t)2 * BB * PARTS * 256;

    // ---------- layer 1 ----------
    hipMemsetAsync(deg, 0, (size_t)BB * NN * 4, stream);
    hipLaunchKernelGGL(csr_count_kernel, dim3(BB * EE / 256), dim3(256), 0, stream, ei + EE, 2 * EE, deg);
    hipLaunchKernelGGL(csr_scan_kernel, dim3(BB), dim3(1024), 0, stream, deg, rowptr, cursor);
    hipLaunchKernelGGL(csr_fill_kernel, dim3(BB * EE / 256), dim3(256), 0, stream, ei, ei + EE, 2 * EE, cursor, csr);
    hipLaunchKernelGGL(agg1_csr_kernel, dim3(NN / 8, BB), dim3(256), 0, stream, x, rowptr, csr, agg);
    hipLaunchKernelGGL((conv_mfma_kernel<FIN>), dim3(NN / 32, BB), dim3(256), 0, stream,
                       x, agg, Wr1, Wl1, b1, p1, bufA, keys, ssc, NN);
    hipLaunchKernelGGL(rank_kernel, dim3(NN / 64, BB), dim3(256), 0, stream, keys, ssc, NN, KK1, perm, vals, inv);
    hipLaunchKernelGGL(gather_part_kernel, dim3(BB * PARTS), dim3(128), 0, stream, bufA, bufB, perm, vals, KK1, part1);
    hipLaunchKernelGGL(remap_count_kernel, dim3(BB * EE / 256), dim3(256), 0, stream, inv, ei, ei + EE, 2 * EE, curS, curD, deg);

    // ---------- layer 2 ----------
    hipLaunchKernelGGL(csr_scan_kernel, dim3(BB), dim3(1024), 0, stream, deg, rowptr, cursor);
    hipLaunchKernelGGL(csr_fill_kernel, dim3(BB * EE / 256), dim3(256), 0, stream, curS, curD, EE, cursor, csr);
    hipLaunchKernelGGL(agg23_csr_kernel, dim3((KK1 + 3) / 4, BB), dim3(128), 0, stream, bufB, rowptr, csr, agg, KK1);
    hipLaunchKernelGGL((conv_mfma_kernel<HH>), dim3((KK1 + 31) / 32, BB), dim3(256), 0, stream,
                       bufB, agg, Wr2, Wl2, b2, p2, bufA, keys, ssc, KK1);
    hipLaunchKernelGGL(rank_kernel, dim3(NN / 64, BB), dim3(256), 0, stream, keys, ssc, KK1, KK2, perm, vals, inv);
    hipLaunchKernelGGL(gather_part_kernel, dim3(BB * PARTS), dim3(128), 0, stream, bufA, bufB, perm, vals, KK2, part2);
    hipLaunchKernelGGL(remap_count_kernel, dim3(BB * EE / 256), dim3(256), 0, stream, inv, curS, curD, EE, curS, curD, deg);

    // ---------- layer 3 ----------
    hipLaunchKernelGGL(csr_scan_kernel, dim3(BB), dim3(1024), 0, stream, deg, rowptr, cursor);
    hipLaunchKernelGGL(csr_fill_kernel, dim3(BB * EE / 256), dim3(256), 0, stream, curS, curD, EE, cursor, csr);
    hipLaunchKernelGGL(agg23_csr_kernel, dim3((KK2 + 3) / 4, BB), dim3(128), 0, stream, bufB, rowptr, csr, agg, KK2);
    hipLaunchKernelGGL((conv_mfma_kernel<HH>), dim3((KK2 + 31) / 32, BB), dim3(256), 0, stream,
                       bufB, agg, Wr3, Wl3, b3, p3, bufA, keys, ssc, KK2);
    hipLaunchKernelGGL(rank_kernel, dim3(NN / 64, BB), dim3(256), 0, stream, keys, ssc, KK2, KK3, perm, vals, inv);
    hipLaunchKernelGGL(gather_part_kernel, dim3(BB * PARTS), dim3(128), 0, stream, bufA, bufB, perm, vals, KK3, part3);

    // ---------- final: hierarchical combine + MLP ----------
    hipLaunchKernelGGL(combine_kernel, dim3(3 * BB * PGRP), dim3(256), 0, stream, partAll, partG);
    hipLaunchKernelGGL(mlp_kernel, dim3(BB), dim3(256), 0, stream,
                       partG, l1W, l1b, l2W, l2b, l3W, l3b, out);
}

// Round 10
// 317.847 us; speedup vs baseline: 1.7873x; 1.1692x over previous
//
#include <hip/hip_runtime.h>
#include <cstdint>
#include <math.h>

#define BB 16
#define NN 2048
#define EE 32768
#define FIN 32
#define HH 128
#define KK1 1639
#define KK2 1312
#define KK3 1050
#define PARTS 128
#define PGRP 8            // combined groups per graph/layer
#define JPG (PARTS / PGRP)

using f16x8 = __attribute__((ext_vector_type(8))) _Float16;
using f32x4 = __attribute__((ext_vector_type(4))) float;

// ---------------- layer-1 CSR count: incoming edges per dst ----------------
__global__ void csr_count_kernel(const int* __restrict__ dsts, int stride,
                                 int* __restrict__ deg) {
    int t = blockIdx.x * blockDim.x + threadIdx.x;   // B*E
    int e = t & (EE - 1);
    int b = t >> 15;
    if (b >= BB) return;
    int d = dsts[(size_t)b * stride + e];
    if (d >= 0) atomicAdd(&deg[b * NN + d], 1);
}

// ---------------- CSR scan (shfl) + self-zero deg for next layer ----------------
__global__ __launch_bounds__(1024) void csr_scan_kernel(
    int* __restrict__ deg, int* __restrict__ rowptr, int* __restrict__ cursor) {
    __shared__ int wsum[16];
    int b = blockIdx.x, t = threadIdx.x;
    int d0 = deg[b * NN + 2 * t];
    int d1 = deg[b * NN + 2 * t + 1];
    deg[b * NN + 2 * t] = 0;                 // zero for next layer's counting
    deg[b * NN + 2 * t + 1] = 0;
    int s = d0 + d1;
    int lane = t & 63;
    int v = s;
#pragma unroll
    for (int off = 1; off < 64; off <<= 1) {
        int u = __shfl_up(v, off);
        if (lane >= off) v += u;
    }
    if (lane == 63) wsum[t >> 6] = v;
    __syncthreads();
    int w = t >> 6;
    int woff = 0;
#pragma unroll
    for (int i = 0; i < 16; i++) woff += (i < w) ? wsum[i] : 0;
    int excl = woff + v - s;
    int base = b * (NN + 1);
    if (t == 0) { rowptr[base] = 0; cursor[base] = 0; }
    int p0 = excl + d0, p1 = excl + d0 + d1;
    rowptr[base + 2 * t + 1] = p0; cursor[base + 2 * t + 1] = p0;
    rowptr[base + 2 * t + 2] = p1; cursor[base + 2 * t + 2] = p1;
}

// ---------------- CSR fill: scatter source ids ----------------
__global__ void csr_fill_kernel(const int* __restrict__ srcs,
                                const int* __restrict__ dsts, int stride,
                                int* __restrict__ cursor, int* __restrict__ csr) {
    int t = blockIdx.x * blockDim.x + threadIdx.x;   // B*E
    int e = t & (EE - 1);
    int b = t >> 15;
    if (b >= BB) return;
    int s = srcs[(size_t)b * stride + e];
    int d = dsts[(size_t)b * stride + e];
    if (s >= 0 && d >= 0) {
        int pos = atomicAdd(&cursor[b * (NN + 1) + d], 1);
        csr[(size_t)b * EE + pos] = s;
    }
}

// ---------------- pull aggregation, F=32 (layer 1): 32-lane group per node, 16-deep ----------------
__global__ __launch_bounds__(256) void agg1_csr_kernel(
    const float* __restrict__ x, const int* __restrict__ rowptr,
    const int* __restrict__ csr, float* __restrict__ agg) {
    int b = blockIdx.y;
    int g = threadIdx.x >> 5, lane = threadIdx.x & 31;
    int node = blockIdx.x * 8 + g;
    int beg = rowptr[b * (NN + 1) + node];
    int end = rowptr[b * (NN + 1) + node + 1];
    float acc = 0.f;
    for (int base = beg; base < end; base += 16) {
        int m = end - base; if (m > 16) m = 16;
        int myidx = (lane < m) ? csr[(size_t)b * EE + base + lane] : 0;
        float v[16];
        int idx[16];
#pragma unroll
        for (int u = 0; u < 16; u++) idx[u] = __shfl(myidx, u, 32);
#pragma unroll
        for (int u = 0; u < 16; u++)
            v[u] = x[((size_t)b * NN + idx[u]) * FIN + lane];
#pragma unroll
        for (int u = 0; u < 16; u++)
            acc += (u < m) ? v[u] : 0.f;
    }
    agg[((size_t)b * NN + node) * FIN + lane] = acc;
}

// ---------------- pull aggregation, F=128 (layers 2/3): wave per node, float2, 16-deep ----------------
__global__ __launch_bounds__(256) void agg23_csr_kernel(
    const float* __restrict__ x, const int* __restrict__ rowptr,
    const int* __restrict__ csr, float* __restrict__ agg, int n) {
    int b = blockIdx.y;
    int wv = threadIdx.x >> 6, lane = threadIdx.x & 63;
    int node = blockIdx.x * 4 + wv;
    if (node >= n) return;
    int beg = rowptr[b * (NN + 1) + node];
    int end = rowptr[b * (NN + 1) + node + 1];
    const float2* xf2 = reinterpret_cast<const float2*>(x);
    float2 acc = make_float2(0.f, 0.f);
    for (int base = beg; base < end; base += 16) {
        int m = end - base; if (m > 16) m = 16;
        int myidx = (lane < m) ? csr[(size_t)b * EE + base + lane] : 0;
        int idx[16];
#pragma unroll
        for (int u = 0; u < 16; u++) idx[u] = __shfl(myidx, u);
        float2 v[16];
#pragma unroll
        for (int u = 0; u < 16; u++)
            v[u] = xf2[((size_t)b * NN + idx[u]) * 64 + lane];
#pragma unroll
        for (int u = 0; u < 16; u++) {
            acc.x += (u < m) ? v[u].x : 0.f;
            acc.y += (u < m) ? v[u].y : 0.f;
        }
    }
    reinterpret_cast<float2*>(agg)[((size_t)b * NN + node) * 64 + lane] = acc;
}

// ---------------- f32 -> f16x8 fragment load (RNE via v_cvt_f16_f32) ----------------
__device__ __forceinline__ f16x8 load_cvt16(const float* src) {
    float4 lo = *reinterpret_cast<const float4*>(src);
    float4 hi = *reinterpret_cast<const float4*>(src + 4);
    f16x8 r;
    r[0] = (_Float16)lo.x; r[1] = (_Float16)lo.y;
    r[2] = (_Float16)lo.z; r[3] = (_Float16)lo.w;
    r[4] = (_Float16)hi.x; r[5] = (_Float16)hi.y;
    r[6] = (_Float16)hi.z; r[7] = (_Float16)hi.w;
    return r;
}

// ---------------- MFMA conv + fused score/key ----------------
// Block = 32 rows x 128 cols, 4 waves, each wave 2x2 tiles of 16x16x32_f16.
// A layout: lane holds A[lane%16][(lane/16)*8 + i]; B (W layout) same.
// D layout: col = lane&15, row = (lane>>4)*4 + reg.
template<int FI>
__global__ __launch_bounds__(256) void conv_mfma_kernel(
    const float* __restrict__ x, const float* __restrict__ agg,
    const float* __restrict__ Wroot, const float* __restrict__ Wrel,
    const float* __restrict__ bias, const float* __restrict__ p,
    float* __restrict__ h, unsigned long long* __restrict__ keys,
    float* __restrict__ ssc, int n) {
    __shared__ float spart[4][32];
    __shared__ float snorm_s;
    int b = blockIdx.y;
    int r0 = blockIdx.x * 32;
    int t = threadIdx.x;
    int wv = t >> 6, lane = t & 63;
    int m16 = lane & 15, q = lane >> 4;

    if (t < 64) {
        float v = p[t] * p[t] + p[t + 64] * p[t + 64];
#pragma unroll
        for (int off = 32; off; off >>= 1) v += __shfl_xor(v, off);
        if (t == 0) snorm_s = sqrtf(v);
    }

    f32x4 acc[2][2];
#pragma unroll
    for (int rt = 0; rt < 2; rt++)
#pragma unroll
        for (int ct = 0; ct < 2; ct++) {
            acc[rt][ct][0] = 0.f; acc[rt][ct][1] = 0.f;
            acc[rt][ct][2] = 0.f; acc[rt][ct][3] = 0.f;
        }

    int rowA[2] = { r0 + m16, r0 + 16 + m16 };
    int colB[2] = { wv * 32 + m16, wv * 32 + 16 + m16 };

#pragma unroll
    for (int step = 0; step < (2 * FI) / 32; step++) {
        int k0 = step * 32 + q * 8;
        f16x8 afr[2], bfr[2];
#pragma unroll
        for (int rt = 0; rt < 2; rt++) {
            const float* src = (k0 < FI)
                ? x   + ((size_t)b * NN + rowA[rt]) * FI + k0
                : agg + ((size_t)b * NN + rowA[rt]) * FI + (k0 - FI);
            afr[rt] = load_cvt16(src);
        }
#pragma unroll
        for (int ct = 0; ct < 2; ct++) {
            const float* src = (k0 < FI)
                ? Wroot + (size_t)colB[ct] * FI + k0
                : Wrel  + (size_t)colB[ct] * FI + (k0 - FI);
            bfr[ct] = load_cvt16(src);
        }
#pragma unroll
        for (int rt = 0; rt < 2; rt++)
#pragma unroll
            for (int ct = 0; ct < 2; ct++)
                acc[rt][ct] = __builtin_amdgcn_mfma_f32_16x16x32_f16(
                    afr[rt], bfr[ct], acc[rt][ct], 0, 0, 0);
    }

    // epilogue: bias + relu + store h + score partial over this wave's 32 cols
    float prt[2][4];
#pragma unroll
    for (int rt = 0; rt < 2; rt++)
#pragma unroll
        for (int reg = 0; reg < 4; reg++) prt[rt][reg] = 0.f;

#pragma unroll
    for (int ct = 0; ct < 2; ct++) {
        int col = wv * 32 + ct * 16 + m16;
        float pc = p[col];
        float bv = bias[col];
#pragma unroll
        for (int rt = 0; rt < 2; rt++)
#pragma unroll
            for (int reg = 0; reg < 4; reg++) {
                int row = r0 + rt * 16 + q * 4 + reg;
                float hv = fmaxf(acc[rt][ct][reg] + bv, 0.f);
                if (row < n)
                    h[((size_t)b * NN + row) * HH + col] = hv;
                prt[rt][reg] += hv * pc;
            }
    }
#pragma unroll
    for (int rt = 0; rt < 2; rt++)
#pragma unroll
        for (int reg = 0; reg < 4; reg++) {
            float v = prt[rt][reg];
            v += __shfl_xor(v, 1); v += __shfl_xor(v, 2);
            v += __shfl_xor(v, 4); v += __shfl_xor(v, 8);
            prt[rt][reg] = v;
        }
    if (m16 == 0) {
#pragma unroll
        for (int rt = 0; rt < 2; rt++)
#pragma unroll
            for (int reg = 0; reg < 4; reg++)
                spart[wv][rt * 16 + q * 4 + reg] = prt[rt][reg];
    }
    __syncthreads();
    if (t < 32) {
        int row = r0 + t;
        if (row < n) {
            float s = spart[0][t] + spart[1][t] + spart[2][t] + spart[3][t];
            float sc = tanhf(s / snorm_s);
            unsigned u = __float_as_uint(sc);
            u = (u & 0x80000000u) ? ~u : (u ^ 0x80000000u);   // monotone asc
            u = ~u;                                            // -> descending
            keys[(size_t)b * NN + row] = ((unsigned long long)u << 32) | (unsigned)row;
            ssc[(size_t)b * NN + row] = sc;
        }
    }
}

// ---------------- exact rank, j-scan partitioned 4-way ----------------
__global__ __launch_bounds__(256) void rank_kernel(
    const unsigned long long* __restrict__ keys, const float* __restrict__ ssc,
    int n, int k, int* __restrict__ perm, float* __restrict__ vals,
    int* __restrict__ inv) {
    __shared__ unsigned long long sk[NN];
    __shared__ int pr2[256];
    int b = blockIdx.y;
    for (int i = threadIdx.x; i < NN; i += 256)
        sk[i] = (i < n) ? keys[(size_t)b * NN + i] : ~0ULL;
    __syncthreads();
    int il = threadIdx.x & 63;           // local i
    int jg = threadIdx.x >> 6;           // j-group (one wave each)
    int i = blockIdx.x * 64 + il;
    unsigned long long my = sk[i];
    int rank = 0;
#pragma unroll 8
    for (int j = jg * 512; j < jg * 512 + 512; j++)
        rank += (sk[j] < my) ? 1 : 0;
    pr2[threadIdx.x] = rank;
    __syncthreads();
    if (jg == 0 && i < n) {
        rank = pr2[il] + pr2[64 + il] + pr2[128 + il] + pr2[192 + il];
        if (rank < k) {
            perm[b * NN + rank] = i;
            vals[b * NN + rank] = ssc[(size_t)b * NN + i];
            inv[b * NN + i] = rank;
        } else {
            inv[b * NN + i] = -1;
        }
    }
}

// ---------------- fused gather*score + readout partials (high-TLP) ----------------
__global__ __launch_bounds__(128) void gather_part_kernel(
    const float* __restrict__ hin, float* __restrict__ xout,
    const int* __restrict__ perm, const float* __restrict__ vals, int k,
    float* __restrict__ part) {
    int b = blockIdx.x >> 7;                 // PARTS=128 splits per graph
    int j = blockIdx.x & (PARTS - 1);
    int f = threadIdx.x;
    float mx = -INFINITY, sm = 0.f;
    for (int i = j; i < k; i += PARTS) {
        int pi = perm[b * NN + i];
        float v = vals[b * NN + i];
        float hv = hin[((size_t)b * NN + pi) * HH + f] * v;
        xout[((size_t)b * NN + i) * HH + f] = hv;
        mx = fmaxf(mx, hv);
        sm += hv;
    }
    part[(size_t)blockIdx.x * 256 + f] = mx;
    part[(size_t)blockIdx.x * 256 + 128 + f] = sm;
}

// ---------------- hierarchical combine: [3][BB][PARTS][256] -> [3][BB][PGRP][256] ----------------
__global__ __launch_bounds__(256) void combine_kernel(
    const float* __restrict__ partAll, float* __restrict__ partG) {
    int blk = blockIdx.x;            // l*BB*PGRP + b*PGRP + g
    int g = blk % PGRP;
    int rem = blk / PGRP;
    int b = rem & 15;
    int l = rem >> 4;
    int f = threadIdx.x;
    const float* src = partAll + ((((size_t)l * BB + b) * PARTS) + (size_t)g * JPG) * 256;
    float r;
    if (f < 128) {
        r = -INFINITY;
#pragma unroll
        for (int j = 0; j < JPG; j++) r = fmaxf(r, src[j * 256 + f]);
    } else {
        r = 0.f;
#pragma unroll
        for (int j = 0; j < JPG; j++) r += src[j * 256 + f];
    }
    partG[(((size_t)l * BB + b) * PGRP + g) * 256 + f] = r;
}

// ---------------- final: combine group partials (3 layers) + MLP ----------------
__global__ __launch_bounds__(256) void mlp_kernel(
    const float* __restrict__ partG,
    const float* __restrict__ W1, const float* __restrict__ b1,
    const float* __restrict__ W2, const float* __restrict__ b2,
    const float* __restrict__ W3, const float* __restrict__ b3,
    float* __restrict__ out) {
    __shared__ float sg[256];
    __shared__ float s1[128];
    __shared__ float s2[64];
    int b = blockIdx.x, tid = threadIdx.x;
    const float kk[3] = {(float)KK1, (float)KK2, (float)KK3};
    float acc = 0.f;
    if (tid < 128) {
#pragma unroll
        for (int l = 0; l < 3; l++) {
            float mx = -INFINITY;
#pragma unroll
            for (int j = 0; j < PGRP; j++)
                mx = fmaxf(mx, partG[(((size_t)l * BB + b) * PGRP + j) * 256 + tid]);
            acc += mx;
        }
    } else {
#pragma unroll
        for (int l = 0; l < 3; l++) {
            float sm = 0.f;
#pragma unroll
            for (int j = 0; j < PGRP; j++)
                sm += partG[(((size_t)l * BB + b) * PGRP + j) * 256 + tid];
            acc += sm / kk[l];
        }
    }
    sg[tid] = acc;
    __syncthreads();
    if (tid < 128) {
        float a = b1[tid];
        for (int j = 0; j < 256; j++) a += sg[j] * W1[tid * 256 + j];
        s1[tid] = fmaxf(a, 0.f);
    }
    __syncthreads();
    if (tid < 64) {
        float a = b2[tid];
        for (int j = 0; j < 128; j++) a += s1[j] * W2[tid * 128 + j];
        s2[tid] = fmaxf(a, 0.f);
    }
    __syncthreads();
    if (tid == 0) {
        float a = b3[0];
        for (int j = 0; j < 64; j++) a += s2[j] * W3[j];
        out[b] = 1.f / (1.f + expf(-a));
    }
}

// ---------------- edge remap through inv + degree count for next CSR ----------------
__global__ void remap_count_kernel(const int* __restrict__ inv,
                                   const int* __restrict__ sin_,
                                   const int* __restrict__ din_,
                                   int in_stride,
                                   int* __restrict__ sout, int* __restrict__ dout,
                                   int* __restrict__ deg) {
    int t = blockIdx.x * blockDim.x + threadIdx.x;   // B*E
    int e = t & (EE - 1);
    int b = t >> 15;
    if (b >= BB) return;
    int s = sin_[(size_t)b * in_stride + e];
    int d = din_[(size_t)b * in_stride + e];
    int ns = -1, nd = -1;
    if (s >= 0 && d >= 0) {
        ns = inv[b * NN + s];
        nd = inv[b * NN + d];
    }
    if (ns < 0 || nd < 0) { ns = -1; nd = -1; }
    sout[b * EE + e] = ns;
    dout[b * EE + e] = nd;
    if (nd >= 0) atomicAdd(&deg[b * NN + nd], 1);
}

extern "C" void kernel_launch(void* const* d_in, const int* in_sizes, int n_in,
                              void* d_out, int out_size, void* d_ws, size_t ws_size,
                              hipStream_t stream) {
    const float* x   = (const float*)d_in[0];
    const int*   ei  = (const int*)d_in[1];
    const float* Wr1 = (const float*)d_in[2];
    const float* Wl1 = (const float*)d_in[3];
    const float* b1  = (const float*)d_in[4];
    const float* p1  = (const float*)d_in[5];
    const float* Wr2 = (const float*)d_in[6];
    const float* Wl2 = (const float*)d_in[7];
    const float* b2  = (const float*)d_in[8];
    const float* p2  = (const float*)d_in[9];
    const float* Wr3 = (const float*)d_in[10];
    const float* Wl3 = (const float*)d_in[11];
    const float* b3  = (const float*)d_in[12];
    const float* p3  = (const float*)d_in[13];
    const float* l1W = (const float*)d_in[14];
    const float* l1b = (const float*)d_in[15];
    const float* l2W = (const float*)d_in[16];
    const float* l2b = (const float*)d_in[17];
    const float* l3W = (const float*)d_in[18];
    const float* l3b = (const float*)d_in[19];
    float* out = (float*)d_out;

    char* ws = (char*)d_ws;
    float* bufA = (float*)ws; ws += (size_t)BB * NN * HH * 4;
    float* bufB = (float*)ws; ws += (size_t)BB * NN * HH * 4;
    float* agg  = (float*)ws; ws += (size_t)BB * NN * HH * 4;
    int*   perm = (int*)ws;   ws += (size_t)BB * NN * 4;
    float* vals = (float*)ws; ws += (size_t)BB * NN * 4;
    int*   inv  = (int*)ws;   ws += (size_t)BB * NN * 4;
    int*   curS = (int*)ws;   ws += (size_t)BB * EE * 4;
    int*   curD = (int*)ws;   ws += (size_t)BB * EE * 4;
    float* partAll = (float*)ws; ws += (size_t)3 * BB * PARTS * 256 * 4;
    float* partG   = (float*)ws; ws += (size_t)3 * BB * PGRP * 256 * 4;
    int*   deg  = (int*)ws;   ws += (size_t)BB * NN * 4;
    int*   rowptr = (int*)ws; ws += (size_t)BB * (NN + 1) * 4;
    int*   cursor = (int*)ws; ws += (size_t)BB * (NN + 1) * 4;
    unsigned long long* keys = (unsigned long long*)ws; ws += (size_t)BB * NN * 8;
    float* ssc  = (float*)ws; ws += (size_t)BB * NN * 4;
    // CSR source array lives in bufA: per layer, CSR build + aggregation finish
    // BEFORE conv writes bufA, and CSR is dead afterwards.
    int*   csr = (int*)bufA;
    float* part1 = partAll;
    float* part2 = partAll + (size_t)BB * PARTS * 256;
    float* part3 = partAll + (size_t)2 * BB * PARTS * 256;

    // ---------- layer 1 ----------
    hipMemsetAsync(deg, 0, (size_t)BB * NN * 4, stream);
    hipLaunchKernelGGL(csr_count_kernel, dim3(BB * EE / 256), dim3(256), 0, stream, ei + EE, 2 * EE, deg);
    hipLaunchKernelGGL(csr_scan_kernel, dim3(BB), dim3(1024), 0, stream, deg, rowptr, cursor);
    hipLaunchKernelGGL(csr_fill_kernel, dim3(BB * EE / 256), dim3(256), 0, stream, ei, ei + EE, 2 * EE, cursor, csr);
    hipLaunchKernelGGL(agg1_csr_kernel, dim3(NN / 8, BB), dim3(256), 0, stream, x, rowptr, csr, agg);
    hipLaunchKernelGGL((conv_mfma_kernel<FIN>), dim3(NN / 32, BB), dim3(256), 0, stream,
                       x, agg, Wr1, Wl1, b1, p1, bufA, keys, ssc, NN);
    hipLaunchKernelGGL(rank_kernel, dim3(NN / 64, BB), dim3(256), 0, stream, keys, ssc, NN, KK1, perm, vals, inv);
    hipLaunchKernelGGL(gather_part_kernel, dim3(BB * PARTS), dim3(128), 0, stream, bufA, bufB, perm, vals, KK1, part1);
    hipLaunchKernelGGL(remap_count_kernel, dim3(BB * EE / 256), dim3(256), 0, stream, inv, ei, ei + EE, 2 * EE, curS, curD, deg);

    // ---------- layer 2 ----------
    hipLaunchKernelGGL(csr_scan_kernel, dim3(BB), dim3(1024), 0, stream, deg, rowptr, cursor);
    hipLaunchKernelGGL(csr_fill_kernel, dim3(BB * EE / 256), dim3(256), 0, stream, curS, curD, EE, cursor, csr);
    hipLaunchKernelGGL(agg23_csr_kernel, dim3((KK1 + 3) / 4, BB), dim3(256), 0, stream, bufB, rowptr, csr, agg, KK1);
    hipLaunchKernelGGL((conv_mfma_kernel<HH>), dim3((KK1 + 31) / 32, BB), dim3(256), 0, stream,
                       bufB, agg, Wr2, Wl2, b2, p2, bufA, keys, ssc, KK1);
    hipLaunchKernelGGL(rank_kernel, dim3(NN / 64, BB), dim3(256), 0, stream, keys, ssc, KK1, KK2, perm, vals, inv);
    hipLaunchKernelGGL(gather_part_kernel, dim3(BB * PARTS), dim3(128), 0, stream, bufA, bufB, perm, vals, KK2, part2);
    hipLaunchKernelGGL(remap_count_kernel, dim3(BB * EE / 256), dim3(256), 0, stream, inv, curS, curD, EE, curS, curD, deg);

    // ---------- layer 3 ----------
    hipLaunchKernelGGL(csr_scan_kernel, dim3(BB), dim3(1024), 0, stream, deg, rowptr, cursor);
    hipLaunchKernelGGL(csr_fill_kernel, dim3(BB * EE / 256), dim3(256), 0, stream, curS, curD, EE, cursor, csr);
    hipLaunchKernelGGL(agg23_csr_kernel, dim3((KK2 + 3) / 4, BB), dim3(256), 0, stream, bufB, rowptr, csr, agg, KK2);
    hipLaunchKernelGGL((conv_mfma_kernel<HH>), dim3((KK2 + 31) / 32, BB), dim3(256), 0, stream,
                       bufB, agg, Wr3, Wl3, b3, p3, bufA, keys, ssc, KK2);
    hipLaunchKernelGGL(rank_kernel, dim3(NN / 64, BB), dim3(256), 0, stream, keys, ssc, KK2, KK3, perm, vals, inv);
    hipLaunchKernelGGL(gather_part_kernel, dim3(BB * PARTS), dim3(128), 0, stream, bufA, bufB, perm, vals, KK3, part3);

    // ---------- final: hierarchical combine + MLP ----------
    hipLaunchKernelGGL(combine_kernel, dim3(3 * BB * PGRP), dim3(256), 0, stream, partAll, partG);
    hipLaunchKernelGGL(mlp_kernel, dim3(BB), dim3(256), 0, stream,
                       partG, l1W, l1b, l2W, l2b, l3W, l3b, out);
}

// Round 11
// 262.221 us; speedup vs baseline: 2.1664x; 1.2121x over previous
//
#include <hip/hip_runtime.h>
#include <cstdint>
#include <math.h>

#define BB 16
#define NN 2048
#define EE 32768
#define FIN 32
#define HH 128
#define KK1 1639
#define KK2 1312
#define KK3 1050
#define PARTS 128
#define PGRP 8            // combined groups per graph/layer
#define JPG (PARTS / PGRP)
#define DEGC 64           // bucket capacity; P(deg>64) ~ 1e-20 for Binom(32768,1/2048)

using f16x8 = __attribute__((ext_vector_type(8))) _Float16;
using f32x4 = __attribute__((ext_vector_type(4))) float;

// ---------------- layer-1 edge pass: bucket-scatter CSR directly ----------------
__global__ void build1_kernel(const int* __restrict__ ei,
                              int* __restrict__ deg, int* __restrict__ csr) {
    int t = blockIdx.x * blockDim.x + threadIdx.x;   // B*E
    int e = t & (EE - 1);
    int b = t >> 15;
    if (b >= BB) return;
    int s = ei[(size_t)b * 2 * EE + e];
    int d = ei[(size_t)b * 2 * EE + EE + e];
    int pos = atomicAdd(&deg[b * NN + d], 1);
    if (pos < DEGC) csr[((size_t)b * NN + d) * DEGC + pos] = s;
}

// ---------------- layer-2/3 edge pass: remap through inv + bucket-scatter ----------------
__global__ void build23_kernel(const int* __restrict__ inv,
                               const int* __restrict__ sin_,
                               const int* __restrict__ din_, int in_stride,
                               int* __restrict__ sout, int* __restrict__ dout,
                               int write_next,
                               int* __restrict__ deg, int* __restrict__ csr) {
    int t = blockIdx.x * blockDim.x + threadIdx.x;   // B*E
    int e = t & (EE - 1);
    int b = t >> 15;
    if (b >= BB) return;
    int s = sin_[(size_t)b * in_stride + e];
    int d = din_[(size_t)b * in_stride + e];
    int ns = -1, nd = -1;
    if (s >= 0 && d >= 0) {
        ns = inv[b * NN + s];
        nd = inv[b * NN + d];
    }
    if (ns < 0 || nd < 0) { ns = -1; nd = -1; }
    if (write_next) {
        sout[(size_t)b * EE + e] = ns;
        dout[(size_t)b * EE + e] = nd;
    }
    if (nd >= 0) {
        int pos = atomicAdd(&deg[b * NN + nd], 1);
        if (pos < DEGC) csr[((size_t)b * NN + nd) * DEGC + pos] = ns;
    }
}

// ---------------- pull aggregation, F=32 (layer 1): 32-lane group per node, 16-deep ----------------
__global__ __launch_bounds__(256) void agg1_csr_kernel(
    const float* __restrict__ x, const int* __restrict__ deg,
    const int* __restrict__ csr, float* __restrict__ agg) {
    int b = blockIdx.y;
    int g = threadIdx.x >> 5, lane = threadIdx.x & 31;
    int node = blockIdx.x * 8 + g;
    int dg = deg[b * NN + node]; if (dg > DEGC) dg = DEGC;
    const int* bucket = csr + ((size_t)b * NN + node) * DEGC;
    float acc = 0.f;
    for (int base = 0; base < dg; base += 16) {
        int m = dg - base; if (m > 16) m = 16;
        int myidx = (lane < m) ? bucket[base + lane] : 0;
        float v[16];
        int idx[16];
#pragma unroll
        for (int u = 0; u < 16; u++) idx[u] = __shfl(myidx, u, 32);
#pragma unroll
        for (int u = 0; u < 16; u++)
            v[u] = x[((size_t)b * NN + idx[u]) * FIN + lane];
#pragma unroll
        for (int u = 0; u < 16; u++)
            acc += (u < m) ? v[u] : 0.f;
    }
    agg[((size_t)b * NN + node) * FIN + lane] = acc;
}

// ---------------- pull aggregation, F=128 (layers 2/3): wave per node, float2, 16-deep ----------------
__global__ __launch_bounds__(256) void agg23_csr_kernel(
    const float* __restrict__ x, const int* __restrict__ deg,
    const int* __restrict__ csr, float* __restrict__ agg, int n) {
    int b = blockIdx.y;
    int wv = threadIdx.x >> 6, lane = threadIdx.x & 63;
    int node = blockIdx.x * 4 + wv;
    if (node >= n) return;
    int dg = deg[b * NN + node]; if (dg > DEGC) dg = DEGC;
    const int* bucket = csr + ((size_t)b * NN + node) * DEGC;
    const float2* xf2 = reinterpret_cast<const float2*>(x);
    float2 acc = make_float2(0.f, 0.f);
    for (int base = 0; base < dg; base += 16) {
        int m = dg - base; if (m > 16) m = 16;
        int myidx = (lane < m) ? bucket[base + lane] : 0;
        int idx[16];
#pragma unroll
        for (int u = 0; u < 16; u++) idx[u] = __shfl(myidx, u);
        float2 v[16];
#pragma unroll
        for (int u = 0; u < 16; u++)
            v[u] = xf2[((size_t)b * NN + idx[u]) * 64 + lane];
#pragma unroll
        for (int u = 0; u < 16; u++) {
            acc.x += (u < m) ? v[u].x : 0.f;
            acc.y += (u < m) ? v[u].y : 0.f;
        }
    }
    reinterpret_cast<float2*>(agg)[((size_t)b * NN + node) * 64 + lane] = acc;
}

// ---------------- f32 -> f16x8 fragment load (RNE via v_cvt_f16_f32) ----------------
__device__ __forceinline__ f16x8 load_cvt16(const float* src) {
    float4 lo = *reinterpret_cast<const float4*>(src);
    float4 hi = *reinterpret_cast<const float4*>(src + 4);
    f16x8 r;
    r[0] = (_Float16)lo.x; r[1] = (_Float16)lo.y;
    r[2] = (_Float16)lo.z; r[3] = (_Float16)lo.w;
    r[4] = (_Float16)hi.x; r[5] = (_Float16)hi.y;
    r[6] = (_Float16)hi.z; r[7] = (_Float16)hi.w;
    return r;
}

// ---------------- MFMA conv + fused score/key ----------------
// Block = 32 rows x 128 cols, 4 waves, each wave 2x2 tiles of 16x16x32_f16.
// A layout: lane holds A[lane%16][(lane/16)*8 + i]; B (W layout) same.
// D layout: col = lane&15, row = (lane>>4)*4 + reg.
template<int FI>
__global__ __launch_bounds__(256) void conv_mfma_kernel(
    const float* __restrict__ x, const float* __restrict__ agg,
    const float* __restrict__ Wroot, const float* __restrict__ Wrel,
    const float* __restrict__ bias, const float* __restrict__ p,
    float* __restrict__ h, unsigned long long* __restrict__ keys,
    float* __restrict__ ssc, int n) {
    __shared__ float spart[4][32];
    __shared__ float snorm_s;
    int b = blockIdx.y;
    int r0 = blockIdx.x * 32;
    int t = threadIdx.x;
    int wv = t >> 6, lane = t & 63;
    int m16 = lane & 15, q = lane >> 4;

    if (t < 64) {
        float v = p[t] * p[t] + p[t + 64] * p[t + 64];
#pragma unroll
        for (int off = 32; off; off >>= 1) v += __shfl_xor(v, off);
        if (t == 0) snorm_s = sqrtf(v);
    }

    f32x4 acc[2][2];
#pragma unroll
    for (int rt = 0; rt < 2; rt++)
#pragma unroll
        for (int ct = 0; ct < 2; ct++) {
            acc[rt][ct][0] = 0.f; acc[rt][ct][1] = 0.f;
            acc[rt][ct][2] = 0.f; acc[rt][ct][3] = 0.f;
        }

    int rowA[2] = { r0 + m16, r0 + 16 + m16 };
    int colB[2] = { wv * 32 + m16, wv * 32 + 16 + m16 };

#pragma unroll
    for (int step = 0; step < (2 * FI) / 32; step++) {
        int k0 = step * 32 + q * 8;
        f16x8 afr[2], bfr[2];
#pragma unroll
        for (int rt = 0; rt < 2; rt++) {
            const float* src = (k0 < FI)
                ? x   + ((size_t)b * NN + rowA[rt]) * FI + k0
                : agg + ((size_t)b * NN + rowA[rt]) * FI + (k0 - FI);
            afr[rt] = load_cvt16(src);
        }
#pragma unroll
        for (int ct = 0; ct < 2; ct++) {
            const float* src = (k0 < FI)
                ? Wroot + (size_t)colB[ct] * FI + k0
                : Wrel  + (size_t)colB[ct] * FI + (k0 - FI);
            bfr[ct] = load_cvt16(src);
        }
#pragma unroll
        for (int rt = 0; rt < 2; rt++)
#pragma unroll
            for (int ct = 0; ct < 2; ct++)
                acc[rt][ct] = __builtin_amdgcn_mfma_f32_16x16x32_f16(
                    afr[rt], bfr[ct], acc[rt][ct], 0, 0, 0);
    }

    // epilogue: bias + relu + store h + score partial over this wave's 32 cols
    float prt[2][4];
#pragma unroll
    for (int rt = 0; rt < 2; rt++)
#pragma unroll
        for (int reg = 0; reg < 4; reg++) prt[rt][reg] = 0.f;

#pragma unroll
    for (int ct = 0; ct < 2; ct++) {
        int col = wv * 32 + ct * 16 + m16;
        float pc = p[col];
        float bv = bias[col];
#pragma unroll
        for (int rt = 0; rt < 2; rt++)
#pragma unroll
            for (int reg = 0; reg < 4; reg++) {
                int row = r0 + rt * 16 + q * 4 + reg;
                float hv = fmaxf(acc[rt][ct][reg] + bv, 0.f);
                if (row < n)
                    h[((size_t)b * NN + row) * HH + col] = hv;
                prt[rt][reg] += hv * pc;
            }
    }
#pragma unroll
    for (int rt = 0; rt < 2; rt++)
#pragma unroll
        for (int reg = 0; reg < 4; reg++) {
            float v = prt[rt][reg];
            v += __shfl_xor(v, 1); v += __shfl_xor(v, 2);
            v += __shfl_xor(v, 4); v += __shfl_xor(v, 8);
            prt[rt][reg] = v;
        }
    if (m16 == 0) {
#pragma unroll
        for (int rt = 0; rt < 2; rt++)
#pragma unroll
            for (int reg = 0; reg < 4; reg++)
                spart[wv][rt * 16 + q * 4 + reg] = prt[rt][reg];
    }
    __syncthreads();
    if (t < 32) {
        int row = r0 + t;
        if (row < n) {
            float s = spart[0][t] + spart[1][t] + spart[2][t] + spart[3][t];
            float sc = tanhf(s / snorm_s);
            unsigned u = __float_as_uint(sc);
            u = (u & 0x80000000u) ? ~u : (u ^ 0x80000000u);   // monotone asc
            u = ~u;                                            // -> descending
            keys[(size_t)b * NN + row] = ((unsigned long long)u << 32) | (unsigned)row;
            ssc[(size_t)b * NN + row] = sc;
        }
    }
}

// ---------------- exact rank, j-scan partitioned 4-way ----------------
__global__ __launch_bounds__(256) void rank_kernel(
    const unsigned long long* __restrict__ keys, const float* __restrict__ ssc,
    int n, int k, int* __restrict__ perm, float* __restrict__ vals,
    int* __restrict__ inv) {
    __shared__ unsigned long long sk[NN];
    __shared__ int pr2[256];
    int b = blockIdx.y;
    for (int i = threadIdx.x; i < NN; i += 256)
        sk[i] = (i < n) ? keys[(size_t)b * NN + i] : ~0ULL;
    __syncthreads();
    int il = threadIdx.x & 63;           // local i
    int jg = threadIdx.x >> 6;           // j-group (one wave each)
    int i = blockIdx.x * 64 + il;
    unsigned long long my = sk[i];
    int rank = 0;
#pragma unroll 8
    for (int j = jg * 512; j < jg * 512 + 512; j++)
        rank += (sk[j] < my) ? 1 : 0;
    pr2[threadIdx.x] = rank;
    __syncthreads();
    if (jg == 0 && i < n) {
        rank = pr2[il] + pr2[64 + il] + pr2[128 + il] + pr2[192 + il];
        if (rank < k) {
            perm[b * NN + rank] = i;
            vals[b * NN + rank] = ssc[(size_t)b * NN + i];
            inv[b * NN + i] = rank;
        } else {
            inv[b * NN + i] = -1;
        }
    }
}

// ---------------- fused gather*score + readout partials (pipelined perm/vals) ----------------
__global__ __launch_bounds__(128) void gather_part_kernel(
    const float* __restrict__ hin, float* __restrict__ xout,
    const int* __restrict__ perm, const float* __restrict__ vals, int k,
    float* __restrict__ part) {
    int b = blockIdx.x >> 7;                 // PARTS=128 splits per graph
    int j = blockIdx.x & (PARTS - 1);
    int f = threadIdx.x;
    float mx = -INFINITY, sm = 0.f;
    int i = j;
    int pi = perm[b * NN + i];
    float v = vals[b * NN + i];
    while (i < k) {
        int inext = i + PARTS;
        int pin = 0; float vn = 0.f;
        if (inext < k) { pin = perm[b * NN + inext]; vn = vals[b * NN + inext]; }
        float hv = hin[((size_t)b * NN + pi) * HH + f] * v;
        xout[((size_t)b * NN + i) * HH + f] = hv;
        mx = fmaxf(mx, hv);
        sm += hv;
        i = inext; pi = pin; v = vn;
    }
    part[(size_t)blockIdx.x * 256 + f] = mx;
    part[(size_t)blockIdx.x * 256 + 128 + f] = sm;
}

// ---------------- hierarchical combine: [3][BB][PARTS][256] -> [3][BB][PGRP][256] ----------------
__global__ __launch_bounds__(256) void combine_kernel(
    const float* __restrict__ partAll, float* __restrict__ partG) {
    int blk = blockIdx.x;            // l*BB*PGRP + b*PGRP + g
    int g = blk % PGRP;
    int rem = blk / PGRP;
    int b = rem & 15;
    int l = rem >> 4;
    int f = threadIdx.x;
    const float* src = partAll + ((((size_t)l * BB + b) * PARTS) + (size_t)g * JPG) * 256;
    float r;
    if (f < 128) {
        r = -INFINITY;
#pragma unroll
        for (int j = 0; j < JPG; j++) r = fmaxf(r, src[j * 256 + f]);
    } else {
        r = 0.f;
#pragma unroll
        for (int j = 0; j < JPG; j++) r += src[j * 256 + f];
    }
    partG[(((size_t)l * BB + b) * PGRP + g) * 256 + f] = r;
}

// ---------------- final: combine group partials (3 layers) + MLP ----------------
__global__ __launch_bounds__(256) void mlp_kernel(
    const float* __restrict__ partG,
    const float* __restrict__ W1, const float* __restrict__ b1,
    const float* __restrict__ W2, const float* __restrict__ b2,
    const float* __restrict__ W3, const float* __restrict__ b3,
    float* __restrict__ out) {
    __shared__ float sg[256];
    __shared__ float s1[128];
    __shared__ float s2[64];
    int b = blockIdx.x, tid = threadIdx.x;
    const float kk[3] = {(float)KK1, (float)KK2, (float)KK3};
    float acc = 0.f;
    if (tid < 128) {
#pragma unroll
        for (int l = 0; l < 3; l++) {
            float mx = -INFINITY;
#pragma unroll
            for (int j = 0; j < PGRP; j++)
                mx = fmaxf(mx, partG[(((size_t)l * BB + b) * PGRP + j) * 256 + tid]);
            acc += mx;
        }
    } else {
#pragma unroll
        for (int l = 0; l < 3; l++) {
            float sm = 0.f;
#pragma unroll
            for (int j = 0; j < PGRP; j++)
                sm += partG[(((size_t)l * BB + b) * PGRP + j) * 256 + tid];
            acc += sm / kk[l];
        }
    }
    sg[tid] = acc;
    __syncthreads();
    if (tid < 128) {
        float a = b1[tid];
        for (int j = 0; j < 256; j++) a += sg[j] * W1[tid * 256 + j];
        s1[tid] = fmaxf(a, 0.f);
    }
    __syncthreads();
    if (tid < 64) {
        float a = b2[tid];
        for (int j = 0; j < 128; j++) a += s1[j] * W2[tid * 128 + j];
        s2[tid] = fmaxf(a, 0.f);
    }
    __syncthreads();
    if (tid == 0) {
        float a = b3[0];
        for (int j = 0; j < 64; j++) a += s2[j] * W3[j];
        out[b] = 1.f / (1.f + expf(-a));
    }
}

extern "C" void kernel_launch(void* const* d_in, const int* in_sizes, int n_in,
                              void* d_out, int out_size, void* d_ws, size_t ws_size,
                              hipStream_t stream) {
    const float* x   = (const float*)d_in[0];
    const int*   ei  = (const int*)d_in[1];
    const float* Wr1 = (const float*)d_in[2];
    const float* Wl1 = (const float*)d_in[3];
    const float* b1  = (const float*)d_in[4];
    const float* p1  = (const float*)d_in[5];
    const float* Wr2 = (const float*)d_in[6];
    const float* Wl2 = (const float*)d_in[7];
    const float* b2  = (const float*)d_in[8];
    const float* p2  = (const float*)d_in[9];
    const float* Wr3 = (const float*)d_in[10];
    const float* Wl3 = (const float*)d_in[11];
    const float* b3  = (const float*)d_in[12];
    const float* p3  = (const float*)d_in[13];
    const float* l1W = (const float*)d_in[14];
    const float* l1b = (const float*)d_in[15];
    const float* l2W = (const float*)d_in[16];
    const float* l2b = (const float*)d_in[17];
    const float* l3W = (const float*)d_in[18];
    const float* l3b = (const float*)d_in[19];
    float* out = (float*)d_out;

    char* ws = (char*)d_ws;
    float* bufA = (float*)ws; ws += (size_t)BB * NN * HH * 4;
    float* bufB = (float*)ws; ws += (size_t)BB * NN * HH * 4;
    float* agg  = (float*)ws; ws += (size_t)BB * NN * HH * 4;
    int*   perm = (int*)ws;   ws += (size_t)BB * NN * 4;
    float* vals = (float*)ws; ws += (size_t)BB * NN * 4;
    int*   inv  = (int*)ws;   ws += (size_t)BB * NN * 4;
    int*   curS = (int*)ws;   ws += (size_t)BB * EE * 4;
    int*   curD = (int*)ws;   ws += (size_t)BB * EE * 4;
    float* partAll = (float*)ws; ws += (size_t)3 * BB * PARTS * 256 * 4;
    float* partG   = (float*)ws; ws += (size_t)3 * BB * PGRP * 256 * 4;
    int*   deg1 = (int*)ws;   ws += (size_t)BB * NN * 4;
    int*   deg2 = (int*)ws;   ws += (size_t)BB * NN * 4;
    int*   deg3 = (int*)ws;   ws += (size_t)BB * NN * 4;
    int*   csr  = (int*)ws;   ws += (size_t)BB * NN * DEGC * 4;   // 8 MB bucketed CSR
    unsigned long long* keys = (unsigned long long*)ws; ws += (size_t)BB * NN * 8;
    float* ssc  = (float*)ws; ws += (size_t)BB * NN * 4;
    float* part1 = partAll;
    float* part2 = partAll + (size_t)BB * PARTS * 256;
    float* part3 = partAll + (size_t)2 * BB * PARTS * 256;

    // one memset covers deg1/deg2/deg3 (contiguous)
    hipMemsetAsync(deg1, 0, (size_t)3 * BB * NN * 4, stream);

    // ---------- layer 1 ----------
    hipLaunchKernelGGL(build1_kernel, dim3(BB * EE / 256), dim3(256), 0, stream, ei, deg1, csr);
    hipLaunchKernelGGL(agg1_csr_kernel, dim3(NN / 8, BB), dim3(256), 0, stream, x, deg1, csr, agg);
    hipLaunchKernelGGL((conv_mfma_kernel<FIN>), dim3(NN / 32, BB), dim3(256), 0, stream,
                       x, agg, Wr1, Wl1, b1, p1, bufA, keys, ssc, NN);
    hipLaunchKernelGGL(rank_kernel, dim3(NN / 64, BB), dim3(256), 0, stream, keys, ssc, NN, KK1, perm, vals, inv);
    hipLaunchKernelGGL(gather_part_kernel, dim3(BB * PARTS), dim3(128), 0, stream, bufA, bufB, perm, vals, KK1, part1);

    // ---------- layer 2 (edge pass fuses remap + CSR build) ----------
    hipLaunchKernelGGL(build23_kernel, dim3(BB * EE / 256), dim3(256), 0, stream,
                       inv, ei, ei + EE, 2 * EE, curS, curD, 1, deg2, csr);
    hipLaunchKernelGGL(agg23_csr_kernel, dim3((KK1 + 3) / 4, BB), dim3(256), 0, stream, bufB, deg2, csr, agg, KK1);
    hipLaunchKernelGGL((conv_mfma_kernel<HH>), dim3((KK1 + 31) / 32, BB), dim3(256), 0, stream,
                       bufB, agg, Wr2, Wl2, b2, p2, bufA, keys, ssc, KK1);
    hipLaunchKernelGGL(rank_kernel, dim3(NN / 64, BB), dim3(256), 0, stream, keys, ssc, KK1, KK2, perm, vals, inv);
    hipLaunchKernelGGL(gather_part_kernel, dim3(BB * PARTS), dim3(128), 0, stream, bufA, bufB, perm, vals, KK2, part2);

    // ---------- layer 3 ----------
    hipLaunchKernelGGL(build23_kernel, dim3(BB * EE / 256), dim3(256), 0, stream,
                       inv, curS, curD, EE, curS, curD, 0, deg3, csr);
    hipLaunchKernelGGL(agg23_csr_kernel, dim3((KK2 + 3) / 4, BB), dim3(256), 0, stream, bufB, deg3, csr, agg, KK2);
    hipLaunchKernelGGL((conv_mfma_kernel<HH>), dim3((KK2 + 31) / 32, BB), dim3(256), 0, stream,
                       bufB, agg, Wr3, Wl3, b3, p3, bufA, keys, ssc, KK2);
    hipLaunchKernelGGL(rank_kernel, dim3(NN / 64, BB), dim3(256), 0, stream, keys, ssc, KK2, KK3, perm, vals, inv);
    hipLaunchKernelGGL(gather_part_kernel, dim3(BB * PARTS), dim3(128), 0, stream, bufA, bufB, perm, vals, KK3, part3);

    // ---------- final: hierarchical combine + MLP ----------
    hipLaunchKernelGGL(combine_kernel, dim3(3 * BB * PGRP), dim3(256), 0, stream, partAll, partG);
    hipLaunchKernelGGL(mlp_kernel, dim3(BB), dim3(256), 0, stream,
                       partG, l1W, l1b, l2W, l2b, l3W, l3b, out);
}

// Round 12
// 226.325 us; speedup vs baseline: 2.5100x; 1.1586x over previous
//
#include <hip/hip_runtime.h>
#include <cstdint>
#include <math.h>

#define BB 16
#define NN 2048
#define EE 32768
#define FIN 32
#define HH 128
#define KK1 1639
#define KK2 1312
#define KK3 1050
#define PARTS 256
#define PGRP 8            // combined groups per graph/layer
#define JPG (PARTS / PGRP)
#define DEGC 64           // bucket capacity; P(deg>64) ~ 1e-20 for Binom(32768,1/2048)

using f16x8 = __attribute__((ext_vector_type(8))) _Float16;
using f16x2 = __attribute__((ext_vector_type(2))) _Float16;
using f32x4 = __attribute__((ext_vector_type(4))) float;

// ---------------- layer-1 edge pass: bucket-scatter CSR directly ----------------
__global__ void build1_kernel(const int* __restrict__ ei,
                              int* __restrict__ deg, int* __restrict__ csr) {
    int t = blockIdx.x * blockDim.x + threadIdx.x;   // B*E
    int e = t & (EE - 1);
    int b = t >> 15;
    if (b >= BB) return;
    int s = ei[(size_t)b * 2 * EE + e];
    int d = ei[(size_t)b * 2 * EE + EE + e];
    int pos = atomicAdd(&deg[b * NN + d], 1);
    if (pos < DEGC) csr[((size_t)b * NN + d) * DEGC + pos] = s;
}

// ---------------- pull aggregation, F=32 (layer 1): x f32 -> agg f16 ----------------
__global__ __launch_bounds__(256) void agg1_csr_kernel(
    const float* __restrict__ x, const int* __restrict__ deg,
    const int* __restrict__ csr, _Float16* __restrict__ agg) {
    int b = blockIdx.y;
    int g = threadIdx.x >> 5, lane = threadIdx.x & 31;
    int node = blockIdx.x * 8 + g;
    int dg = deg[b * NN + node]; if (dg > DEGC) dg = DEGC;
    const int* bucket = csr + ((size_t)b * NN + node) * DEGC;
    float acc = 0.f;
    for (int base = 0; base < dg; base += 16) {
        int m = dg - base; if (m > 16) m = 16;
        int myidx = (lane < m) ? bucket[base + lane] : 0;
        float v[16];
        int idx[16];
#pragma unroll
        for (int u = 0; u < 16; u++) idx[u] = __shfl(myidx, u, 32);
#pragma unroll
        for (int u = 0; u < 16; u++)
            v[u] = x[((size_t)b * NN + idx[u]) * FIN + lane];
#pragma unroll
        for (int u = 0; u < 16; u++)
            acc += (u < m) ? v[u] : 0.f;
    }
    agg[((size_t)b * NN + node) * FIN + lane] = (_Float16)acc;
}

// ---------------- pull aggregation, F=128 (layers 2/3): f16 in/out, wave per node ----------------
__global__ __launch_bounds__(256) void agg23_csr_kernel(
    const _Float16* __restrict__ x, const int* __restrict__ deg,
    const int* __restrict__ csr, _Float16* __restrict__ agg, int n) {
    int b = blockIdx.y;
    int wv = threadIdx.x >> 6, lane = threadIdx.x & 63;
    int node = blockIdx.x * 4 + wv;
    if (node >= n) return;
    int dg = deg[b * NN + node]; if (dg > DEGC) dg = DEGC;
    const int* bucket = csr + ((size_t)b * NN + node) * DEGC;
    const f16x2* xf2 = reinterpret_cast<const f16x2*>(x);
    float ax = 0.f, ay = 0.f;
    for (int base = 0; base < dg; base += 16) {
        int m = dg - base; if (m > 16) m = 16;
        int myidx = (lane < m) ? bucket[base + lane] : 0;
        int idx[16];
#pragma unroll
        for (int u = 0; u < 16; u++) idx[u] = __shfl(myidx, u);
        f16x2 v[16];
#pragma unroll
        for (int u = 0; u < 16; u++)
            v[u] = xf2[((size_t)b * NN + idx[u]) * 64 + lane];
#pragma unroll
        for (int u = 0; u < 16; u++) {
            ax += (u < m) ? (float)v[u][0] : 0.f;
            ay += (u < m) ? (float)v[u][1] : 0.f;
        }
    }
    f16x2 o; o[0] = (_Float16)ax; o[1] = (_Float16)ay;
    reinterpret_cast<f16x2*>(agg)[((size_t)b * NN + node) * 64 + lane] = o;
}

// ---------------- f32 -> f16x8 fragment load (RNE via v_cvt_f16_f32) ----------------
__device__ __forceinline__ f16x8 load_cvt16(const float* src) {
    float4 lo = *reinterpret_cast<const float4*>(src);
    float4 hi = *reinterpret_cast<const float4*>(src + 4);
    f16x8 r;
    r[0] = (_Float16)lo.x; r[1] = (_Float16)lo.y;
    r[2] = (_Float16)lo.z; r[3] = (_Float16)lo.w;
    r[4] = (_Float16)hi.x; r[5] = (_Float16)hi.y;
    r[6] = (_Float16)hi.z; r[7] = (_Float16)hi.w;
    return r;
}

// ---------------- MFMA conv + fused score/key (h stored f16) ----------------
// Block = 32 rows x 128 cols, 4 waves, each wave 2x2 tiles of 16x16x32_f16.
// XF32: layer-1 (x f32, cvt); else x is f16 (direct 16B loads). agg always f16.
// A layout: lane holds A[lane%16][(lane/16)*8 + i]; B (W layout) same.
// D layout: col = lane&15, row = (lane>>4)*4 + reg.
template<int FI, bool XF32>
__global__ __launch_bounds__(256) void conv_mfma_kernel(
    const void* __restrict__ xv, const void* __restrict__ aggv,
    const float* __restrict__ Wroot, const float* __restrict__ Wrel,
    const float* __restrict__ bias, const float* __restrict__ p,
    _Float16* __restrict__ h, unsigned long long* __restrict__ keys,
    float* __restrict__ ssc, int n) {
    __shared__ float spart[4][32];
    __shared__ float snorm_s;
    const float* xf = (const float*)xv;
    const _Float16* xh = (const _Float16*)xv;
    const _Float16* ah = (const _Float16*)aggv;
    int b = blockIdx.y;
    int r0 = blockIdx.x * 32;
    int t = threadIdx.x;
    int wv = t >> 6, lane = t & 63;
    int m16 = lane & 15, q = lane >> 4;

    if (t < 64) {
        float v = p[t] * p[t] + p[t + 64] * p[t + 64];
#pragma unroll
        for (int off = 32; off; off >>= 1) v += __shfl_xor(v, off);
        if (t == 0) snorm_s = sqrtf(v);
    }

    f32x4 acc[2][2];
#pragma unroll
    for (int rt = 0; rt < 2; rt++)
#pragma unroll
        for (int ct = 0; ct < 2; ct++) {
            acc[rt][ct][0] = 0.f; acc[rt][ct][1] = 0.f;
            acc[rt][ct][2] = 0.f; acc[rt][ct][3] = 0.f;
        }

    int rowA[2] = { r0 + m16, r0 + 16 + m16 };
    int colB[2] = { wv * 32 + m16, wv * 32 + 16 + m16 };

#pragma unroll
    for (int step = 0; step < (2 * FI) / 32; step++) {
        int k0 = step * 32 + q * 8;
        f16x8 afr[2], bfr[2];
#pragma unroll
        for (int rt = 0; rt < 2; rt++) {
            if (k0 < FI) {
                if constexpr (XF32)
                    afr[rt] = load_cvt16(xf + ((size_t)b * NN + rowA[rt]) * FI + k0);
                else
                    afr[rt] = *reinterpret_cast<const f16x8*>(
                        xh + ((size_t)b * NN + rowA[rt]) * FI + k0);
            } else {
                afr[rt] = *reinterpret_cast<const f16x8*>(
                    ah + ((size_t)b * NN + rowA[rt]) * FI + (k0 - FI));
            }
        }
#pragma unroll
        for (int ct = 0; ct < 2; ct++) {
            const float* src = (k0 < FI)
                ? Wroot + (size_t)colB[ct] * FI + k0
                : Wrel  + (size_t)colB[ct] * FI + (k0 - FI);
            bfr[ct] = load_cvt16(src);
        }
#pragma unroll
        for (int rt = 0; rt < 2; rt++)
#pragma unroll
            for (int ct = 0; ct < 2; ct++)
                acc[rt][ct] = __builtin_amdgcn_mfma_f32_16x16x32_f16(
                    afr[rt], bfr[ct], acc[rt][ct], 0, 0, 0);
    }

    // epilogue: bias + relu + store h (f16) + score partial over this wave's 32 cols
    float prt[2][4];
#pragma unroll
    for (int rt = 0; rt < 2; rt++)
#pragma unroll
        for (int reg = 0; reg < 4; reg++) prt[rt][reg] = 0.f;

#pragma unroll
    for (int ct = 0; ct < 2; ct++) {
        int col = wv * 32 + ct * 16 + m16;
        float pc = p[col];
        float bv = bias[col];
#pragma unroll
        for (int rt = 0; rt < 2; rt++)
#pragma unroll
            for (int reg = 0; reg < 4; reg++) {
                int row = r0 + rt * 16 + q * 4 + reg;
                float hv = fmaxf(acc[rt][ct][reg] + bv, 0.f);
                if (row < n)
                    h[((size_t)b * NN + row) * HH + col] = (_Float16)hv;
                prt[rt][reg] += hv * pc;
            }
    }
#pragma unroll
    for (int rt = 0; rt < 2; rt++)
#pragma unroll
        for (int reg = 0; reg < 4; reg++) {
            float v = prt[rt][reg];
            v += __shfl_xor(v, 1); v += __shfl_xor(v, 2);
            v += __shfl_xor(v, 4); v += __shfl_xor(v, 8);
            prt[rt][reg] = v;
        }
    if (m16 == 0) {
#pragma unroll
        for (int rt = 0; rt < 2; rt++)
#pragma unroll
            for (int reg = 0; reg < 4; reg++)
                spart[wv][rt * 16 + q * 4 + reg] = prt[rt][reg];
    }
    __syncthreads();
    if (t < 32) {
        int row = r0 + t;
        if (row < n) {
            float s = spart[0][t] + spart[1][t] + spart[2][t] + spart[3][t];
            float sc = tanhf(s / snorm_s);
            unsigned u = __float_as_uint(sc);
            u = (u & 0x80000000u) ? ~u : (u ^ 0x80000000u);   // monotone asc
            u = ~u;                                            // -> descending
            keys[(size_t)b * NN + row] = ((unsigned long long)u << 32) | (unsigned)row;
            ssc[(size_t)b * NN + row] = sc;
        }
    }
}

// ---------------- exact rank, j-scan partitioned 4-way ----------------
__global__ __launch_bounds__(256) void rank_kernel(
    const unsigned long long* __restrict__ keys, const float* __restrict__ ssc,
    int n, int k, int* __restrict__ perm, float* __restrict__ vals,
    int* __restrict__ inv) {
    __shared__ unsigned long long sk[NN];
    __shared__ int pr2[256];
    int b = blockIdx.y;
    for (int i = threadIdx.x; i < NN; i += 256)
        sk[i] = (i < n) ? keys[(size_t)b * NN + i] : ~0ULL;
    __syncthreads();
    int il = threadIdx.x & 63;           // local i
    int jg = threadIdx.x >> 6;           // j-group (one wave each)
    int i = blockIdx.x * 64 + il;
    unsigned long long my = sk[i];
    int rank = 0;
#pragma unroll 8
    for (int j = jg * 512; j < jg * 512 + 512; j++)
        rank += (sk[j] < my) ? 1 : 0;
    pr2[threadIdx.x] = rank;
    __syncthreads();
    if (jg == 0 && i < n) {
        rank = pr2[il] + pr2[64 + il] + pr2[128 + il] + pr2[192 + il];
        if (rank < k) {
            perm[b * NN + rank] = i;
            vals[b * NN + rank] = ssc[(size_t)b * NN + i];
            inv[b * NN + i] = rank;
        } else {
            inv[b * NN + i] = -1;
        }
    }
}

// ---------------- fat kernel: [0,nbuild) = edge remap+CSR build; rest = gather+readout ----------------
// build path (256 thr): remap edge through inv, optional next-edge write, bucket scatter.
// gather path (256 thr = 2 jobs x 128): x_new = h[perm]*val (f16 out) + max/sum partials.
__global__ __launch_bounds__(256) void fat_gather_build_kernel(
    int nbuild,
    const int* __restrict__ inv,
    const int* __restrict__ sin_, const int* __restrict__ din_, int in_stride,
    int* __restrict__ sout, int* __restrict__ dout, int write_next,
    int* __restrict__ deg, int* __restrict__ csr,
    const _Float16* __restrict__ hin, _Float16* __restrict__ xout,
    const int* __restrict__ perm, const float* __restrict__ vals, int k,
    float* __restrict__ part) {
    if ((int)blockIdx.x < nbuild) {
        int t = blockIdx.x * 256 + threadIdx.x;   // B*E
        int e = t & (EE - 1);
        int b = t >> 15;
        if (b >= BB) return;
        int s = sin_[(size_t)b * in_stride + e];
        int d = din_[(size_t)b * in_stride + e];
        int ns = -1, nd = -1;
        if (s >= 0 && d >= 0) {
            ns = inv[b * NN + s];
            nd = inv[b * NN + d];
        }
        if (ns < 0 || nd < 0) { ns = -1; nd = -1; }
        if (write_next) {
            sout[(size_t)b * EE + e] = ns;
            dout[(size_t)b * EE + e] = nd;
        }
        if (nd >= 0) {
            int pos = atomicAdd(&deg[b * NN + nd], 1);
            if (pos < DEGC) csr[((size_t)b * NN + nd) * DEGC + pos] = ns;
        }
    } else {
        int gblk = blockIdx.x - nbuild;
        int pair = gblk * 2 + (threadIdx.x >> 7);  // (b,j) job
        int b = pair >> 8;
        int j = pair & (PARTS - 1);
        int f = threadIdx.x & 127;
        float mx = -INFINITY, sm = 0.f;
        int i = j;
        int pi = (i < k) ? perm[b * NN + i] : 0;
        float v = (i < k) ? vals[b * NN + i] : 0.f;
        while (i < k) {
            int inext = i + PARTS;
            int pin = 0; float vn = 0.f;
            if (inext < k) { pin = perm[b * NN + inext]; vn = vals[b * NN + inext]; }
            float hv = (float)hin[((size_t)b * NN + pi) * HH + f] * v;
            xout[((size_t)b * NN + i) * HH + f] = (_Float16)hv;
            mx = fmaxf(mx, hv);
            sm += hv;
            i = inext; pi = pin; v = vn;
        }
        part[((size_t)b * PARTS + j) * 256 + f] = mx;
        part[((size_t)b * PARTS + j) * 256 + 128 + f] = sm;
    }
}

// ---------------- hierarchical combine: [3][BB][PARTS][256] -> [3][BB][PGRP][256] ----------------
__global__ __launch_bounds__(256) void combine_kernel(
    const float* __restrict__ partAll, float* __restrict__ partG) {
    int blk = blockIdx.x;            // l*BB*PGRP + b*PGRP + g
    int g = blk % PGRP;
    int rem = blk / PGRP;
    int b = rem & 15;
    int l = rem >> 4;
    int f = threadIdx.x;
    const float* src = partAll + ((((size_t)l * BB + b) * PARTS) + (size_t)g * JPG) * 256;
    float r;
    if (f < 128) {
        r = -INFINITY;
#pragma unroll
        for (int j = 0; j < JPG; j++) r = fmaxf(r, src[j * 256 + f]);
    } else {
        r = 0.f;
#pragma unroll
        for (int j = 0; j < JPG; j++) r += src[j * 256 + f];
    }
    partG[(((size_t)l * BB + b) * PGRP + g) * 256 + f] = r;
}

// ---------------- final: combine group partials (3 layers) + MLP ----------------
__global__ __launch_bounds__(256) void mlp_kernel(
    const float* __restrict__ partG,
    const float* __restrict__ W1, const float* __restrict__ b1,
    const float* __restrict__ W2, const float* __restrict__ b2,
    const float* __restrict__ W3, const float* __restrict__ b3,
    float* __restrict__ out) {
    __shared__ float sg[256];
    __shared__ float s1[128];
    __shared__ float s2[64];
    int b = blockIdx.x, tid = threadIdx.x;
    const float kk[3] = {(float)KK1, (float)KK2, (float)KK3};
    float acc = 0.f;
    if (tid < 128) {
#pragma unroll
        for (int l = 0; l < 3; l++) {
            float mx = -INFINITY;
#pragma unroll
            for (int j = 0; j < PGRP; j++)
                mx = fmaxf(mx, partG[(((size_t)l * BB + b) * PGRP + j) * 256 + tid]);
            acc += mx;
        }
    } else {
#pragma unroll
        for (int l = 0; l < 3; l++) {
            float sm = 0.f;
#pragma unroll
            for (int j = 0; j < PGRP; j++)
                sm += partG[(((size_t)l * BB + b) * PGRP + j) * 256 + tid];
            acc += sm / kk[l];
        }
    }
    sg[tid] = acc;
    __syncthreads();
    if (tid < 128) {
        float a = b1[tid];
        for (int j = 0; j < 256; j++) a += sg[j] * W1[tid * 256 + j];
        s1[tid] = fmaxf(a, 0.f);
    }
    __syncthreads();
    if (tid < 64) {
        float a = b2[tid];
        for (int j = 0; j < 128; j++) a += s1[j] * W2[tid * 128 + j];
        s2[tid] = fmaxf(a, 0.f);
    }
    __syncthreads();
    if (tid == 0) {
        float a = b3[0];
        for (int j = 0; j < 64; j++) a += s2[j] * W3[j];
        out[b] = 1.f / (1.f + expf(-a));
    }
}

extern "C" void kernel_launch(void* const* d_in, const int* in_sizes, int n_in,
                              void* d_out, int out_size, void* d_ws, size_t ws_size,
                              hipStream_t stream) {
    const float* x   = (const float*)d_in[0];
    const int*   ei  = (const int*)d_in[1];
    const float* Wr1 = (const float*)d_in[2];
    const float* Wl1 = (const float*)d_in[3];
    const float* b1  = (const float*)d_in[4];
    const float* p1  = (const float*)d_in[5];
    const float* Wr2 = (const float*)d_in[6];
    const float* Wl2 = (const float*)d_in[7];
    const float* b2  = (const float*)d_in[8];
    const float* p2  = (const float*)d_in[9];
    const float* Wr3 = (const float*)d_in[10];
    const float* Wl3 = (const float*)d_in[11];
    const float* b3  = (const float*)d_in[12];
    const float* p3  = (const float*)d_in[13];
    const float* l1W = (const float*)d_in[14];
    const float* l1b = (const float*)d_in[15];
    const float* l2W = (const float*)d_in[16];
    const float* l2b = (const float*)d_in[17];
    const float* l3W = (const float*)d_in[18];
    const float* l3b = (const float*)d_in[19];
    float* out = (float*)d_out;

    char* ws = (char*)d_ws;
    _Float16* bufA = (_Float16*)ws; ws += (size_t)BB * NN * HH * 2;
    _Float16* bufB = (_Float16*)ws; ws += (size_t)BB * NN * HH * 2;
    _Float16* agg  = (_Float16*)ws; ws += (size_t)BB * NN * HH * 2;
    int*   perm = (int*)ws;   ws += (size_t)BB * NN * 4;
    float* vals = (float*)ws; ws += (size_t)BB * NN * 4;
    int*   inv  = (int*)ws;   ws += (size_t)BB * NN * 4;
    int*   curS = (int*)ws;   ws += (size_t)BB * EE * 4;
    int*   curD = (int*)ws;   ws += (size_t)BB * EE * 4;
    float* partAll = (float*)ws; ws += (size_t)3 * BB * PARTS * 256 * 4;
    float* partG   = (float*)ws; ws += (size_t)3 * BB * PGRP * 256 * 4;
    int*   deg1 = (int*)ws;   ws += (size_t)BB * NN * 4;
    int*   deg2 = (int*)ws;   ws += (size_t)BB * NN * 4;
    int*   deg3 = (int*)ws;   ws += (size_t)BB * NN * 4;
    int*   csr  = (int*)ws;   ws += (size_t)BB * NN * DEGC * 4;   // 8 MB bucketed CSR
    unsigned long long* keys = (unsigned long long*)ws; ws += (size_t)BB * NN * 8;
    float* ssc  = (float*)ws; ws += (size_t)BB * NN * 4;
    float* part1 = partAll;
    float* part2 = partAll + (size_t)BB * PARTS * 256;
    float* part3 = partAll + (size_t)2 * BB * PARTS * 256;

    // one memset covers deg1/deg2/deg3 (contiguous)
    hipMemsetAsync(deg1, 0, (size_t)3 * BB * NN * 4, stream);

    // ---------- layer 1 ----------
    hipLaunchKernelGGL(build1_kernel, dim3(BB * EE / 256), dim3(256), 0, stream, ei, deg1, csr);
    hipLaunchKernelGGL(agg1_csr_kernel, dim3(NN / 8, BB), dim3(256), 0, stream, x, deg1, csr, agg);
    hipLaunchKernelGGL((conv_mfma_kernel<FIN, true>), dim3(NN / 32, BB), dim3(256), 0, stream,
                       (const void*)x, (const void*)agg, Wr1, Wl1, b1, p1, bufA, keys, ssc, NN);
    hipLaunchKernelGGL(rank_kernel, dim3(NN / 64, BB), dim3(256), 0, stream, keys, ssc, NN, KK1, perm, vals, inv);
    // fat: gather L1 (bufA->bufB, part1)  +  build L2 CSR (remap ei through inv)
    hipLaunchKernelGGL(fat_gather_build_kernel, dim3(2048 + BB * PARTS / 2), dim3(256), 0, stream,
                       2048, inv, ei, ei + EE, 2 * EE, curS, curD, 1, deg2, csr,
                       bufA, bufB, perm, vals, KK1, part1);

    // ---------- layer 2 ----------
    hipLaunchKernelGGL(agg23_csr_kernel, dim3((KK1 + 3) / 4, BB), dim3(256), 0, stream, bufB, deg2, csr, agg, KK1);
    hipLaunchKernelGGL((conv_mfma_kernel<HH, false>), dim3((KK1 + 31) / 32, BB), dim3(256), 0, stream,
                       (const void*)bufB, (const void*)agg, Wr2, Wl2, b2, p2, bufA, keys, ssc, KK1);
    hipLaunchKernelGGL(rank_kernel, dim3(NN / 64, BB), dim3(256), 0, stream, keys, ssc, KK1, KK2, perm, vals, inv);
    hipLaunchKernelGGL(fat_gather_build_kernel, dim3(2048 + BB * PARTS / 2), dim3(256), 0, stream,
                       2048, inv, curS, curD, EE, curS, curD, 0, deg3, csr,
                       bufA, bufB, perm, vals, KK2, part2);

    // ---------- layer 3 ----------
    hipLaunchKernelGGL(agg23_csr_kernel, dim3((KK2 + 3) / 4, BB), dim3(256), 0, stream, bufB, deg3, csr, agg, KK2);
    hipLaunchKernelGGL((conv_mfma_kernel<HH, false>), dim3((KK2 + 31) / 32, BB), dim3(256), 0, stream,
                       (const void*)bufB, (const void*)agg, Wr3, Wl3, b3, p3, bufA, keys, ssc, KK2);
    hipLaunchKernelGGL(rank_kernel, dim3(NN / 64, BB), dim3(256), 0, stream, keys, ssc, KK2, KK3, perm, vals, inv);
    hipLaunchKernelGGL(fat_gather_build_kernel, dim3(BB * PARTS / 2), dim3(256), 0, stream,
                       0, inv, curS, curD, EE, curS, curD, 0, deg3, csr,
                       bufA, bufB, perm, vals, KK3, part3);

    // ---------- final: hierarchical combine + MLP ----------
    hipLaunchKernelGGL(combine_kernel, dim3(3 * BB * PGRP), dim3(256), 0, stream, partAll, partG);
    hipLaunchKernelGGL(mlp_kernel, dim3(BB), dim3(256), 0, stream,
                       partG, l1W, l1b, l2W, l2b, l3W, l3b, out);
}

// Round 13
// 217.456 us; speedup vs baseline: 2.6124x; 1.0408x over previous
//
#include <hip/hip_runtime.h>
#include <cstdint>
#include <math.h>

#define BB 16
#define NN 2048
#define EE 32768
#define FIN 32
#define HH 128
#define KK1 1639
#define KK2 1312
#define KK3 1050
#define PARTS 128
#define PGRP 8            // combined groups per graph/layer
#define JPG (PARTS / PGRP)
#define DEGC 64           // bucket capacity; P(deg>64) ~ 1e-20 for Binom(32768,1/2048)

using f16x8 = __attribute__((ext_vector_type(8))) _Float16;
using f16x2 = __attribute__((ext_vector_type(2))) _Float16;
using f32x4 = __attribute__((ext_vector_type(4))) float;

// ---------------- one-shot W concat+convert: [Wroot|Wrel] -> f16 wcat ----------------
// wcat1: 128x64 (layer1), wcat2/wcat3: 128x256
__global__ void wcvt_kernel(const float* __restrict__ Wr1, const float* __restrict__ Wl1,
                            const float* __restrict__ Wr2, const float* __restrict__ Wl2,
                            const float* __restrict__ Wr3, const float* __restrict__ Wl3,
                            _Float16* __restrict__ wcat1, _Float16* __restrict__ wcat2,
                            _Float16* __restrict__ wcat3) {
    int idx = blockIdx.x * 256 + threadIdx.x;
    if (idx < 128 * 64) {
        int col = idx >> 6, k = idx & 63;
        float v = (k < FIN) ? Wr1[col * FIN + k] : Wl1[col * FIN + (k - FIN)];
        wcat1[idx] = (_Float16)v;
    } else if (idx < 128 * 64 + 128 * 256) {
        int i2 = idx - 128 * 64;
        int col = i2 >> 8, k = i2 & 255;
        float v = (k < HH) ? Wr2[col * HH + k] : Wl2[col * HH + (k - HH)];
        wcat2[i2] = (_Float16)v;
    } else {
        int i3 = idx - 128 * 64 - 128 * 256;
        if (i3 < 128 * 256) {
            int col = i3 >> 8, k = i3 & 255;
            float v = (k < HH) ? Wr3[col * HH + k] : Wl3[col * HH + (k - HH)];
            wcat3[i3] = (_Float16)v;
        }
    }
}

// ---------------- layer-1 edge pass: bucket-scatter CSR directly ----------------
__global__ void build1_kernel(const int* __restrict__ ei,
                              int* __restrict__ deg, int* __restrict__ csr) {
    int t = blockIdx.x * blockDim.x + threadIdx.x;   // B*E
    int e = t & (EE - 1);
    int b = t >> 15;
    if (b >= BB) return;
    int s = ei[(size_t)b * 2 * EE + e];
    int d = ei[(size_t)b * 2 * EE + EE + e];
    int pos = atomicAdd(&deg[b * NN + d], 1);
    if (pos < DEGC) csr[((size_t)b * NN + d) * DEGC + pos] = s;
}

// ---------------- pull aggregation, F=32 (layer 1): graph in bx (XCD affinity) ----------------
__global__ __launch_bounds__(256) void agg1_csr_kernel(
    const float* __restrict__ x, const int* __restrict__ deg,
    const int* __restrict__ csr, _Float16* __restrict__ agg) {
    int b = blockIdx.x;
    int g = threadIdx.x >> 5, lane = threadIdx.x & 31;
    int node = blockIdx.y * 8 + g;
    int dg = deg[b * NN + node]; if (dg > DEGC) dg = DEGC;
    const int* bucket = csr + ((size_t)b * NN + node) * DEGC;
    float acc = 0.f;
    for (int base = 0; base < dg; base += 16) {
        int m = dg - base; if (m > 16) m = 16;
        int myidx = (lane < m) ? bucket[base + lane] : 0;
        float v[16];
        int idx[16];
#pragma unroll
        for (int u = 0; u < 16; u++) idx[u] = __shfl(myidx, u, 32);
#pragma unroll
        for (int u = 0; u < 16; u++)
            v[u] = x[((size_t)b * NN + idx[u]) * FIN + lane];
#pragma unroll
        for (int u = 0; u < 16; u++)
            acc += (u < m) ? v[u] : 0.f;
    }
    agg[((size_t)b * NN + node) * FIN + lane] = (_Float16)acc;
}

// ---------------- pull aggregation, F=128: graph in bx (XCD affinity) ----------------
__global__ __launch_bounds__(256) void agg23_csr_kernel(
    const _Float16* __restrict__ x, const int* __restrict__ deg,
    const int* __restrict__ csr, _Float16* __restrict__ agg, int n) {
    int b = blockIdx.x;
    int wv = threadIdx.x >> 6, lane = threadIdx.x & 63;
    int node = blockIdx.y * 4 + wv;
    if (node >= n) return;
    int dg = deg[b * NN + node]; if (dg > DEGC) dg = DEGC;
    const int* bucket = csr + ((size_t)b * NN + node) * DEGC;
    const f16x2* xf2 = reinterpret_cast<const f16x2*>(x);
    float ax = 0.f, ay = 0.f;
    for (int base = 0; base < dg; base += 16) {
        int m = dg - base; if (m > 16) m = 16;
        int myidx = (lane < m) ? bucket[base + lane] : 0;
        int idx[16];
#pragma unroll
        for (int u = 0; u < 16; u++) idx[u] = __shfl(myidx, u);
        f16x2 v[16];
#pragma unroll
        for (int u = 0; u < 16; u++)
            v[u] = xf2[((size_t)b * NN + idx[u]) * 64 + lane];
#pragma unroll
        for (int u = 0; u < 16; u++) {
            ax += (u < m) ? (float)v[u][0] : 0.f;
            ay += (u < m) ? (float)v[u][1] : 0.f;
        }
    }
    f16x2 o; o[0] = (_Float16)ax; o[1] = (_Float16)ay;
    reinterpret_cast<f16x2*>(agg)[((size_t)b * NN + node) * 64 + lane] = o;
}

// ---------------- f32 -> f16x8 fragment load ----------------
__device__ __forceinline__ f16x8 load_cvt16(const float* src) {
    float4 lo = *reinterpret_cast<const float4*>(src);
    float4 hi = *reinterpret_cast<const float4*>(src + 4);
    f16x8 r;
    r[0] = (_Float16)lo.x; r[1] = (_Float16)lo.y;
    r[2] = (_Float16)lo.z; r[3] = (_Float16)lo.w;
    r[4] = (_Float16)hi.x; r[5] = (_Float16)hi.y;
    r[6] = (_Float16)hi.z; r[7] = (_Float16)hi.w;
    return r;
}

// ---------------- MFMA conv + fused score/key; graph in bx (XCD affinity) ----------------
// Block = 32 rows x 128 cols, 4 waves, 2x2 tiles of 16x16x32_f16. W pre-cat f16.
template<int FI, bool XF32>
__global__ __launch_bounds__(256) void conv_mfma_kernel(
    const void* __restrict__ xv, const _Float16* __restrict__ ah,
    const _Float16* __restrict__ wcat,
    const float* __restrict__ bias, const float* __restrict__ p,
    _Float16* __restrict__ h, unsigned long long* __restrict__ keys,
    float* __restrict__ ssc, int n) {
    __shared__ float spart[4][32];
    __shared__ float snorm_s;
    const float* xf = (const float*)xv;
    const _Float16* xh = (const _Float16*)xv;
    int b = blockIdx.x;
    int r0 = blockIdx.y * 32;
    int t = threadIdx.x;
    int wv = t >> 6, lane = t & 63;
    int m16 = lane & 15, q = lane >> 4;

    if (t < 64) {
        float v = p[t] * p[t] + p[t + 64] * p[t + 64];
#pragma unroll
        for (int off = 32; off; off >>= 1) v += __shfl_xor(v, off);
        if (t == 0) snorm_s = sqrtf(v);
    }

    f32x4 acc[2][2];
#pragma unroll
    for (int rt = 0; rt < 2; rt++)
#pragma unroll
        for (int ct = 0; ct < 2; ct++) {
            acc[rt][ct][0] = 0.f; acc[rt][ct][1] = 0.f;
            acc[rt][ct][2] = 0.f; acc[rt][ct][3] = 0.f;
        }

    int rowA[2] = { r0 + m16, r0 + 16 + m16 };
    int colB[2] = { wv * 32 + m16, wv * 32 + 16 + m16 };

#pragma unroll
    for (int step = 0; step < (2 * FI) / 32; step++) {
        int k0 = step * 32 + q * 8;
        f16x8 afr[2], bfr[2];
#pragma unroll
        for (int rt = 0; rt < 2; rt++) {
            if (k0 < FI) {
                if constexpr (XF32)
                    afr[rt] = load_cvt16(xf + ((size_t)b * NN + rowA[rt]) * FI + k0);
                else
                    afr[rt] = *reinterpret_cast<const f16x8*>(
                        xh + ((size_t)b * NN + rowA[rt]) * FI + k0);
            } else {
                afr[rt] = *reinterpret_cast<const f16x8*>(
                    ah + ((size_t)b * NN + rowA[rt]) * FI + (k0 - FI));
            }
        }
#pragma unroll
        for (int ct = 0; ct < 2; ct++)
            bfr[ct] = *reinterpret_cast<const f16x8*>(
                wcat + (size_t)colB[ct] * (2 * FI) + k0);
#pragma unroll
        for (int rt = 0; rt < 2; rt++)
#pragma unroll
            for (int ct = 0; ct < 2; ct++)
                acc[rt][ct] = __builtin_amdgcn_mfma_f32_16x16x32_f16(
                    afr[rt], bfr[ct], acc[rt][ct], 0, 0, 0);
    }

    float prt[2][4];
#pragma unroll
    for (int rt = 0; rt < 2; rt++)
#pragma unroll
        for (int reg = 0; reg < 4; reg++) prt[rt][reg] = 0.f;

#pragma unroll
    for (int ct = 0; ct < 2; ct++) {
        int col = wv * 32 + ct * 16 + m16;
        float pc = p[col];
        float bv = bias[col];
#pragma unroll
        for (int rt = 0; rt < 2; rt++)
#pragma unroll
            for (int reg = 0; reg < 4; reg++) {
                int row = r0 + rt * 16 + q * 4 + reg;
                float hv = fmaxf(acc[rt][ct][reg] + bv, 0.f);
                if (row < n)
                    h[((size_t)b * NN + row) * HH + col] = (_Float16)hv;
                prt[rt][reg] += hv * pc;
            }
    }
#pragma unroll
    for (int rt = 0; rt < 2; rt++)
#pragma unroll
        for (int reg = 0; reg < 4; reg++) {
            float v = prt[rt][reg];
            v += __shfl_xor(v, 1); v += __shfl_xor(v, 2);
            v += __shfl_xor(v, 4); v += __shfl_xor(v, 8);
            prt[rt][reg] = v;
        }
    if (m16 == 0) {
#pragma unroll
        for (int rt = 0; rt < 2; rt++)
#pragma unroll
            for (int reg = 0; reg < 4; reg++)
                spart[wv][rt * 16 + q * 4 + reg] = prt[rt][reg];
    }
    __syncthreads();
    if (t < 32) {
        int row = r0 + t;
        if (row < n) {
            float s = spart[0][t] + spart[1][t] + spart[2][t] + spart[3][t];
            float sc = tanhf(s / snorm_s);
            unsigned u = __float_as_uint(sc);
            u = (u & 0x80000000u) ? ~u : (u ^ 0x80000000u);   // monotone asc
            u = ~u;                                            // -> descending
            keys[(size_t)b * NN + row] = ((unsigned long long)u << 32) | (unsigned)row;
            ssc[(size_t)b * NN + row] = sc;
        }
    }
}

// ---------------- exact rank; graph in bx (XCD affinity) ----------------
__global__ __launch_bounds__(256) void rank_kernel(
    const unsigned long long* __restrict__ keys, const float* __restrict__ ssc,
    int n, int k, int* __restrict__ perm, float* __restrict__ vals,
    int* __restrict__ inv) {
    __shared__ unsigned long long sk[NN];
    __shared__ int pr2[256];
    int b = blockIdx.x;
    for (int i = threadIdx.x; i < NN; i += 256)
        sk[i] = (i < n) ? keys[(size_t)b * NN + i] : ~0ULL;
    __syncthreads();
    int il = threadIdx.x & 63;           // local i
    int jg = threadIdx.x >> 6;           // j-group (one wave each)
    int i = blockIdx.y * 64 + il;
    unsigned long long my = sk[i];
    int rank = 0;
#pragma unroll 8
    for (int j = jg * 512; j < jg * 512 + 512; j++)
        rank += (sk[j] < my) ? 1 : 0;
    pr2[threadIdx.x] = rank;
    __syncthreads();
    if (jg == 0 && i < n) {
        rank = pr2[il] + pr2[64 + il] + pr2[128 + il] + pr2[192 + il];
        if (rank < k) {
            perm[b * NN + rank] = i;
            vals[b * NN + rank] = ssc[(size_t)b * NN + i];
            inv[b * NN + i] = rank;
        } else {
            inv[b * NN + i] = -1;
        }
    }
}

// ---------------- fat kernel: [0,nbuild) = edge remap+CSR build; rest = gather ----------------
// gather: pair = gblk*2 + half; b = pair & 15 (XCD affinity: graph b -> XCD b/2), j = pair >> 4.
__global__ __launch_bounds__(256) void fat_gather_build_kernel(
    int nbuild,
    const int* __restrict__ inv,
    const int* __restrict__ sin_, const int* __restrict__ din_, int in_stride,
    int* __restrict__ sout, int* __restrict__ dout, int write_next,
    int* __restrict__ deg, int* __restrict__ csr,
    const _Float16* __restrict__ hin, _Float16* __restrict__ xout,
    const int* __restrict__ perm, const float* __restrict__ vals, int k,
    float* __restrict__ part) {
    if ((int)blockIdx.x < nbuild) {
        int t = blockIdx.x * 256 + threadIdx.x;   // B*E
        int e = t & (EE - 1);
        int b = t >> 15;
        if (b >= BB) return;
        int s = sin_[(size_t)b * in_stride + e];
        int d = din_[(size_t)b * in_stride + e];
        int ns = -1, nd = -1;
        if (s >= 0 && d >= 0) {
            ns = inv[b * NN + s];
            nd = inv[b * NN + d];
        }
        if (ns < 0 || nd < 0) { ns = -1; nd = -1; }
        if (write_next) {
            sout[(size_t)b * EE + e] = ns;
            dout[(size_t)b * EE + e] = nd;
        }
        if (nd >= 0) {
            int pos = atomicAdd(&deg[b * NN + nd], 1);
            if (pos < DEGC) csr[((size_t)b * NN + nd) * DEGC + pos] = ns;
        }
    } else {
        int gblk = blockIdx.x - nbuild;
        int pair = gblk * 2 + (threadIdx.x >> 7);  // [0, BB*PARTS)
        int b = pair & 15;                          // XCD affinity
        int j = pair >> 4;                          // [0, PARTS)
        int f = threadIdx.x & 127;
        float mx = -INFINITY, sm = 0.f;
        int i = j;
        int pi = (i < k) ? perm[b * NN + i] : 0;
        float v = (i < k) ? vals[b * NN + i] : 0.f;
        while (i < k) {
            int inext = i + PARTS;
            int pin = 0; float vn = 0.f;
            if (inext < k) { pin = perm[b * NN + inext]; vn = vals[b * NN + inext]; }
            float hv = (float)hin[((size_t)b * NN + pi) * HH + f] * v;
            xout[((size_t)b * NN + i) * HH + f] = (_Float16)hv;
            mx = fmaxf(mx, hv);
            sm += hv;
            i = inext; pi = pin; v = vn;
        }
        part[((size_t)b * PARTS + j) * 256 + f] = mx;
        part[((size_t)b * PARTS + j) * 256 + 128 + f] = sm;
    }
}

// ---------------- hierarchical combine: [3][BB][PARTS][256] -> [3][BB][PGRP][256] ----------------
__global__ __launch_bounds__(256) void combine_kernel(
    const float* __restrict__ partAll, float* __restrict__ partG) {
    int blk = blockIdx.x;            // l*BB*PGRP + b*PGRP + g
    int g = blk % PGRP;
    int rem = blk / PGRP;
    int b = rem & 15;
    int l = rem >> 4;
    int f = threadIdx.x;
    const float* src = partAll + ((((size_t)l * BB + b) * PARTS) + (size_t)g * JPG) * 256;
    float r;
    if (f < 128) {
        r = -INFINITY;
#pragma unroll
        for (int j = 0; j < JPG; j++) r = fmaxf(r, src[j * 256 + f]);
    } else {
        r = 0.f;
#pragma unroll
        for (int j = 0; j < JPG; j++) r += src[j * 256 + f];
    }
    partG[(((size_t)l * BB + b) * PGRP + g) * 256 + f] = r;
}

// ---------------- final: combine group partials (3 layers) + MLP ----------------
__global__ __launch_bounds__(256) void mlp_kernel(
    const float* __restrict__ partG,
    const float* __restrict__ W1, const float* __restrict__ b1,
    const float* __restrict__ W2, const float* __restrict__ b2,
    const float* __restrict__ W3, const float* __restrict__ b3,
    float* __restrict__ out) {
    __shared__ float sg[256];
    __shared__ float s1[128];
    __shared__ float s2[64];
    int b = blockIdx.x, tid = threadIdx.x;
    const float kk[3] = {(float)KK1, (float)KK2, (float)KK3};
    float acc = 0.f;
    if (tid < 128) {
#pragma unroll
        for (int l = 0; l < 3; l++) {
            float mx = -INFINITY;
#pragma unroll
            for (int j = 0; j < PGRP; j++)
                mx = fmaxf(mx, partG[(((size_t)l * BB + b) * PGRP + j) * 256 + tid]);
            acc += mx;
        }
    } else {
#pragma unroll
        for (int l = 0; l < 3; l++) {
            float sm = 0.f;
#pragma unroll
            for (int j = 0; j < PGRP; j++)
                sm += partG[(((size_t)l * BB + b) * PGRP + j) * 256 + tid];
            acc += sm / kk[l];
        }
    }
    sg[tid] = acc;
    __syncthreads();
    if (tid < 128) {
        float a = b1[tid];
        for (int j = 0; j < 256; j++) a += sg[j] * W1[tid * 256 + j];
        s1[tid] = fmaxf(a, 0.f);
    }
    __syncthreads();
    if (tid < 64) {
        float a = b2[tid];
        for (int j = 0; j < 128; j++) a += s1[j] * W2[tid * 128 + j];
        s2[tid] = fmaxf(a, 0.f);
    }
    __syncthreads();
    if (tid == 0) {
        float a = b3[0];
        for (int j = 0; j < 64; j++) a += s2[j] * W3[j];
        out[b] = 1.f / (1.f + expf(-a));
    }
}

extern "C" void kernel_launch(void* const* d_in, const int* in_sizes, int n_in,
                              void* d_out, int out_size, void* d_ws, size_t ws_size,
                              hipStream_t stream) {
    const float* x   = (const float*)d_in[0];
    const int*   ei  = (const int*)d_in[1];
    const float* Wr1 = (const float*)d_in[2];
    const float* Wl1 = (const float*)d_in[3];
    const float* b1  = (const float*)d_in[4];
    const float* p1  = (const float*)d_in[5];
    const float* Wr2 = (const float*)d_in[6];
    const float* Wl2 = (const float*)d_in[7];
    const float* b2  = (const float*)d_in[8];
    const float* p2  = (const float*)d_in[9];
    const float* Wr3 = (const float*)d_in[10];
    const float* Wl3 = (const float*)d_in[11];
    const float* b3  = (const float*)d_in[12];
    const float* p3  = (const float*)d_in[13];
    const float* l1W = (const float*)d_in[14];
    const float* l1b = (const float*)d_in[15];
    const float* l2W = (const float*)d_in[16];
    const float* l2b = (const float*)d_in[17];
    const float* l3W = (const float*)d_in[18];
    const float* l3b = (const float*)d_in[19];
    float* out = (float*)d_out;

    char* ws = (char*)d_ws;
    _Float16* bufA = (_Float16*)ws; ws += (size_t)BB * NN * HH * 2;
    _Float16* bufB = (_Float16*)ws; ws += (size_t)BB * NN * HH * 2;
    _Float16* agg  = (_Float16*)ws; ws += (size_t)BB * NN * HH * 2;
    int*   perm = (int*)ws;   ws += (size_t)BB * NN * 4;
    float* vals = (float*)ws; ws += (size_t)BB * NN * 4;
    int*   inv  = (int*)ws;   ws += (size_t)BB * NN * 4;
    int*   curS = (int*)ws;   ws += (size_t)BB * EE * 4;
    int*   curD = (int*)ws;   ws += (size_t)BB * EE * 4;
    float* partAll = (float*)ws; ws += (size_t)3 * BB * PARTS * 256 * 4;
    float* partG   = (float*)ws; ws += (size_t)3 * BB * PGRP * 256 * 4;
    int*   deg1 = (int*)ws;   ws += (size_t)BB * NN * 4;
    int*   deg2 = (int*)ws;   ws += (size_t)BB * NN * 4;
    int*   deg3 = (int*)ws;   ws += (size_t)BB * NN * 4;
    int*   csr  = (int*)ws;   ws += (size_t)BB * NN * DEGC * 4;   // 8 MB bucketed CSR
    unsigned long long* keys = (unsigned long long*)ws; ws += (size_t)BB * NN * 8;
    float* ssc  = (float*)ws; ws += (size_t)BB * NN * 4;
    _Float16* wcat1 = (_Float16*)ws; ws += (size_t)128 * 64 * 2;
    _Float16* wcat2 = (_Float16*)ws; ws += (size_t)128 * 256 * 2;
    _Float16* wcat3 = (_Float16*)ws; ws += (size_t)128 * 256 * 2;
    float* part1 = partAll;
    float* part2 = partAll + (size_t)BB * PARTS * 256;
    float* part3 = partAll + (size_t)2 * BB * PARTS * 256;

    // one memset covers deg1/deg2/deg3 (contiguous)
    hipMemsetAsync(deg1, 0, (size_t)3 * BB * NN * 4, stream);
    hipLaunchKernelGGL(wcvt_kernel, dim3((128 * 64 + 2 * 128 * 256 + 255) / 256), dim3(256), 0, stream,
                       Wr1, Wl1, Wr2, Wl2, Wr3, Wl3, wcat1, wcat2, wcat3);

    // ---------- layer 1 ----------
    hipLaunchKernelGGL(build1_kernel, dim3(BB * EE / 256), dim3(256), 0, stream, ei, deg1, csr);
    hipLaunchKernelGGL(agg1_csr_kernel, dim3(BB, NN / 8), dim3(256), 0, stream, x, deg1, csr, agg);
    hipLaunchKernelGGL((conv_mfma_kernel<FIN, true>), dim3(BB, NN / 32), dim3(256), 0, stream,
                       (const void*)x, agg, wcat1, b1, p1, bufA, keys, ssc, NN);
    hipLaunchKernelGGL(rank_kernel, dim3(BB, NN / 64), dim3(256), 0, stream, keys, ssc, NN, KK1, perm, vals, inv);
    hipLaunchKernelGGL(fat_gather_build_kernel, dim3(2048 + BB * PARTS / 2), dim3(256), 0, stream,
                       2048, inv, ei, ei + EE, 2 * EE, curS, curD, 1, deg2, csr,
                       bufA, bufB, perm, vals, KK1, part1);

    // ---------- layer 2 ----------
    hipLaunchKernelGGL(agg23_csr_kernel, dim3(BB, (KK1 + 3) / 4), dim3(256), 0, stream, bufB, deg2, csr, agg, KK1);
    hipLaunchKernelGGL((conv_mfma_kernel<HH, false>), dim3(BB, (KK1 + 31) / 32), dim3(256), 0, stream,
                       (const void*)bufB, agg, wcat2, b2, p2, bufA, keys, ssc, KK1);
    hipLaunchKernelGGL(rank_kernel, dim3(BB, NN / 64), dim3(256), 0, stream, keys, ssc, KK1, KK2, perm, vals, inv);
    hipLaunchKernelGGL(fat_gather_build_kernel, dim3(2048 + BB * PARTS / 2), dim3(256), 0, stream,
                       2048, inv, curS, curD, EE, curS, curD, 0, deg3, csr,
                       bufA, bufB, perm, vals, KK2, part2);

    // ---------- layer 3 ----------
    hipLaunchKernelGGL(agg23_csr_kernel, dim3(BB, (KK2 + 3) / 4), dim3(256), 0, stream, bufB, deg3, csr, agg, KK2);
    hipLaunchKernelGGL((conv_mfma_kernel<HH, false>), dim3(BB, (KK2 + 31) / 32), dim3(256), 0, stream,
                       (const void*)bufB, agg, wcat3, b3, p3, bufA, keys, ssc, KK2);
    hipLaunchKernelGGL(rank_kernel, dim3(BB, NN / 64), dim3(256), 0, stream, keys, ssc, KK2, KK3, perm, vals, inv);
    hipLaunchKernelGGL(fat_gather_build_kernel, dim3(BB * PARTS / 2), dim3(256), 0, stream,
                       0, inv, curS, curD, EE, curS, curD, 0, deg3, csr,
                       bufA, bufB, perm, vals, KK3, part3);

    // ---------- final: hierarchical combine + MLP ----------
    hipLaunchKernelGGL(combine_kernel, dim3(3 * BB * PGRP), dim3(256), 0, stream, partAll, partG);
    hipLaunchKernelGGL(mlp_kernel, dim3(BB), dim3(256), 0, stream,
                       partG, l1W, l1b, l2W, l2b, l3W, l3b, out);
}